// Round 3
// baseline (624.814 us; speedup 1.0000x reference)
//
#include <hip/hip_runtime.h>
#include <math.h>

// ---------------- problem constants ----------------
// B=2, K=19 -> BK=38 batches; M=1024 points; C=256 feat ch; NPOINT=NSAMPLE=128
#define NBK   38

// ---------------- workspace layout (bytes) ----------------
#define OFF_XC    0u          // [38][3][1024] f32        = 466944
#define OFF_NXYZ  466944u     // [38][128][3]  f32        = 58368
#define OFF_BIDX  525312u     // [38][128][128] i32       = 2490368
#define OFF_W1F   3015680u    // [38][1024][128] f32      = 19922944
#define OFF_PREP  22938624u   // 4096 f32
#define OFF_WF    22955008u   // 196608 shorts: w2/w3 (0), unused (65536), c1/c2 (131072)
#define OFF_CNT   23348224u   // [38][128] i32 ball counts = 19456

// ---------------- d_out layout (float offsets) ----------------
#define OUT_AGG   24320       // scores at 0: (2,19,128,5)
#define OUT_FEAT  38912       // agg: (2,19,128,3), feat: (2,19,128,128)

typedef short bf16x8 __attribute__((ext_vector_type(8)));   // 8 bf16 = 4 VGPR
typedef float f32x4  __attribute__((ext_vector_type(4)));
typedef int   v4i    __attribute__((ext_vector_type(4)));
typedef int   v2i    __attribute__((ext_vector_type(2)));

// exact IEEE fp32 squared distance, no FMA contraction, ((d0^2+d1^2)+d2^2)
__device__ __forceinline__ float dist2f(float a0, float a1, float a2,
                                        float b0, float b1, float b2) {
#pragma clang fp contract(off)
  float d0 = a0 - b0;
  float d1 = a1 - b1;
  float d2 = a2 - b2;
  return d0 * d0 + d1 * d1 + d2 * d2;
}

// 2-way bf16 split with round-to-nearest-even: v ~= hi + mid, residual <= 2^-18 |v|
__device__ __forceinline__ void split2rn(float v, unsigned& sh, unsigned& sm) {
  unsigned u = __float_as_uint(v);
  unsigned rh = (u + 0x7fffu + ((u >> 16) & 1u)) & 0xffff0000u;
  sh = rh >> 16;
  float r1 = v - __uint_as_float(rh);        // exact in fp32
  unsigned u1 = __float_as_uint(r1);
  unsigned rm = (u1 + 0x7fffu + ((u1 >> 16) & 1u)) & 0xffff0000u;
  sm = rm >> 16;
}

// DPP fmax step: v = fmax(v, v shifted by ctrl); invalid lanes keep own value.
#define DPP_FMAX_STEP(v, ctrl)                                                 \
  {                                                                            \
    int _s = __builtin_amdgcn_update_dpp(__float_as_int(v), __float_as_int(v), \
                                         (ctrl), 0xf, 0xf, false);             \
    (v) = fmaxf((v), __int_as_float(_s));                                      \
  }

__device__ __forceinline__ float readlane_f(float v, int l) {
  return __int_as_float(__builtin_amdgcn_readlane(__float_as_int(v), l));
}

// ---------------- dedicated fps kernel: 38 blocks x 256 threads --------------
// Own kernel => own register budget: the 64-float point set + tournament temps
// stay in VGPRs (launch_bounds(256,1) caps at 512 regs, ~170 needed, no spill).
__global__ __launch_bounds__(256, 1) void fps_kernel(
    const float* __restrict__ xyz, float* __restrict__ xc,
    float* __restrict__ nxyz, float* __restrict__ agg)
{
  __shared__ __align__(16) float4 sp4[1024];
  int bk = blockIdx.x;
  int b = bk / 19, k = bk % 19;
  int t = threadIdx.x, lane = t & 63, wave = t >> 6;

  // stage points into LDS + write the transposed xc copy (4 waves)
  for (int i = t; i < 1024; i += 256) {
    const float* src = xyz + ((size_t)((b * 1024 + i) * 19 + k)) * 3;
    float x0 = src[0], x1 = src[1], x2 = src[2];
    sp4[i] = make_float4(x0, x1, x2, 0.f);
    xc[(bk * 3 + 0) * 1024 + i] = x0;
    xc[(bk * 3 + 1) * 1024 + i] = x1;
    xc[(bk * 3 + 2) * 1024 + i] = x2;
  }
  __syncthreads();
  if (wave != 0) return;

  // lane owns contiguous points m = lane*16 + j  => ctz(ballot) over lanes +
  // >=-left-wins tree within lane == exact jnp.argmax first-max semantics
  float px[16], py[16], pz[16], dist[16];
#pragma unroll
  for (int j = 0; j < 16; ++j) {
    float4 p = sp4[(lane << 4) + j];
    px[j] = p.x; py[j] = p.y; pz[j] = p.z;
    dist[j] = 1e10f;
  }
#pragma unroll
  for (int j = 0; j < 16; ++j)
    asm volatile("" : "+v"(px[j]), "+v"(py[j]), "+v"(pz[j]));

  // center 0 = point 0 (lane 0, j = 0)
  float cx = readlane_f(px[0], 0);
  float cy = readlane_f(py[0], 0);
  float cz = readlane_f(pz[0], 0);
  if (lane == 0) {
    nxyz[bk * 384 + 0] = cx; nxyz[bk * 384 + 1] = cy; nxyz[bk * 384 + 2] = cz;
    agg[bk * 384 + 0] = cx;  agg[bk * 384 + 1] = cy;  agg[bk * 384 + 2] = cz;
  }

  for (int it = 1; it < 128; ++it) {
#pragma unroll
    for (int j = 0; j < 16; ++j) {
      float d = dist2f(px[j], py[j], pz[j], cx, cy, cz);
      dist[j] = fminf(dist[j], d);
    }
    // local first-max tournament carrying coordinates (>= keeps left =>
    // smallest j on ties); index itself is never needed downstream.
    float tv[8], tx[8], ty[8], tz[8];
#pragma unroll
    for (int i = 0; i < 8; ++i) {
      bool L = dist[2 * i] >= dist[2 * i + 1];
      tv[i] = L ? dist[2 * i] : dist[2 * i + 1];
      tx[i] = L ? px[2 * i] : px[2 * i + 1];
      ty[i] = L ? py[2 * i] : py[2 * i + 1];
      tz[i] = L ? pz[2 * i] : pz[2 * i + 1];
    }
#pragma unroll
    for (int s = 1; s < 8; s <<= 1) {
#pragma unroll
      for (int i = 0; i < 8; i += 2 * s) {
        bool L = tv[i] >= tv[i + s];
        tv[i] = L ? tv[i] : tv[i + s];
        tx[i] = L ? tx[i] : tx[i + s];
        ty[i] = L ? ty[i] : ty[i + s];
        tz[i] = L ? tz[i] : tz[i + s];
      }
    }
    float lmax = tv[0];
    // in-row max via DPP row_shr (VALU only): lanes 15/31/47/63 hold row max
    float g = lmax;
    DPP_FMAX_STEP(g, 0x111);   // row_shr:1
    DPP_FMAX_STEP(g, 0x112);   // row_shr:2
    DPP_FMAX_STEP(g, 0x114);   // row_shr:4
    DPP_FMAX_STEP(g, 0x118);   // row_shr:8
    float r0 = readlane_f(g, 15);
    float r1 = readlane_f(g, 31);
    float r2 = readlane_f(g, 47);
    float r3 = readlane_f(g, 63);
    float gmax = fmaxf(fmaxf(r0, r1), fmaxf(r2, r3));
    unsigned long long mk = __ballot(lmax == gmax);
    int wl = (int)__builtin_ctzll(mk);
    cx = readlane_f(tx[0], wl);
    cy = readlane_f(ty[0], wl);
    cz = readlane_f(tz[0], wl);
    if (lane == 0) {
      nxyz[bk * 384 + it * 3 + 0] = cx;
      nxyz[bk * 384 + it * 3 + 1] = cy;
      nxyz[bk * 384 + it * 3 + 2] = cz;
      agg[bk * 384 + it * 3 + 0] = cx;
      agg[bk * 384 + it * 3 + 1] = cy;
      agg[bk * 384 + it * 3 + 2] = cz;
    }
  }
}

// ---------------- K1 "front" (512-thread blocks) ----------------
// blocks 0..37: ball query (points re-staged from xc, centers from nxyz);
// 38..341: w1f (256 active threads); 342..357: w2/w3 split;
// 358..373: c1/c2 split; 374: prep constants.
__global__ __launch_bounds__(512, 2) void front_kernel(
    const float* __restrict__ xyz, const float* __restrict__ feats,
    const float* __restrict__ m1w, const float* __restrict__ m1b,
    const float* __restrict__ m1g, const float* __restrict__ m1be,
    const float* __restrict__ m2w, const float* __restrict__ m2b,
    const float* __restrict__ m2g, const float* __restrict__ m2be,
    const float* __restrict__ m3w, const float* __restrict__ m3b,
    const float* __restrict__ m3g, const float* __restrict__ m3be,
    const float* __restrict__ c1w, const float* __restrict__ c1b,
    const float* __restrict__ c1g, const float* __restrict__ c1be,
    const float* __restrict__ c2w, const float* __restrict__ c2b,
    const float* __restrict__ c2g, const float* __restrict__ c2be,
    float* __restrict__ xc, float* __restrict__ nxyz,
    int* __restrict__ bidx, int* __restrict__ counts,
    float* __restrict__ W1f, short* __restrict__ Wf, float* __restrict__ prep)
{
  __shared__ __align__(16) char smem[32768];
  int bid = blockIdx.x, t = threadIdx.x;
  int wave = t >> 6, lane = t & 63;

  if (bid < NBK) {
    // ================= ball query only (fps already done) =================
    int bk = bid;
    float4* sp4 = (float4*)smem;                    // 1024 float4 = 16KB
    float4* scen4 = (float4*)(smem + 16384);        // 128 float4 = 2KB

    for (int i = t; i < 1024; i += 512) {
      sp4[i] = make_float4(xc[(bk * 3 + 0) * 1024 + i],
                           xc[(bk * 3 + 1) * 1024 + i],
                           xc[(bk * 3 + 2) * 1024 + i], 0.f);
    }
    if (t < 128) {
      scen4[t] = make_float4(nxyz[(bk * 128 + t) * 3 + 0],
                             nxyz[(bk * 128 + t) * 3 + 1],
                             nxyz[(bk * 128 + t) * 3 + 2], 0.f);
    }
    __syncthreads();

    // ---- ball query: 8 waves x 16 balls from LDS ----
    for (int p = wave * 16; p < wave * 16 + 16; ++p) {
      float4 cen = scen4[p];
      int* outp = bidx + ((size_t)(bk * 128 + p)) * 128;
      int count = 0, first = 0;
      bool got = false;
      for (int ch = 0; ch < 16 && count < 128; ++ch) {
        int m = (ch << 6) + lane;
        float4 pv = sp4[m];
        float d = dist2f(pv.x, pv.y, pv.z, cen.x, cen.y, cen.z);
        bool flag = d < 0.0225f;                 // strict fp32, RADIUS^2
        unsigned long long mask = __ballot(flag);
        if (!got && mask) { first = (ch << 6) + __builtin_ctzll(mask); got = true; }
        int pos = count + (int)__popcll(mask & ((1ull << lane) - 1ull));
        if (flag && pos < 128) outp[pos] = m;
        count += (int)__popcll(mask);
      }
      for (int j = count + lane; j < 128; j += 64) outp[j] = first;
      if (lane == 0) counts[bk * 128 + p] = count > 128 ? 128 : count;
    }
    return;
  }

  if (bid < 342) {
    // ================= w1f: 256 active threads; idle waves match 8 barriers =====
    short* ffrag = (short*)smem;                  // 32KB
    if (t >= 256) {
      for (int i = 0; i < 8; ++i) __syncthreads();
      return;
    }
    int blk = bid - NBK;
    int bk = blk >> 3, m0 = (blk & 7) << 7;
    int b = bk / 19, k = bk % 19;
    int quad = lane >> 4, nl = lane & 15;
    int mloc = t & 127, chalf = t >> 7;
    int st_w = mloc >> 4, sl_w = mloc & 15;
    const float* fbase = feats + ((size_t)(b * 4864 + k)) * 1024 + m0 + mloc;

    f32x4 acc[2][8];
#pragma unroll
    for (int oi = 0; oi < 2; ++oi)
#pragma unroll
      for (int st = 0; st < 8; ++st) acc[oi][st] = (f32x4){0.f, 0.f, 0.f, 0.f};

    for (int ch = 0; ch < 4; ++ch) {
      int cbase = ch * 64 + chalf * 32;
#pragma unroll
      for (int g = 0; g < 4; ++g) {
        float v[8];
#pragma unroll
        for (int j = 0; j < 8; ++j)
          v[j] = fbase[(size_t)(cbase + g * 8 + j) * 19456];
        unsigned sh[8], sm[8];
#pragma unroll
        for (int j = 0; j < 8; ++j) split2rn(v[j], sh[j], sm[j]);
        int base = chalf * 4096 + st_w * 512 + (g * 16 + sl_w) * 8;
        v4i ph = {(int)(sh[0] | (sh[1] << 16)), (int)(sh[2] | (sh[3] << 16)),
                  (int)(sh[4] | (sh[5] << 16)), (int)(sh[6] | (sh[7] << 16))};
        *(v4i*)&ffrag[base] = ph;
        v4i pm = {(int)(sm[0] | (sm[1] << 16)), (int)(sm[2] | (sm[3] << 16)),
                  (int)(sm[4] | (sm[5] << 16)), (int)(sm[6] | (sm[7] << 16))};
        *(v4i*)&ffrag[base + 8192] = pm;
      }
      __syncthreads();
#pragma unroll
      for (int kkl = 0; kkl < 2; ++kkl) {
        int kk = ch * 2 + kkl;
        bf16x8 a[2][2];
#pragma unroll
        for (int oi = 0; oi < 2; ++oi) {
          int o_row = (wave * 2 + oi) * 16 + nl;
          const float* wsrc = m1w + o_row * 259 + 3 + kk * 32 + quad * 8;
          float wv[8];
#pragma unroll
          for (int j = 0; j < 8; ++j) wv[j] = wsrc[j];
          unsigned sh[8], sm[8];
#pragma unroll
          for (int j = 0; j < 8; ++j) split2rn(wv[j], sh[j], sm[j]);
          short ah[8], am[8];
#pragma unroll
          for (int j = 0; j < 8; ++j) { ah[j] = (short)sh[j]; am[j] = (short)sm[j]; }
          a[oi][0] = (bf16x8){ah[0], ah[1], ah[2], ah[3], ah[4], ah[5], ah[6], ah[7]};
          a[oi][1] = (bf16x8){am[0], am[1], am[2], am[3], am[4], am[5], am[6], am[7]};
        }
#pragma unroll
        for (int st = 0; st < 8; ++st) {
          const short* hb = ffrag + kkl * 4096 + st * 512 + lane * 8;
          bf16x8 b0 = *(const bf16x8*)hb;
          bf16x8 b1 = *(const bf16x8*)(hb + 8192);
#pragma unroll
          for (int oi = 0; oi < 2; ++oi) {
            f32x4 c = acc[oi][st];
            c = __builtin_amdgcn_mfma_f32_16x16x32_bf16(a[oi][1], b0, c, 0, 0, 0);
            c = __builtin_amdgcn_mfma_f32_16x16x32_bf16(a[oi][0], b1, c, 0, 0, 0);
            c = __builtin_amdgcn_mfma_f32_16x16x32_bf16(a[oi][0], b0, c, 0, 0, 0);
            acc[oi][st] = c;
          }
        }
      }
      __syncthreads();
    }
    float inv = 1.0f / sqrtf(1.0f + 1e-5f);
#pragma unroll
    for (int oi = 0; oi < 2; ++oi) {
      int o0 = (wave * 2 + oi) * 16 + quad * 4;
      float4 bb = *(const float4*)&m1b[o0];
      float4 gg = *(const float4*)&m1g[o0];
#pragma unroll
      for (int st = 0; st < 8; ++st) {
        int m_out = m0 + st * 16 + nl;
        f32x4 cc = acc[oi][st];
        float4 r;
        r.x = (cc[0] + bb.x) * (gg.x * inv);
        r.y = (cc[1] + bb.y) * (gg.y * inv);
        r.z = (cc[2] + bb.z) * (gg.z * inv);
        r.w = (cc[3] + bb.w) * (gg.w * inv);
        *(float4*)&W1f[((size_t)(bk * 1024 + m_out)) * 128 + o0] = r;
      }
    }
    return;
  }

  if (bid < 358) {
    // ================= w2/w3 split =================
    int idx = (bid - 342) * 512 + t;               // 0..8191
#pragma unroll
    for (int e = 0; e < 4; ++e) {
      int i = idx * 4 + e;                         // 0..32767
      int c = i & 127, o = (i >> 7) & 127, l = i >> 14;
      float w = (l ? m3w : m2w)[o * 128 + c];
      unsigned sh, sm;
      split2rn(w, sh, sm);
      int ot = o >> 4, mm = o & 15, kk = c >> 5, q = (c & 31) >> 3, j = c & 7;
      int within = (q * 16 + mm) * 8 + j;
      Wf[(((l * 2 + 0) * 4 + kk) * 8 + ot) * 512 + within] = (short)sh;
      Wf[(((l * 2 + 1) * 4 + kk) * 8 + ot) * 512 + within] = (short)sm;
    }
    return;
  }

  if (bid < 374) {
    // ================= c1/c2 split =================
    int idx2 = (bid - 358) * 512 + t;              // 0..8191
#pragma unroll
    for (int e = 0; e < 4; ++e) {
      int i = idx2 * 4 + e;                        // 0..32767
      int c = i & 127, o = (i >> 7) & 127, l = i >> 14;
      float w = (l ? c2w : c1w)[o * 128 + c];
      unsigned sh, sm;
      split2rn(w, sh, sm);
      int ot = o >> 4, mm = o & 15, kk = c >> 5, q = (c & 31) >> 3, j = c & 7;
      int within = (q * 16 + mm) * 8 + j;
      Wf[131072 + (((l * 2 + 0) * 4 + kk) * 8 + ot) * 512 + within] = (short)sh;
      Wf[131072 + (((l * 2 + 1) * 4 + kk) * 8 + ot) * 512 + within] = (short)sm;
    }
    return;
  }

  // ================= prep constants =================
  if (t < 128) {
    float inv = 1.0f / sqrtf(1.0f + 1e-5f);
    float a1 = m1g[t] * inv;
    prep[t] = a1;
    float a2 = m2g[t] * inv;  prep[256 + t] = a2;  prep[384 + t] = fmaf(m2b[t], a2, m2be[t]);
    float a3 = m3g[t] * inv;  prep[512 + t] = a3;  prep[640 + t] = fmaf(m3b[t], a3, m3be[t]);
    float ac1 = c1g[t] * inv; prep[768 + t] = ac1; prep[896 + t] = fmaf(c1b[t], ac1, c1be[t]);
    float ac2 = c2g[t] * inv; prep[1024 + t] = ac2; prep[1152 + t] = fmaf(c2b[t], ac2, c2be[t]);
    prep[1280 + 4 * t + 0] = m1w[t * 259 + 0] * a1;
    prep[1280 + 4 * t + 1] = m1w[t * 259 + 1] * a1;
    prep[1280 + 4 * t + 2] = m1w[t * 259 + 2] * a1;
    prep[1280 + 4 * t + 3] = m1be[t];
  }
}

// ---------------- MFMA GEMM over one 128(c) x nst_h*16(s) fragment buffer ----------
__device__ __forceinline__ void mfma_layer(const short* __restrict__ Wf,
                                           const short* hfrag, int l,
                                           int wave, int lane, int nst_h,
                                           f32x4 acc[2][4])
{
#pragma unroll 1
  for (int kk = 0; kk < 4; ++kk) {
    bf16x8 a[2][2];
#pragma unroll
    for (int oi = 0; oi < 2; ++oi)
#pragma unroll
      for (int sp = 0; sp < 2; ++sp)
        a[oi][sp] = *(const bf16x8*)(Wf + (((l * 2 + sp) * 4 + kk) * 8 + (wave * 2 + oi)) * 512 + lane * 8);
    for (int st = 0; st < nst_h; ++st) {
      const short* hb = hfrag + kk * 2048 + st * 512 + lane * 8;
      bf16x8 b0 = *(const bf16x8*)(hb);           // hi
      bf16x8 b1 = *(const bf16x8*)(hb + 8192);    // mid
#pragma unroll
      for (int oi = 0; oi < 2; ++oi) {
        f32x4 c = acc[oi][st];
        c = __builtin_amdgcn_mfma_f32_16x16x32_bf16(a[oi][1], b0, c, 0, 0, 0);
        c = __builtin_amdgcn_mfma_f32_16x16x32_bf16(a[oi][0], b1, c, 0, 0, 0);
        c = __builtin_amdgcn_mfma_f32_16x16x32_bf16(a[oi][0], b0, c, 0, 0, 0);
        acc[oi][st] = c;
      }
    }
  }
}

// ---------------- fused SA: 4 balls per block, tiles packed over passes ----------
__global__ __launch_bounds__(256, 3) void sa_kernel(
    const float* __restrict__ xc, const float* __restrict__ nxyz,
    const int* __restrict__ bidx, const int* __restrict__ counts,
    const float* __restrict__ W1f, const float* __restrict__ prep,
    const short* __restrict__ Wf, float* __restrict__ feat_out)
{
  __shared__ __align__(16) short hfrag[16384];   // 32KB
  __shared__ float pcs[512];
  __shared__ float sm[32 * 128];                 // 16KB per-tile o-max
  __shared__ float ccen[12];
  __shared__ int scnt[4];
  int gb = blockIdx.x, bk = gb >> 5, pb = (gb & 31) << 2;
  int t = threadIdx.x;
  int wave = t >> 6, lane = t & 63;
  int quad = lane >> 4, nl = lane & 15;

  pcs[t] = prep[1280 + t];
  pcs[256 + t] = prep[1536 + t];
  if (t < 4) scnt[t] = counts[bk * 128 + pb + t];
  if (t < 12) {
    int bb = t / 3, c = t % 3;
    ccen[t] = nxyz[(bk * 128 + pb + bb) * 3 + c];
  }
  __syncthreads();
  int n0 = (scnt[0] + 15) >> 4, n1 = (scnt[1] + 15) >> 4;
  int n2 = (scnt[2] + 15) >> 4, n3 = (scnt[3] + 15) >> 4;
  int pf1 = n0, pf2 = n0 + n1, pf3 = n0 + n1 + n2, T = n0 + n1 + n2 + n3;

  for (int q0 = 0; q0 < T; q0 += 4) {
    int nst_h = T - q0;
    if (nst_h > 4) nst_h = 4;
    // ---- h1 build ----
    {
      int cg = wave;
      int st = lane >> 4, sl = lane & 15;
      if (st < nst_h) {
        int q = q0 + st;
        int bq = (q >= pf1) + (q >= pf2) + (q >= pf3);
        int tstart = (bq == 0) ? 0 : (bq == 1) ? pf1 : (bq == 2) ? pf2 : pf3;
        int tslot = q - tstart;
        int m = bidx[((size_t)(bk * 128 + pb + bq)) * 128 + tslot * 16 + sl];
        float cen0 = ccen[bq * 3 + 0], cen1 = ccen[bq * 3 + 1], cen2 = ccen[bq * 3 + 2];
        float g0 = (xc[(bk * 3 + 0) * 1024 + m] - cen0) * (1.0f / 0.15f);
        float g1 = (xc[(bk * 3 + 1) * 1024 + m] - cen1) * (1.0f / 0.15f);
        float g2 = (xc[(bk * 3 + 2) * 1024 + m] - cen2) * (1.0f / 0.15f);
        const float4* wrow = (const float4*)(W1f + ((size_t)(bk * 1024 + m)) * 128 + cg * 32);
        const float4* pcp = (const float4*)pcs + cg * 32;
#pragma unroll
        for (int g = 0; g < 4; ++g) {
          float4 wva = wrow[g * 2], wvb = wrow[g * 2 + 1];
          float wv[8] = {wva.x, wva.y, wva.z, wva.w, wvb.x, wvb.y, wvb.z, wvb.w};
          unsigned sh[8], smv[8];
#pragma unroll
          for (int e = 0; e < 8; ++e) {
            float4 pc = pcp[g * 8 + e];
            float hv = fmaxf(wv[e] + pc.x * g0 + pc.y * g1 + pc.z * g2 + pc.w, 0.f);
            split2rn(hv, sh[e], smv[e]);
          }
          int base = (cg * 4 + st) * 512 + (g * 16 + sl) * 8;
          v4i ph = {(int)(sh[0] | (sh[1] << 16)), (int)(sh[2] | (sh[3] << 16)),
                    (int)(sh[4] | (sh[5] << 16)), (int)(sh[6] | (sh[7] << 16))};
          *(v4i*)&hfrag[base] = ph;
          v4i pm = {(int)(smv[0] | (smv[1] << 16)), (int)(smv[2] | (smv[3] << 16)),
                    (int)(smv[4] | (smv[5] << 16)), (int)(smv[6] | (smv[7] << 16))};
          *(v4i*)&hfrag[base + 8192] = pm;
        }
      }
    }
    __syncthreads();

    // ---- layer 2 ----
    f32x4 acc[2][4];
#pragma unroll
    for (int oi = 0; oi < 2; ++oi)
#pragma unroll
      for (int st = 0; st < 4; ++st) acc[oi][st] = (f32x4){0.f, 0.f, 0.f, 0.f};
    mfma_layer(Wf, hfrag, 0, wave, lane, nst_h, acc);
    __syncthreads();

    // ---- h2 epilogue ----
#pragma unroll
    for (int oi = 0; oi < 2; ++oi) {
      int o0 = (wave * 2 + oi) * 16 + quad * 4;
      float4 al = *(const float4*)&prep[256 + o0];
      float4 be = *(const float4*)&prep[384 + o0];
      int kk2 = o0 >> 5, g2 = (o0 & 31) >> 3, j0 = o0 & 7;
      for (int st = 0; st < nst_h; ++st) {
        f32x4 cc = acc[oi][st];
        float v0 = fmaxf(fmaf(cc[0], al.x, be.x), 0.f);
        float v1 = fmaxf(fmaf(cc[1], al.y, be.y), 0.f);
        float v2 = fmaxf(fmaf(cc[2], al.z, be.z), 0.f);
        float v3 = fmaxf(fmaf(cc[3], al.w, be.w), 0.f);
        unsigned h0, m0_, h1, m1_, h2, m2_, h3, m3_;
        split2rn(v0, h0, m0_); split2rn(v1, h1, m1_);
        split2rn(v2, h2, m2_); split2rn(v3, h3, m3_);
        int base = (kk2 * 4 + st) * 512 + (g2 * 16 + nl) * 8 + j0;
        v2i w0 = {(int)(h0 | (h1 << 16)), (int)(h2 | (h3 << 16))};
        *(v2i*)&hfrag[base] = w0;
        v2i w1 = {(int)(m0_ | (m1_ << 16)), (int)(m2_ | (m3_ << 16))};
        *(v2i*)&hfrag[base + 8192] = w1;
      }
    }
    __syncthreads();

    // ---- layer 3 ----
#pragma unroll
    for (int oi = 0; oi < 2; ++oi)
#pragma unroll
      for (int st = 0; st < 4; ++st) acc[oi][st] = (f32x4){0.f, 0.f, 0.f, 0.f};
    mfma_layer(Wf, hfrag, 1, wave, lane, nst_h, acc);

    // ---- layer-3 epilogue: BN+ReLU, quad-reduce max per tile ----
#pragma unroll
    for (int oi = 0; oi < 2; ++oi) {
      int o0 = (wave * 2 + oi) * 16 + quad * 4;
      float4 al = *(const float4*)&prep[512 + o0];
      float4 be = *(const float4*)&prep[640 + o0];
      for (int st = 0; st < nst_h; ++st) {
        f32x4 cc = acc[oi][st];
        float v[4];
        v[0] = fmaxf(fmaf(cc[0], al.x, be.x), 0.f);
        v[1] = fmaxf(fmaf(cc[1], al.y, be.y), 0.f);
        v[2] = fmaxf(fmaf(cc[2], al.z, be.z), 0.f);
        v[3] = fmaxf(fmaf(cc[3], al.w, be.w), 0.f);
#pragma unroll
        for (int r = 0; r < 4; ++r) {
          float x = v[r];
          x = fmaxf(x, __shfl_xor(x, 1));
          x = fmaxf(x, __shfl_xor(x, 2));
          x = fmaxf(x, __shfl_xor(x, 4));
          x = fmaxf(x, __shfl_xor(x, 8));
          if (nl == 0) sm[(q0 + st) * 128 + o0 + r] = x;
        }
      }
    }
    __syncthreads();
  }

  // ---- final: merge tiles per ball, write feat ----
#pragma unroll
  for (int e = t; e < 512; e += 256) {
    int bb = e >> 7, o = e & 127;
    int qs = (bb == 0) ? 0 : (bb == 1) ? pf1 : (bb == 2) ? pf2 : pf3;
    int nq = (bb == 0) ? n0 : (bb == 1) ? n1 : (bb == 2) ? n2 : n3;
    float v = sm[qs * 128 + o];
    for (int q = 1; q < nq; ++q) v = fmaxf(v, sm[(qs + q) * 128 + o]);
    feat_out[(((size_t)bk) << 14) + (o << 7) + pb + bb] = v;
  }
}

// ---------------- head: c1 -> c2 (split2 MFMA) -> op -> scores; 2 blocks/bk ------
__global__ __launch_bounds__(256) void head_kernel(const float* __restrict__ featg,
    const float* __restrict__ prep, const short* __restrict__ Wf,
    const float* __restrict__ nxyz, const float* __restrict__ opw,
    const float* __restrict__ opb, float* __restrict__ scores)
{
  __shared__ __align__(16) short hfrag[16384];   // 32KB frags (128c x 64p)
  __shared__ float hplain[128 * 65];             // stride 65 vs conflicts
  int bk = blockIdx.x >> 1, p0 = (blockIdx.x & 1) << 6;
  int t = threadIdx.x;
  int wave = t >> 6, lane = t & 63;
  int quad = lane >> 4, nl = lane & 15;
  const short* WC = Wf + 131072;

  // ---- stage feat[c][p0..p0+63] into split2 B-frags ----
  {
    int cg = wave;
    int st = lane >> 4, sl = lane & 15;
    const float* fb = featg + (bk << 14) + p0 + lane;
#pragma unroll
    for (int g = 0; g < 4; ++g) {
      float v[8];
#pragma unroll
      for (int e = 0; e < 8; ++e)
        v[e] = fb[(cg * 32 + g * 8 + e) << 7];
      unsigned sh[8], sm[8];
#pragma unroll
      for (int e = 0; e < 8; ++e) split2rn(v[e], sh[e], sm[e]);
      int base = (cg * 4 + st) * 512 + (g * 16 + sl) * 8;
      v4i ph = {(int)(sh[0] | (sh[1] << 16)), (int)(sh[2] | (sh[3] << 16)),
                (int)(sh[4] | (sh[5] << 16)), (int)(sh[6] | (sh[7] << 16))};
      *(v4i*)&hfrag[base] = ph;
      v4i pm = {(int)(sm[0] | (sm[1] << 16)), (int)(sm[2] | (sm[3] << 16)),
                (int)(sm[4] | (sm[5] << 16)), (int)(sm[6] | (sm[7] << 16))};
      *(v4i*)&hfrag[base + 8192] = pm;
    }
  }
  __syncthreads();

  // ---- c1 ----
  f32x4 acc[2][4];
#pragma unroll
  for (int oi = 0; oi < 2; ++oi)
#pragma unroll
    for (int st = 0; st < 4; ++st) acc[oi][st] = (f32x4){0.f, 0.f, 0.f, 0.f};
  mfma_layer(WC, hfrag, 0, wave, lane, 4, acc);
  __syncthreads();

  // ---- c1 epilogue: BN+ReLU, write back frags ----
#pragma unroll
  for (int oi = 0; oi < 2; ++oi) {
    int o0 = (wave * 2 + oi) * 16 + quad * 4;
    float4 al = *(const float4*)&prep[768 + o0];
    float4 be = *(const float4*)&prep[896 + o0];
    int kk2 = o0 >> 5, g2 = (o0 & 31) >> 3, j0 = o0 & 7;
#pragma unroll
    for (int st = 0; st < 4; ++st) {
      f32x4 cc = acc[oi][st];
      float v0 = fmaxf(fmaf(cc[0], al.x, be.x), 0.f);
      float v1 = fmaxf(fmaf(cc[1], al.y, be.y), 0.f);
      float v2 = fmaxf(fmaf(cc[2], al.z, be.z), 0.f);
      float v3 = fmaxf(fmaf(cc[3], al.w, be.w), 0.f);
      unsigned h0, m0_, h1, m1_, h2, m2_, h3, m3_;
      split2rn(v0, h0, m0_); split2rn(v1, h1, m1_);
      split2rn(v2, h2, m2_); split2rn(v3, h3, m3_);
      int base = (kk2 * 4 + st) * 512 + (g2 * 16 + nl) * 8 + j0;
      v2i w0 = {(int)(h0 | (h1 << 16)), (int)(h2 | (h3 << 16))};
      *(v2i*)&hfrag[base] = w0;
      v2i w1 = {(int)(m0_ | (m1_ << 16)), (int)(m2_ | (m3_ << 16))};
      *(v2i*)&hfrag[base + 8192] = w1;
    }
  }
  __syncthreads();

  // ---- c2 ----
#pragma unroll
  for (int oi = 0; oi < 2; ++oi)
#pragma unroll
    for (int st = 0; st < 4; ++st) acc[oi][st] = (f32x4){0.f, 0.f, 0.f, 0.f};
  mfma_layer(WC, hfrag, 1, wave, lane, 4, acc);

  // ---- c2 epilogue: BN+ReLU -> hplain[c][p] ----
#pragma unroll
  for (int oi = 0; oi < 2; ++oi) {
    int o0 = (wave * 2 + oi) * 16 + quad * 4;
    float4 al = *(const float4*)&prep[1024 + o0];
    float4 be = *(const float4*)&prep[1152 + o0];
#pragma unroll
    for (int st = 0; st < 4; ++st) {
      f32x4 cc = acc[oi][st];
      int p = st * 16 + nl;
      hplain[(o0 + 0) * 65 + p] = fmaxf(fmaf(cc[0], al.x, be.x), 0.f);
      hplain[(o0 + 1) * 65 + p] = fmaxf(fmaf(cc[1], al.y, be.y), 0.f);
      hplain[(o0 + 2) * 65 + p] = fmaxf(fmaf(cc[2], al.z, be.z), 0.f);
      hplain[(o0 + 3) * 65 + p] = fmaxf(fmaf(cc[3], al.w, be.w), 0.f);
    }
  }
  __syncthreads();

  // ---- op head + scores ----
  if (t < 64) {
    int p = t, k = bk % 19;
    float res[5];
#pragma unroll
    for (int j = 0; j < 5; ++j) {
      const float* wr = opw + ((size_t)(k * 5 + j)) * 128;
      float a = opb[k * 5 + j];
      for (int c = 0; c < 128; ++c) a = fmaf(wr[c], hplain[c * 65 + p], a);
      res[j] = a;
    }
    int pg = p0 + p;
    float a0 = nxyz[(bk * 128 + pg) * 3 + 0];
    float a1 = nxyz[(bk * 128 + pg) * 3 + 1];
    float a2 = nxyz[(bk * 128 + pg) * 3 + 2];
    float* sc = scores + ((size_t)(bk * 128 + pg)) * 5;
    sc[0] = res[0];
    sc[1] = res[1];
    sc[2] = a0 + res[2];
    sc[3] = a1 + res[3];
    sc[4] = a2 + res[4];
  }
}

extern "C" void kernel_launch(void* const* d_in, const int* in_sizes, int n_in,
                              void* d_out, int out_size, void* d_ws, size_t ws_size,
                              hipStream_t stream) {
  (void)in_sizes; (void)n_in; (void)out_size; (void)ws_size;
  const float* xyz  = (const float*)d_in[0];
  const float* fts  = (const float*)d_in[1];
  const float* m1w  = (const float*)d_in[2];
  const float* m1b  = (const float*)d_in[3];
  const float* m1g  = (const float*)d_in[4];
  const float* m1be = (const float*)d_in[5];
  const float* m2w  = (const float*)d_in[6];
  const float* m2b  = (const float*)d_in[7];
  const float* m2g  = (const float*)d_in[8];
  const float* m2be = (const float*)d_in[9];
  const float* m3w  = (const float*)d_in[10];
  const float* m3b  = (const float*)d_in[11];
  const float* m3g  = (const float*)d_in[12];
  const float* m3be = (const float*)d_in[13];
  const float* c1w  = (const float*)d_in[14];
  const float* c1b  = (const float*)d_in[15];
  const float* c1g  = (const float*)d_in[16];
  const float* c1be = (const float*)d_in[17];
  const float* c2w  = (const float*)d_in[18];
  const float* c2b  = (const float*)d_in[19];
  const float* c2g  = (const float*)d_in[20];
  const float* c2be = (const float*)d_in[21];
  const float* opw  = (const float*)d_in[22];
  const float* opb  = (const float*)d_in[23];

  float* out = (float*)d_out;
  char* ws = (char*)d_ws;
  float* xc   = (float*)(ws + OFF_XC);
  float* nxyz = (float*)(ws + OFF_NXYZ);
  int*   bidx = (int*)(ws + OFF_BIDX);
  float* W1f  = (float*)(ws + OFF_W1F);
  float* prep = (float*)(ws + OFF_PREP);
  short* Wf   = (short*)(ws + OFF_WF);
  int*   cnt  = (int*)(ws + OFF_CNT);

  hipLaunchKernelGGL(fps_kernel, dim3(NBK), dim3(256), 0, stream,
                     xyz, xc, nxyz, out + OUT_AGG);
  hipLaunchKernelGGL(front_kernel, dim3(375), dim3(512), 0, stream,
                     xyz, fts, m1w, m1b, m1g, m1be, m2w, m2b, m2g, m2be,
                     m3w, m3b, m3g, m3be, c1w, c1b, c1g, c1be,
                     c2w, c2b, c2g, c2be,
                     xc, nxyz, bidx, cnt, W1f, Wf, prep);
  hipLaunchKernelGGL(sa_kernel, dim3(NBK * 32), dim3(256), 0, stream,
                     xc, nxyz, bidx, cnt, W1f, prep, Wf, out + OUT_FEAT);
  hipLaunchKernelGGL(head_kernel, dim3(NBK * 2), dim3(256), 0, stream,
                     out + OUT_FEAT, prep, Wf, nxyz, opw, opb, out);
}

// Round 4
// 291.140 us; speedup vs baseline: 2.1461x; 2.1461x over previous
//
#include <hip/hip_runtime.h>
#include <math.h>

// ---------------- problem constants ----------------
// B=2, K=19 -> BK=38 batches; M=1024 points; C=256 feat ch; NPOINT=NSAMPLE=128
#define NBK   38

// ---------------- workspace layout (bytes) ----------------
#define OFF_XC    0u          // [38][3][1024] f32        = 466944
#define OFF_NXYZ  466944u     // [38][128][3]  f32        = 58368
#define OFF_BIDX  525312u     // [38][128][128] i32       = 2490368
#define OFF_W1F   3015680u    // [38][1024][128] f32      = 19922944
#define OFF_PREP  22938624u   // 4096 f32
#define OFF_WF    22955008u   // 196608 shorts: w2/w3 (0), unused (65536), c1/c2 (131072)
#define OFF_CNT   23348224u   // [38][128] i32 ball counts = 19456

// ---------------- d_out layout (float offsets) ----------------
#define OUT_AGG   24320       // scores at 0: (2,19,128,5)
#define OUT_FEAT  38912       // agg: (2,19,128,3), feat: (2,19,128,128)

typedef short bf16x8 __attribute__((ext_vector_type(8)));   // 8 bf16 = 4 VGPR
typedef float f32x4  __attribute__((ext_vector_type(4)));
typedef int   v4i    __attribute__((ext_vector_type(4)));
typedef int   v2i    __attribute__((ext_vector_type(2)));

// exact IEEE fp32 squared distance, no FMA contraction, ((d0^2+d1^2)+d2^2)
__device__ __forceinline__ float dist2f(float a0, float a1, float a2,
                                        float b0, float b1, float b2) {
#pragma clang fp contract(off)
  float d0 = a0 - b0;
  float d1 = a1 - b1;
  float d2 = a2 - b2;
  return d0 * d0 + d1 * d1 + d2 * d2;
}

// 2-way bf16 split with round-to-nearest-even: v ~= hi + mid, residual <= 2^-18 |v|
__device__ __forceinline__ void split2rn(float v, unsigned& sh, unsigned& sm) {
  unsigned u = __float_as_uint(v);
  unsigned rh = (u + 0x7fffu + ((u >> 16) & 1u)) & 0xffff0000u;
  sh = rh >> 16;
  float r1 = v - __uint_as_float(rh);        // exact in fp32
  unsigned u1 = __float_as_uint(r1);
  unsigned rm = (u1 + 0x7fffu + ((u1 >> 16) & 1u)) & 0xffff0000u;
  sm = rm >> 16;
}

// DPP fmax step: v = fmax(v, v shifted by ctrl); invalid lanes keep own value.
#define DPP_FMAX_STEP(v, ctrl)                                                 \
  {                                                                            \
    int _s = __builtin_amdgcn_update_dpp(__float_as_int(v), __float_as_int(v), \
                                         (ctrl), 0xf, 0xf, false);             \
    (v) = fmaxf((v), __int_as_float(_s));                                      \
  }

__device__ __forceinline__ float readlane_f(float v, int l) {
  return __int_as_float(__builtin_amdgcn_readlane(__float_as_int(v), l));
}

// ---------------- dedicated fps kernel: 38 blocks x 128 threads (2 waves) ----
// Each lane owns 8 contiguous points (m = wave*512 + lane*8 + j): live set
// ~45 VGPRs fits the 64-reg budget -> no LDS-remat on the serial chain.
// Cross-wave candidate exchange via double-buffered LDS slot, 1 barrier/iter.
__global__ __launch_bounds__(128, 1) void fps_kernel(
    const float* __restrict__ xyz, float* __restrict__ xc,
    float* __restrict__ nxyz, float* __restrict__ agg)
{
  __shared__ __align__(16) float4 sp4[1024];   // 16KB points
  __shared__ int2 cexch[2][2];                 // [parity][wave] = (dist bits, m)
  __shared__ int sfar[128];
  int bk = blockIdx.x;
  int b = bk / 19, k = bk % 19;
  int t = threadIdx.x, lane = t & 63, wave = t >> 6;

  // stage points into LDS + write the transposed xc copy (2 waves, 8 iters)
  for (int i = t; i < 1024; i += 128) {
    const float* src = xyz + ((size_t)((b * 1024 + i) * 19 + k)) * 3;
    float x0 = src[0], x1 = src[1], x2 = src[2];
    sp4[i] = make_float4(x0, x1, x2, 0.f);
    xc[(bk * 3 + 0) * 1024 + i] = x0;
    xc[(bk * 3 + 1) * 1024 + i] = x1;
    xc[(bk * 3 + 2) * 1024 + i] = x2;
  }
  if (t == 0) sfar[0] = 0;
  __syncthreads();

  // lane-local points: m = wave*512 + lane*8 + j (contiguous => ctz/left-wins
  // tie-breaking reproduces jnp.argmax first-max exactly)
  float px[8], py[8], pz[8], dist[8];
  int mbase = (wave << 9) + (lane << 3);
#pragma unroll
  for (int j = 0; j < 8; ++j) {
    float4 p = sp4[mbase + j];
    px[j] = p.x; py[j] = p.y; pz[j] = p.z;
    dist[j] = 1e10f;
  }

  int far = 0;
  for (int it = 1; it < 128; ++it) {
    float4 c = sp4[far];                       // uniform-address b128 read
#pragma unroll
    for (int j = 0; j < 8; ++j) {
      float d = dist2f(px[j], py[j], pz[j], c.x, c.y, c.z);
      dist[j] = fminf(dist[j], d);
    }
    // local first-max tree over 8 (>= keeps left => smallest j on ties)
    float tv[4]; int tj[4];
#pragma unroll
    for (int i = 0; i < 4; ++i) {
      bool L = dist[2 * i] >= dist[2 * i + 1];
      tv[i] = L ? dist[2 * i] : dist[2 * i + 1];
      tj[i] = L ? (2 * i) : (2 * i + 1);
    }
    {
      bool L0 = tv[0] >= tv[1];
      float v0 = L0 ? tv[0] : tv[1]; int j0 = L0 ? tj[0] : tj[1];
      bool L1 = tv[2] >= tv[3];
      float v1 = L1 ? tv[2] : tv[3]; int j1 = L1 ? tj[2] : tj[3];
      bool L = v0 >= v1;
      tv[0] = L ? v0 : v1; tj[0] = L ? j0 : j1;
    }
    float lmax = tv[0];
    // in-row max via DPP row_shr: lanes 15/31/47/63 hold row maxes
    float g = lmax;
    DPP_FMAX_STEP(g, 0x111);   // row_shr:1
    DPP_FMAX_STEP(g, 0x112);   // row_shr:2
    DPP_FMAX_STEP(g, 0x114);   // row_shr:4
    DPP_FMAX_STEP(g, 0x118);   // row_shr:8
    float r0 = readlane_f(g, 15);
    float r1 = readlane_f(g, 31);
    float r2 = readlane_f(g, 47);
    float r3 = readlane_f(g, 63);
    float gmax = fmaxf(fmaxf(r0, r1), fmaxf(r2, r3));
    // smallest lane whose local max equals the wave max
    unsigned long long mk = __ballot(lmax == gmax);
    int wl = (int)__builtin_ctzll(mk);
    int lj = (lane << 3) + tj[0];
    int cand_m = (wave << 9) + __builtin_amdgcn_readlane(lj, wl);
    if (lane == 0) cexch[it & 1][wave] = make_int2(__float_as_int(gmax), cand_m);
    __syncthreads();
    int2 c0 = cexch[it & 1][0];
    int2 c1 = cexch[it & 1][1];
    // wave0 wins ties (owns smaller indices)
    far = (__int_as_float(c1.x) > __int_as_float(c0.x)) ? c1.y : c0.y;
    if (t == 0) sfar[it] = far;
  }
  __syncthreads();

  // flush centers from recorded indices
  if (t < 128) {
    float4 c = sp4[sfar[t]];
    nxyz[bk * 384 + t * 3 + 0] = c.x;
    nxyz[bk * 384 + t * 3 + 1] = c.y;
    nxyz[bk * 384 + t * 3 + 2] = c.z;
    agg[bk * 384 + t * 3 + 0] = c.x;
    agg[bk * 384 + t * 3 + 1] = c.y;
    agg[bk * 384 + t * 3 + 2] = c.z;
  }
}

// ---------------- K1 "front" (512-thread blocks) ----------------
// blocks 0..37: ball query (points re-staged from xc, centers from nxyz);
// 38..341: w1f (256 active threads); 342..357: w2/w3 split;
// 358..373: c1/c2 split; 374: prep constants.
__global__ __launch_bounds__(512, 2) void front_kernel(
    const float* __restrict__ xyz, const float* __restrict__ feats,
    const float* __restrict__ m1w, const float* __restrict__ m1b,
    const float* __restrict__ m1g, const float* __restrict__ m1be,
    const float* __restrict__ m2w, const float* __restrict__ m2b,
    const float* __restrict__ m2g, const float* __restrict__ m2be,
    const float* __restrict__ m3w, const float* __restrict__ m3b,
    const float* __restrict__ m3g, const float* __restrict__ m3be,
    const float* __restrict__ c1w, const float* __restrict__ c1b,
    const float* __restrict__ c1g, const float* __restrict__ c1be,
    const float* __restrict__ c2w, const float* __restrict__ c2b,
    const float* __restrict__ c2g, const float* __restrict__ c2be,
    float* __restrict__ xc, float* __restrict__ nxyz,
    int* __restrict__ bidx, int* __restrict__ counts,
    float* __restrict__ W1f, short* __restrict__ Wf, float* __restrict__ prep)
{
  __shared__ __align__(16) char smem[32768];
  int bid = blockIdx.x, t = threadIdx.x;
  int wave = t >> 6, lane = t & 63;

  if (bid < NBK) {
    // ================= ball query only (fps already done) =================
    int bk = bid;
    float4* sp4 = (float4*)smem;                    // 1024 float4 = 16KB
    float4* scen4 = (float4*)(smem + 16384);        // 128 float4 = 2KB

    for (int i = t; i < 1024; i += 512) {
      sp4[i] = make_float4(xc[(bk * 3 + 0) * 1024 + i],
                           xc[(bk * 3 + 1) * 1024 + i],
                           xc[(bk * 3 + 2) * 1024 + i], 0.f);
    }
    if (t < 128) {
      scen4[t] = make_float4(nxyz[(bk * 128 + t) * 3 + 0],
                             nxyz[(bk * 128 + t) * 3 + 1],
                             nxyz[(bk * 128 + t) * 3 + 2], 0.f);
    }
    __syncthreads();

    // ---- ball query: 8 waves x 16 balls from LDS ----
    for (int p = wave * 16; p < wave * 16 + 16; ++p) {
      float4 cen = scen4[p];
      int* outp = bidx + ((size_t)(bk * 128 + p)) * 128;
      int count = 0, first = 0;
      bool got = false;
      for (int ch = 0; ch < 16 && count < 128; ++ch) {
        int m = (ch << 6) + lane;
        float4 pv = sp4[m];
        float d = dist2f(pv.x, pv.y, pv.z, cen.x, cen.y, cen.z);
        bool flag = d < 0.0225f;                 // strict fp32, RADIUS^2
        unsigned long long mask = __ballot(flag);
        if (!got && mask) { first = (ch << 6) + __builtin_ctzll(mask); got = true; }
        int pos = count + (int)__popcll(mask & ((1ull << lane) - 1ull));
        if (flag && pos < 128) outp[pos] = m;
        count += (int)__popcll(mask);
      }
      for (int j = count + lane; j < 128; j += 64) outp[j] = first;
      if (lane == 0) counts[bk * 128 + p] = count > 128 ? 128 : count;
    }
    return;
  }

  if (bid < 342) {
    // ================= w1f: 256 active threads; idle waves match 8 barriers =====
    short* ffrag = (short*)smem;                  // 32KB
    if (t >= 256) {
      for (int i = 0; i < 8; ++i) __syncthreads();
      return;
    }
    int blk = bid - NBK;
    int bk = blk >> 3, m0 = (blk & 7) << 7;
    int b = bk / 19, k = bk % 19;
    int quad = lane >> 4, nl = lane & 15;
    int mloc = t & 127, chalf = t >> 7;
    int st_w = mloc >> 4, sl_w = mloc & 15;
    const float* fbase = feats + ((size_t)(b * 4864 + k)) * 1024 + m0 + mloc;

    f32x4 acc[2][8];
#pragma unroll
    for (int oi = 0; oi < 2; ++oi)
#pragma unroll
      for (int st = 0; st < 8; ++st) acc[oi][st] = (f32x4){0.f, 0.f, 0.f, 0.f};

    for (int ch = 0; ch < 4; ++ch) {
      int cbase = ch * 64 + chalf * 32;
#pragma unroll
      for (int g = 0; g < 4; ++g) {
        float v[8];
#pragma unroll
        for (int j = 0; j < 8; ++j)
          v[j] = fbase[(size_t)(cbase + g * 8 + j) * 19456];
        unsigned sh[8], sm[8];
#pragma unroll
        for (int j = 0; j < 8; ++j) split2rn(v[j], sh[j], sm[j]);
        int base = chalf * 4096 + st_w * 512 + (g * 16 + sl_w) * 8;
        v4i ph = {(int)(sh[0] | (sh[1] << 16)), (int)(sh[2] | (sh[3] << 16)),
                  (int)(sh[4] | (sh[5] << 16)), (int)(sh[6] | (sh[7] << 16))};
        *(v4i*)&ffrag[base] = ph;
        v4i pm = {(int)(sm[0] | (sm[1] << 16)), (int)(sm[2] | (sm[3] << 16)),
                  (int)(sm[4] | (sm[5] << 16)), (int)(sm[6] | (sm[7] << 16))};
        *(v4i*)&ffrag[base + 8192] = pm;
      }
      __syncthreads();
#pragma unroll
      for (int kkl = 0; kkl < 2; ++kkl) {
        int kk = ch * 2 + kkl;
        bf16x8 a[2][2];
#pragma unroll
        for (int oi = 0; oi < 2; ++oi) {
          int o_row = (wave * 2 + oi) * 16 + nl;
          const float* wsrc = m1w + o_row * 259 + 3 + kk * 32 + quad * 8;
          float wv[8];
#pragma unroll
          for (int j = 0; j < 8; ++j) wv[j] = wsrc[j];
          unsigned sh[8], sm[8];
#pragma unroll
          for (int j = 0; j < 8; ++j) split2rn(wv[j], sh[j], sm[j]);
          short ah[8], am[8];
#pragma unroll
          for (int j = 0; j < 8; ++j) { ah[j] = (short)sh[j]; am[j] = (short)sm[j]; }
          a[oi][0] = (bf16x8){ah[0], ah[1], ah[2], ah[3], ah[4], ah[5], ah[6], ah[7]};
          a[oi][1] = (bf16x8){am[0], am[1], am[2], am[3], am[4], am[5], am[6], am[7]};
        }
#pragma unroll
        for (int st = 0; st < 8; ++st) {
          const short* hb = ffrag + kkl * 4096 + st * 512 + lane * 8;
          bf16x8 b0 = *(const bf16x8*)hb;
          bf16x8 b1 = *(const bf16x8*)(hb + 8192);
#pragma unroll
          for (int oi = 0; oi < 2; ++oi) {
            f32x4 c = acc[oi][st];
            c = __builtin_amdgcn_mfma_f32_16x16x32_bf16(a[oi][1], b0, c, 0, 0, 0);
            c = __builtin_amdgcn_mfma_f32_16x16x32_bf16(a[oi][0], b1, c, 0, 0, 0);
            c = __builtin_amdgcn_mfma_f32_16x16x32_bf16(a[oi][0], b0, c, 0, 0, 0);
            acc[oi][st] = c;
          }
        }
      }
      __syncthreads();
    }
    float inv = 1.0f / sqrtf(1.0f + 1e-5f);
#pragma unroll
    for (int oi = 0; oi < 2; ++oi) {
      int o0 = (wave * 2 + oi) * 16 + quad * 4;
      float4 bb = *(const float4*)&m1b[o0];
      float4 gg = *(const float4*)&m1g[o0];
#pragma unroll
      for (int st = 0; st < 8; ++st) {
        int m_out = m0 + st * 16 + nl;
        f32x4 cc = acc[oi][st];
        float4 r;
        r.x = (cc[0] + bb.x) * (gg.x * inv);
        r.y = (cc[1] + bb.y) * (gg.y * inv);
        r.z = (cc[2] + bb.z) * (gg.z * inv);
        r.w = (cc[3] + bb.w) * (gg.w * inv);
        *(float4*)&W1f[((size_t)(bk * 1024 + m_out)) * 128 + o0] = r;
      }
    }
    return;
  }

  if (bid < 358) {
    // ================= w2/w3 split =================
    int idx = (bid - 342) * 512 + t;               // 0..8191
#pragma unroll
    for (int e = 0; e < 4; ++e) {
      int i = idx * 4 + e;                         // 0..32767
      int c = i & 127, o = (i >> 7) & 127, l = i >> 14;
      float w = (l ? m3w : m2w)[o * 128 + c];
      unsigned sh, sm;
      split2rn(w, sh, sm);
      int ot = o >> 4, mm = o & 15, kk = c >> 5, q = (c & 31) >> 3, j = c & 7;
      int within = (q * 16 + mm) * 8 + j;
      Wf[(((l * 2 + 0) * 4 + kk) * 8 + ot) * 512 + within] = (short)sh;
      Wf[(((l * 2 + 1) * 4 + kk) * 8 + ot) * 512 + within] = (short)sm;
    }
    return;
  }

  if (bid < 374) {
    // ================= c1/c2 split =================
    int idx2 = (bid - 358) * 512 + t;              // 0..8191
#pragma unroll
    for (int e = 0; e < 4; ++e) {
      int i = idx2 * 4 + e;                        // 0..32767
      int c = i & 127, o = (i >> 7) & 127, l = i >> 14;
      float w = (l ? c2w : c1w)[o * 128 + c];
      unsigned sh, sm;
      split2rn(w, sh, sm);
      int ot = o >> 4, mm = o & 15, kk = c >> 5, q = (c & 31) >> 3, j = c & 7;
      int within = (q * 16 + mm) * 8 + j;
      Wf[131072 + (((l * 2 + 0) * 4 + kk) * 8 + ot) * 512 + within] = (short)sh;
      Wf[131072 + (((l * 2 + 1) * 4 + kk) * 8 + ot) * 512 + within] = (short)sm;
    }
    return;
  }

  // ================= prep constants =================
  if (t < 128) {
    float inv = 1.0f / sqrtf(1.0f + 1e-5f);
    float a1 = m1g[t] * inv;
    prep[t] = a1;
    float a2 = m2g[t] * inv;  prep[256 + t] = a2;  prep[384 + t] = fmaf(m2b[t], a2, m2be[t]);
    float a3 = m3g[t] * inv;  prep[512 + t] = a3;  prep[640 + t] = fmaf(m3b[t], a3, m3be[t]);
    float ac1 = c1g[t] * inv; prep[768 + t] = ac1; prep[896 + t] = fmaf(c1b[t], ac1, c1be[t]);
    float ac2 = c2g[t] * inv; prep[1024 + t] = ac2; prep[1152 + t] = fmaf(c2b[t], ac2, c2be[t]);
    prep[1280 + 4 * t + 0] = m1w[t * 259 + 0] * a1;
    prep[1280 + 4 * t + 1] = m1w[t * 259 + 1] * a1;
    prep[1280 + 4 * t + 2] = m1w[t * 259 + 2] * a1;
    prep[1280 + 4 * t + 3] = m1be[t];
  }
}

// ---------------- MFMA GEMM over one 128(c) x nst_h*16(s) fragment buffer ----------
__device__ __forceinline__ void mfma_layer(const short* __restrict__ Wf,
                                           const short* hfrag, int l,
                                           int wave, int lane, int nst_h,
                                           f32x4 acc[2][4])
{
#pragma unroll 1
  for (int kk = 0; kk < 4; ++kk) {
    bf16x8 a[2][2];
#pragma unroll
    for (int oi = 0; oi < 2; ++oi)
#pragma unroll
      for (int sp = 0; sp < 2; ++sp)
        a[oi][sp] = *(const bf16x8*)(Wf + (((l * 2 + sp) * 4 + kk) * 8 + (wave * 2 + oi)) * 512 + lane * 8);
    for (int st = 0; st < nst_h; ++st) {
      const short* hb = hfrag + kk * 2048 + st * 512 + lane * 8;
      bf16x8 b0 = *(const bf16x8*)(hb);           // hi
      bf16x8 b1 = *(const bf16x8*)(hb + 8192);    // mid
#pragma unroll
      for (int oi = 0; oi < 2; ++oi) {
        f32x4 c = acc[oi][st];
        c = __builtin_amdgcn_mfma_f32_16x16x32_bf16(a[oi][1], b0, c, 0, 0, 0);
        c = __builtin_amdgcn_mfma_f32_16x16x32_bf16(a[oi][0], b1, c, 0, 0, 0);
        c = __builtin_amdgcn_mfma_f32_16x16x32_bf16(a[oi][0], b0, c, 0, 0, 0);
        acc[oi][st] = c;
      }
    }
  }
}

// ---------------- fused SA: 4 balls per block, tiles packed over passes ----------
__global__ __launch_bounds__(256, 3) void sa_kernel(
    const float* __restrict__ xc, const float* __restrict__ nxyz,
    const int* __restrict__ bidx, const int* __restrict__ counts,
    const float* __restrict__ W1f, const float* __restrict__ prep,
    const short* __restrict__ Wf, float* __restrict__ feat_out)
{
  __shared__ __align__(16) short hfrag[16384];   // 32KB
  __shared__ float pcs[512];
  __shared__ float sm[32 * 128];                 // 16KB per-tile o-max
  __shared__ float ccen[12];
  __shared__ int scnt[4];
  int gb = blockIdx.x, bk = gb >> 5, pb = (gb & 31) << 2;
  int t = threadIdx.x;
  int wave = t >> 6, lane = t & 63;
  int quad = lane >> 4, nl = lane & 15;

  pcs[t] = prep[1280 + t];
  pcs[256 + t] = prep[1536 + t];
  if (t < 4) scnt[t] = counts[bk * 128 + pb + t];
  if (t < 12) {
    int bb = t / 3, c = t % 3;
    ccen[t] = nxyz[(bk * 128 + pb + bb) * 3 + c];
  }
  __syncthreads();
  int n0 = (scnt[0] + 15) >> 4, n1 = (scnt[1] + 15) >> 4;
  int n2 = (scnt[2] + 15) >> 4, n3 = (scnt[3] + 15) >> 4;
  int pf1 = n0, pf2 = n0 + n1, pf3 = n0 + n1 + n2, T = n0 + n1 + n2 + n3;

  for (int q0 = 0; q0 < T; q0 += 4) {
    int nst_h = T - q0;
    if (nst_h > 4) nst_h = 4;
    // ---- h1 build ----
    {
      int cg = wave;
      int st = lane >> 4, sl = lane & 15;
      if (st < nst_h) {
        int q = q0 + st;
        int bq = (q >= pf1) + (q >= pf2) + (q >= pf3);
        int tstart = (bq == 0) ? 0 : (bq == 1) ? pf1 : (bq == 2) ? pf2 : pf3;
        int tslot = q - tstart;
        int m = bidx[((size_t)(bk * 128 + pb + bq)) * 128 + tslot * 16 + sl];
        float cen0 = ccen[bq * 3 + 0], cen1 = ccen[bq * 3 + 1], cen2 = ccen[bq * 3 + 2];
        float g0 = (xc[(bk * 3 + 0) * 1024 + m] - cen0) * (1.0f / 0.15f);
        float g1 = (xc[(bk * 3 + 1) * 1024 + m] - cen1) * (1.0f / 0.15f);
        float g2 = (xc[(bk * 3 + 2) * 1024 + m] - cen2) * (1.0f / 0.15f);
        const float4* wrow = (const float4*)(W1f + ((size_t)(bk * 1024 + m)) * 128 + cg * 32);
        const float4* pcp = (const float4*)pcs + cg * 32;
#pragma unroll
        for (int g = 0; g < 4; ++g) {
          float4 wva = wrow[g * 2], wvb = wrow[g * 2 + 1];
          float wv[8] = {wva.x, wva.y, wva.z, wva.w, wvb.x, wvb.y, wvb.z, wvb.w};
          unsigned sh[8], smv[8];
#pragma unroll
          for (int e = 0; e < 8; ++e) {
            float4 pc = pcp[g * 8 + e];
            float hv = fmaxf(wv[e] + pc.x * g0 + pc.y * g1 + pc.z * g2 + pc.w, 0.f);
            split2rn(hv, sh[e], smv[e]);
          }
          int base = (cg * 4 + st) * 512 + (g * 16 + sl) * 8;
          v4i ph = {(int)(sh[0] | (sh[1] << 16)), (int)(sh[2] | (sh[3] << 16)),
                    (int)(sh[4] | (sh[5] << 16)), (int)(sh[6] | (sh[7] << 16))};
          *(v4i*)&hfrag[base] = ph;
          v4i pm = {(int)(smv[0] | (smv[1] << 16)), (int)(smv[2] | (smv[3] << 16)),
                    (int)(smv[4] | (smv[5] << 16)), (int)(smv[6] | (smv[7] << 16))};
          *(v4i*)&hfrag[base + 8192] = pm;
        }
      }
    }
    __syncthreads();

    // ---- layer 2 ----
    f32x4 acc[2][4];
#pragma unroll
    for (int oi = 0; oi < 2; ++oi)
#pragma unroll
      for (int st = 0; st < 4; ++st) acc[oi][st] = (f32x4){0.f, 0.f, 0.f, 0.f};
    mfma_layer(Wf, hfrag, 0, wave, lane, nst_h, acc);
    __syncthreads();

    // ---- h2 epilogue ----
#pragma unroll
    for (int oi = 0; oi < 2; ++oi) {
      int o0 = (wave * 2 + oi) * 16 + quad * 4;
      float4 al = *(const float4*)&prep[256 + o0];
      float4 be = *(const float4*)&prep[384 + o0];
      int kk2 = o0 >> 5, g2 = (o0 & 31) >> 3, j0 = o0 & 7;
      for (int st = 0; st < nst_h; ++st) {
        f32x4 cc = acc[oi][st];
        float v0 = fmaxf(fmaf(cc[0], al.x, be.x), 0.f);
        float v1 = fmaxf(fmaf(cc[1], al.y, be.y), 0.f);
        float v2 = fmaxf(fmaf(cc[2], al.z, be.z), 0.f);
        float v3 = fmaxf(fmaf(cc[3], al.w, be.w), 0.f);
        unsigned h0, m0_, h1, m1_, h2, m2_, h3, m3_;
        split2rn(v0, h0, m0_); split2rn(v1, h1, m1_);
        split2rn(v2, h2, m2_); split2rn(v3, h3, m3_);
        int base = (kk2 * 4 + st) * 512 + (g2 * 16 + nl) * 8 + j0;
        v2i w0 = {(int)(h0 | (h1 << 16)), (int)(h2 | (h3 << 16))};
        *(v2i*)&hfrag[base] = w0;
        v2i w1 = {(int)(m0_ | (m1_ << 16)), (int)(m2_ | (m3_ << 16))};
        *(v2i*)&hfrag[base + 8192] = w1;
      }
    }
    __syncthreads();

    // ---- layer 3 ----
#pragma unroll
    for (int oi = 0; oi < 2; ++oi)
#pragma unroll
      for (int st = 0; st < 4; ++st) acc[oi][st] = (f32x4){0.f, 0.f, 0.f, 0.f};
    mfma_layer(Wf, hfrag, 1, wave, lane, nst_h, acc);

    // ---- layer-3 epilogue: BN+ReLU, quad-reduce max per tile ----
#pragma unroll
    for (int oi = 0; oi < 2; ++oi) {
      int o0 = (wave * 2 + oi) * 16 + quad * 4;
      float4 al = *(const float4*)&prep[512 + o0];
      float4 be = *(const float4*)&prep[640 + o0];
      for (int st = 0; st < nst_h; ++st) {
        f32x4 cc = acc[oi][st];
        float v[4];
        v[0] = fmaxf(fmaf(cc[0], al.x, be.x), 0.f);
        v[1] = fmaxf(fmaf(cc[1], al.y, be.y), 0.f);
        v[2] = fmaxf(fmaf(cc[2], al.z, be.z), 0.f);
        v[3] = fmaxf(fmaf(cc[3], al.w, be.w), 0.f);
#pragma unroll
        for (int r = 0; r < 4; ++r) {
          float x = v[r];
          x = fmaxf(x, __shfl_xor(x, 1));
          x = fmaxf(x, __shfl_xor(x, 2));
          x = fmaxf(x, __shfl_xor(x, 4));
          x = fmaxf(x, __shfl_xor(x, 8));
          if (nl == 0) sm[(q0 + st) * 128 + o0 + r] = x;
        }
      }
    }
    __syncthreads();
  }

  // ---- final: merge tiles per ball, write feat ----
#pragma unroll
  for (int e = t; e < 512; e += 256) {
    int bb = e >> 7, o = e & 127;
    int qs = (bb == 0) ? 0 : (bb == 1) ? pf1 : (bb == 2) ? pf2 : pf3;
    int nq = (bb == 0) ? n0 : (bb == 1) ? n1 : (bb == 2) ? n2 : n3;
    float v = sm[qs * 128 + o];
    for (int q = 1; q < nq; ++q) v = fmaxf(v, sm[(qs + q) * 128 + o]);
    feat_out[(((size_t)bk) << 14) + (o << 7) + pb + bb] = v;
  }
}

// ---------------- head: c1 -> c2 (split2 MFMA) -> op -> scores; 2 blocks/bk ------
__global__ __launch_bounds__(256) void head_kernel(const float* __restrict__ featg,
    const float* __restrict__ prep, const short* __restrict__ Wf,
    const float* __restrict__ nxyz, const float* __restrict__ opw,
    const float* __restrict__ opb, float* __restrict__ scores)
{
  __shared__ __align__(16) short hfrag[16384];   // 32KB frags (128c x 64p)
  __shared__ float hplain[128 * 65];             // stride 65 vs conflicts
  int bk = blockIdx.x >> 1, p0 = (blockIdx.x & 1) << 6;
  int t = threadIdx.x;
  int wave = t >> 6, lane = t & 63;
  int quad = lane >> 4, nl = lane & 15;
  const short* WC = Wf + 131072;

  // ---- stage feat[c][p0..p0+63] into split2 B-frags ----
  {
    int cg = wave;
    int st = lane >> 4, sl = lane & 15;
    const float* fb = featg + (bk << 14) + p0 + lane;
#pragma unroll
    for (int g = 0; g < 4; ++g) {
      float v[8];
#pragma unroll
      for (int e = 0; e < 8; ++e)
        v[e] = fb[(cg * 32 + g * 8 + e) << 7];
      unsigned sh[8], sm[8];
#pragma unroll
      for (int e = 0; e < 8; ++e) split2rn(v[e], sh[e], sm[e]);
      int base = (cg * 4 + st) * 512 + (g * 16 + sl) * 8;
      v4i ph = {(int)(sh[0] | (sh[1] << 16)), (int)(sh[2] | (sh[3] << 16)),
                (int)(sh[4] | (sh[5] << 16)), (int)(sh[6] | (sh[7] << 16))};
      *(v4i*)&hfrag[base] = ph;
      v4i pm = {(int)(sm[0] | (sm[1] << 16)), (int)(sm[2] | (sm[3] << 16)),
                (int)(sm[4] | (sm[5] << 16)), (int)(sm[6] | (sm[7] << 16))};
      *(v4i*)&hfrag[base + 8192] = pm;
    }
  }
  __syncthreads();

  // ---- c1 ----
  f32x4 acc[2][4];
#pragma unroll
  for (int oi = 0; oi < 2; ++oi)
#pragma unroll
    for (int st = 0; st < 4; ++st) acc[oi][st] = (f32x4){0.f, 0.f, 0.f, 0.f};
  mfma_layer(WC, hfrag, 0, wave, lane, 4, acc);
  __syncthreads();

  // ---- c1 epilogue: BN+ReLU, write back frags ----
#pragma unroll
  for (int oi = 0; oi < 2; ++oi) {
    int o0 = (wave * 2 + oi) * 16 + quad * 4;
    float4 al = *(const float4*)&prep[768 + o0];
    float4 be = *(const float4*)&prep[896 + o0];
    int kk2 = o0 >> 5, g2 = (o0 & 31) >> 3, j0 = o0 & 7;
#pragma unroll
    for (int st = 0; st < 4; ++st) {
      f32x4 cc = acc[oi][st];
      float v0 = fmaxf(fmaf(cc[0], al.x, be.x), 0.f);
      float v1 = fmaxf(fmaf(cc[1], al.y, be.y), 0.f);
      float v2 = fmaxf(fmaf(cc[2], al.z, be.z), 0.f);
      float v3 = fmaxf(fmaf(cc[3], al.w, be.w), 0.f);
      unsigned h0, m0_, h1, m1_, h2, m2_, h3, m3_;
      split2rn(v0, h0, m0_); split2rn(v1, h1, m1_);
      split2rn(v2, h2, m2_); split2rn(v3, h3, m3_);
      int base = (kk2 * 4 + st) * 512 + (g2 * 16 + nl) * 8 + j0;
      v2i w0 = {(int)(h0 | (h1 << 16)), (int)(h2 | (h3 << 16))};
      *(v2i*)&hfrag[base] = w0;
      v2i w1 = {(int)(m0_ | (m1_ << 16)), (int)(m2_ | (m3_ << 16))};
      *(v2i*)&hfrag[base + 8192] = w1;
    }
  }
  __syncthreads();

  // ---- c2 ----
#pragma unroll
  for (int oi = 0; oi < 2; ++oi)
#pragma unroll
    for (int st = 0; st < 4; ++st) acc[oi][st] = (f32x4){0.f, 0.f, 0.f, 0.f};
  mfma_layer(WC, hfrag, 1, wave, lane, 4, acc);

  // ---- c2 epilogue: BN+ReLU -> hplain[c][p] ----
#pragma unroll
  for (int oi = 0; oi < 2; ++oi) {
    int o0 = (wave * 2 + oi) * 16 + quad * 4;
    float4 al = *(const float4*)&prep[1024 + o0];
    float4 be = *(const float4*)&prep[1152 + o0];
#pragma unroll
    for (int st = 0; st < 4; ++st) {
      f32x4 cc = acc[oi][st];
      int p = st * 16 + nl;
      hplain[(o0 + 0) * 65 + p] = fmaxf(fmaf(cc[0], al.x, be.x), 0.f);
      hplain[(o0 + 1) * 65 + p] = fmaxf(fmaf(cc[1], al.y, be.y), 0.f);
      hplain[(o0 + 2) * 65 + p] = fmaxf(fmaf(cc[2], al.z, be.z), 0.f);
      hplain[(o0 + 3) * 65 + p] = fmaxf(fmaf(cc[3], al.w, be.w), 0.f);
    }
  }
  __syncthreads();

  // ---- op head + scores ----
  if (t < 64) {
    int p = t, k = bk % 19;
    float res[5];
#pragma unroll
    for (int j = 0; j < 5; ++j) {
      const float* wr = opw + ((size_t)(k * 5 + j)) * 128;
      float a = opb[k * 5 + j];
      for (int c = 0; c < 128; ++c) a = fmaf(wr[c], hplain[c * 65 + p], a);
      res[j] = a;
    }
    int pg = p0 + p;
    float a0 = nxyz[(bk * 128 + pg) * 3 + 0];
    float a1 = nxyz[(bk * 128 + pg) * 3 + 1];
    float a2 = nxyz[(bk * 128 + pg) * 3 + 2];
    float* sc = scores + ((size_t)(bk * 128 + pg)) * 5;
    sc[0] = res[0];
    sc[1] = res[1];
    sc[2] = a0 + res[2];
    sc[3] = a1 + res[3];
    sc[4] = a2 + res[4];
  }
}

extern "C" void kernel_launch(void* const* d_in, const int* in_sizes, int n_in,
                              void* d_out, int out_size, void* d_ws, size_t ws_size,
                              hipStream_t stream) {
  (void)in_sizes; (void)n_in; (void)out_size; (void)ws_size;
  const float* xyz  = (const float*)d_in[0];
  const float* fts  = (const float*)d_in[1];
  const float* m1w  = (const float*)d_in[2];
  const float* m1b  = (const float*)d_in[3];
  const float* m1g  = (const float*)d_in[4];
  const float* m1be = (const float*)d_in[5];
  const float* m2w  = (const float*)d_in[6];
  const float* m2b  = (const float*)d_in[7];
  const float* m2g  = (const float*)d_in[8];
  const float* m2be = (const float*)d_in[9];
  const float* m3w  = (const float*)d_in[10];
  const float* m3b  = (const float*)d_in[11];
  const float* m3g  = (const float*)d_in[12];
  const float* m3be = (const float*)d_in[13];
  const float* c1w  = (const float*)d_in[14];
  const float* c1b  = (const float*)d_in[15];
  const float* c1g  = (const float*)d_in[16];
  const float* c1be = (const float*)d_in[17];
  const float* c2w  = (const float*)d_in[18];
  const float* c2b  = (const float*)d_in[19];
  const float* c2g  = (const float*)d_in[20];
  const float* c2be = (const float*)d_in[21];
  const float* opw  = (const float*)d_in[22];
  const float* opb  = (const float*)d_in[23];

  float* out = (float*)d_out;
  char* ws = (char*)d_ws;
  float* xc   = (float*)(ws + OFF_XC);
  float* nxyz = (float*)(ws + OFF_NXYZ);
  int*   bidx = (int*)(ws + OFF_BIDX);
  float* W1f  = (float*)(ws + OFF_W1F);
  float* prep = (float*)(ws + OFF_PREP);
  short* Wf   = (short*)(ws + OFF_WF);
  int*   cnt  = (int*)(ws + OFF_CNT);

  hipLaunchKernelGGL(fps_kernel, dim3(NBK), dim3(128), 0, stream,
                     xyz, xc, nxyz, out + OUT_AGG);
  hipLaunchKernelGGL(front_kernel, dim3(375), dim3(512), 0, stream,
                     xyz, fts, m1w, m1b, m1g, m1be, m2w, m2b, m2g, m2be,
                     m3w, m3b, m3g, m3be, c1w, c1b, c1g, c1be,
                     c2w, c2b, c2g, c2be,
                     xc, nxyz, bidx, cnt, W1f, Wf, prep);
  hipLaunchKernelGGL(sa_kernel, dim3(NBK * 32), dim3(256), 0, stream,
                     xc, nxyz, bidx, cnt, W1f, prep, Wf, out + OUT_FEAT);
  hipLaunchKernelGGL(head_kernel, dim3(NBK * 2), dim3(256), 0, stream,
                     out + OUT_FEAT, prep, Wf, nxyz, opw, opb, out);
}

// Round 5
// 288.733 us; speedup vs baseline: 2.1640x; 1.0083x over previous
//
#include <hip/hip_runtime.h>
#include <math.h>

// ---------------- problem constants ----------------
// B=2, K=19 -> BK=38 batches; M=1024 points; C=256 feat ch; NPOINT=NSAMPLE=128
#define NBK   38

// ---------------- workspace layout (bytes) ----------------
#define OFF_XC    0u          // [38][3][1024] f32        = 466944
#define OFF_NXYZ  466944u     // [38][128][3]  f32        = 58368
#define OFF_BIDX  525312u     // [38][128][128] i32       = 2490368
#define OFF_W1F   3015680u    // [38][1024][128] f32      = 19922944
#define OFF_PREP  22938624u   // 4096 f32
#define OFF_WF    22955008u   // 196608 shorts: w2/w3 (0), unused (65536), c1/c2 (131072)
#define OFF_CNT   23348224u   // [38][128] i32 ball counts = 19456

// ---------------- d_out layout (float offsets) ----------------
#define OUT_AGG   24320       // scores at 0: (2,19,128,5)
#define OUT_FEAT  38912       // agg: (2,19,128,3), feat: (2,19,128,128)

typedef short bf16x8 __attribute__((ext_vector_type(8)));   // 8 bf16 = 4 VGPR
typedef float f32x4  __attribute__((ext_vector_type(4)));
typedef int   v4i    __attribute__((ext_vector_type(4)));
typedef int   v2i    __attribute__((ext_vector_type(2)));

// exact IEEE fp32 squared distance, no FMA contraction, ((d0^2+d1^2)+d2^2)
__device__ __forceinline__ float dist2f(float a0, float a1, float a2,
                                        float b0, float b1, float b2) {
#pragma clang fp contract(off)
  float d0 = a0 - b0;
  float d1 = a1 - b1;
  float d2 = a2 - b2;
  return d0 * d0 + d1 * d1 + d2 * d2;
}

// 2-way bf16 split with round-to-nearest-even: v ~= hi + mid, residual <= 2^-18 |v|
__device__ __forceinline__ void split2rn(float v, unsigned& sh, unsigned& sm) {
  unsigned u = __float_as_uint(v);
  unsigned rh = (u + 0x7fffu + ((u >> 16) & 1u)) & 0xffff0000u;
  sh = rh >> 16;
  float r1 = v - __uint_as_float(rh);        // exact in fp32
  unsigned u1 = __float_as_uint(r1);
  unsigned rm = (u1 + 0x7fffu + ((u1 >> 16) & 1u)) & 0xffff0000u;
  sm = rm >> 16;
}

// DPP fmax step: v = fmax(v, v shifted by ctrl); invalid lanes keep own value.
#define DPP_FMAX_STEP(v, ctrl)                                                 \
  {                                                                            \
    int _s = __builtin_amdgcn_update_dpp(__float_as_int(v), __float_as_int(v), \
                                         (ctrl), 0xf, 0xf, false);             \
    (v) = fmaxf((v), __int_as_float(_s));                                      \
  }

__device__ __forceinline__ float readlane_f(float v, int l) {
  return __int_as_float(__builtin_amdgcn_readlane(__float_as_int(v), l));
}

// ---------------- K1 "front" (512-thread blocks) ----------------
// blocks 0..37: fps (2-wave, 8 pts/lane, ~44 live VGPRs - fits the shared
//   budget) + ball query, overlapped with the w1f blocks on other CUs;
// 38..341: w1f (256 active threads); 342..357: w2/w3 split;
// 358..373: c1/c2 split; 374: prep constants.
__global__ __launch_bounds__(512, 2) void front_kernel(
    const float* __restrict__ xyz, const float* __restrict__ feats,
    const float* __restrict__ m1w, const float* __restrict__ m1b,
    const float* __restrict__ m1g, const float* __restrict__ m1be,
    const float* __restrict__ m2w, const float* __restrict__ m2b,
    const float* __restrict__ m2g, const float* __restrict__ m2be,
    const float* __restrict__ m3w, const float* __restrict__ m3b,
    const float* __restrict__ m3g, const float* __restrict__ m3be,
    const float* __restrict__ c1w, const float* __restrict__ c1b,
    const float* __restrict__ c1g, const float* __restrict__ c1be,
    const float* __restrict__ c2w, const float* __restrict__ c2b,
    const float* __restrict__ c2g, const float* __restrict__ c2be,
    float* __restrict__ xc, float* __restrict__ nxyz, float* __restrict__ agg,
    int* __restrict__ bidx, int* __restrict__ counts,
    float* __restrict__ W1f, short* __restrict__ Wf, float* __restrict__ prep)
{
  __shared__ __align__(16) char smem[32768];
  int bid = blockIdx.x, t = threadIdx.x;
  int wave = t >> 6, lane = t & 63;

  if (bid < NBK) {
    // ================= fps (waves 0-1) + ball query (8 waves) =============
    int bk = bid;
    int b = bk / 19, k = bk % 19;
    float4* sp4 = (float4*)smem;                    // 1024 float4 = 16KB
    float4* scen4 = (float4*)(smem + 16384);        // 128 float4 = 2KB
    int* sfar = (int*)(smem + 18432);               // 128 ints
    int2* cexch = (int2*)(smem + 18944);            // [parity][wave]

    for (int i = t; i < 1024; i += 512) {
      const float* src = xyz + ((size_t)((b * 1024 + i) * 19 + k)) * 3;
      float x0 = src[0], x1 = src[1], x2 = src[2];
      sp4[i] = make_float4(x0, x1, x2, 0.f);
      xc[(bk * 3 + 0) * 1024 + i] = x0;
      xc[(bk * 3 + 1) * 1024 + i] = x1;
      xc[(bk * 3 + 2) * 1024 + i] = x2;
    }
    if (t == 0) sfar[0] = 0;
    __syncthreads();

    // lane-local points: m = wave*512 + lane*8 + j (contiguous => ctz/left-wins
    // tie-breaking reproduces jnp.argmax first-max exactly)
    float px[8], py[8], pz[8], dist[8];
    if (wave < 2) {
      int mbase = (wave << 9) + (lane << 3);
#pragma unroll
      for (int j = 0; j < 8; ++j) {
        float4 p = sp4[mbase + j];
        px[j] = p.x; py[j] = p.y; pz[j] = p.z;
        dist[j] = 1e10f;
      }
    }

    int far = 0;
    for (int it = 1; it < 128; ++it) {
      if (wave < 2) {
        float4 c = sp4[far];                       // uniform-address b128 read
#pragma unroll
        for (int j = 0; j < 8; ++j) {
          float d = dist2f(px[j], py[j], pz[j], c.x, c.y, c.z);
          dist[j] = fminf(dist[j], d);
        }
        // local first-max tree over 8 (>= keeps left => smallest j on ties)
        float tv[4]; int tj[4];
#pragma unroll
        for (int i = 0; i < 4; ++i) {
          bool L = dist[2 * i] >= dist[2 * i + 1];
          tv[i] = L ? dist[2 * i] : dist[2 * i + 1];
          tj[i] = L ? (2 * i) : (2 * i + 1);
        }
        {
          bool L0 = tv[0] >= tv[1];
          float v0 = L0 ? tv[0] : tv[1]; int j0 = L0 ? tj[0] : tj[1];
          bool L1 = tv[2] >= tv[3];
          float v1 = L1 ? tv[2] : tv[3]; int j1 = L1 ? tj[2] : tj[3];
          bool L = v0 >= v1;
          tv[0] = L ? v0 : v1; tj[0] = L ? j0 : j1;
        }
        float lmax = tv[0];
        // in-row max via DPP row_shr: lanes 15/31/47/63 hold row maxes
        float g = lmax;
        DPP_FMAX_STEP(g, 0x111);   // row_shr:1
        DPP_FMAX_STEP(g, 0x112);   // row_shr:2
        DPP_FMAX_STEP(g, 0x114);   // row_shr:4
        DPP_FMAX_STEP(g, 0x118);   // row_shr:8
        float r0 = readlane_f(g, 15);
        float r1 = readlane_f(g, 31);
        float r2 = readlane_f(g, 47);
        float r3 = readlane_f(g, 63);
        float gmax = fmaxf(fmaxf(r0, r1), fmaxf(r2, r3));
        // smallest lane whose local max equals the wave max
        unsigned long long mk = __ballot(lmax == gmax);
        int wl = (int)__builtin_ctzll(mk);
        int lj = (lane << 3) + tj[0];
        int cand_m = (wave << 9) + __builtin_amdgcn_readlane(lj, wl);
        if (lane == 0) cexch[(it & 1) * 2 + wave] =
            make_int2(__float_as_int(gmax), cand_m);
      }
      __syncthreads();
      if (wave < 2) {
        int2 c0 = cexch[(it & 1) * 2 + 0];
        int2 c1 = cexch[(it & 1) * 2 + 1];
        // wave0 wins ties (owns smaller indices)
        far = (__int_as_float(c1.x) > __int_as_float(c0.x)) ? c1.y : c0.y;
        if (t == 0) sfar[it] = far;
      }
    }
    __syncthreads();

    // ---- flush centers (LDS scen4 + global nxyz/agg) ----
    if (t < 128) {
      float4 c = sp4[sfar[t]];
      scen4[t] = c;
      nxyz[bk * 384 + t * 3 + 0] = c.x;
      nxyz[bk * 384 + t * 3 + 1] = c.y;
      nxyz[bk * 384 + t * 3 + 2] = c.z;
      agg[bk * 384 + t * 3 + 0] = c.x;
      agg[bk * 384 + t * 3 + 1] = c.y;
      agg[bk * 384 + t * 3 + 2] = c.z;
    }
    __syncthreads();

    // ---- ball query: 8 waves x 16 balls from LDS ----
    for (int p = wave * 16; p < wave * 16 + 16; ++p) {
      float4 cen = scen4[p];
      int* outp = bidx + ((size_t)(bk * 128 + p)) * 128;
      int count = 0, first = 0;
      bool got = false;
      for (int ch = 0; ch < 16 && count < 128; ++ch) {
        int m = (ch << 6) + lane;
        float4 pv = sp4[m];
        float d = dist2f(pv.x, pv.y, pv.z, cen.x, cen.y, cen.z);
        bool flag = d < 0.0225f;                 // strict fp32, RADIUS^2
        unsigned long long mask = __ballot(flag);
        if (!got && mask) { first = (ch << 6) + __builtin_ctzll(mask); got = true; }
        int pos = count + (int)__popcll(mask & ((1ull << lane) - 1ull));
        if (flag && pos < 128) outp[pos] = m;
        count += (int)__popcll(mask);
      }
      for (int j = count + lane; j < 128; j += 64) outp[j] = first;
      if (lane == 0) counts[bk * 128 + p] = count > 128 ? 128 : count;
    }
    return;
  }

  if (bid < 342) {
    // ================= w1f: 256 active threads; idle waves match 8 barriers =====
    short* ffrag = (short*)smem;                  // 32KB
    if (t >= 256) {
      for (int i = 0; i < 8; ++i) __syncthreads();
      return;
    }
    int blk = bid - NBK;
    int bk = blk >> 3, m0 = (blk & 7) << 7;
    int b = bk / 19, k = bk % 19;
    int quad = lane >> 4, nl = lane & 15;
    int mloc = t & 127, chalf = t >> 7;
    int st_w = mloc >> 4, sl_w = mloc & 15;
    const float* fbase = feats + ((size_t)(b * 4864 + k)) * 1024 + m0 + mloc;

    f32x4 acc[2][8];
#pragma unroll
    for (int oi = 0; oi < 2; ++oi)
#pragma unroll
      for (int st = 0; st < 8; ++st) acc[oi][st] = (f32x4){0.f, 0.f, 0.f, 0.f};

    for (int ch = 0; ch < 4; ++ch) {
      int cbase = ch * 64 + chalf * 32;
#pragma unroll
      for (int g = 0; g < 4; ++g) {
        float v[8];
#pragma unroll
        for (int j = 0; j < 8; ++j)
          v[j] = fbase[(size_t)(cbase + g * 8 + j) * 19456];
        unsigned sh[8], sm[8];
#pragma unroll
        for (int j = 0; j < 8; ++j) split2rn(v[j], sh[j], sm[j]);
        int base = chalf * 4096 + st_w * 512 + (g * 16 + sl_w) * 8;
        v4i ph = {(int)(sh[0] | (sh[1] << 16)), (int)(sh[2] | (sh[3] << 16)),
                  (int)(sh[4] | (sh[5] << 16)), (int)(sh[6] | (sh[7] << 16))};
        *(v4i*)&ffrag[base] = ph;
        v4i pm = {(int)(sm[0] | (sm[1] << 16)), (int)(sm[2] | (sm[3] << 16)),
                  (int)(sm[4] | (sm[5] << 16)), (int)(sm[6] | (sm[7] << 16))};
        *(v4i*)&ffrag[base + 8192] = pm;
      }
      __syncthreads();
#pragma unroll
      for (int kkl = 0; kkl < 2; ++kkl) {
        int kk = ch * 2 + kkl;
        bf16x8 a[2][2];
#pragma unroll
        for (int oi = 0; oi < 2; ++oi) {
          int o_row = (wave * 2 + oi) * 16 + nl;
          const float* wsrc = m1w + o_row * 259 + 3 + kk * 32 + quad * 8;
          float wv[8];
#pragma unroll
          for (int j = 0; j < 8; ++j) wv[j] = wsrc[j];
          unsigned sh[8], sm[8];
#pragma unroll
          for (int j = 0; j < 8; ++j) split2rn(wv[j], sh[j], sm[j]);
          short ah[8], am[8];
#pragma unroll
          for (int j = 0; j < 8; ++j) { ah[j] = (short)sh[j]; am[j] = (short)sm[j]; }
          a[oi][0] = (bf16x8){ah[0], ah[1], ah[2], ah[3], ah[4], ah[5], ah[6], ah[7]};
          a[oi][1] = (bf16x8){am[0], am[1], am[2], am[3], am[4], am[5], am[6], am[7]};
        }
#pragma unroll
        for (int st = 0; st < 8; ++st) {
          const short* hb = ffrag + kkl * 4096 + st * 512 + lane * 8;
          bf16x8 b0 = *(const bf16x8*)hb;
          bf16x8 b1 = *(const bf16x8*)(hb + 8192);
#pragma unroll
          for (int oi = 0; oi < 2; ++oi) {
            f32x4 c = acc[oi][st];
            c = __builtin_amdgcn_mfma_f32_16x16x32_bf16(a[oi][1], b0, c, 0, 0, 0);
            c = __builtin_amdgcn_mfma_f32_16x16x32_bf16(a[oi][0], b1, c, 0, 0, 0);
            c = __builtin_amdgcn_mfma_f32_16x16x32_bf16(a[oi][0], b0, c, 0, 0, 0);
            acc[oi][st] = c;
          }
        }
      }
      __syncthreads();
    }
    float inv = 1.0f / sqrtf(1.0f + 1e-5f);
#pragma unroll
    for (int oi = 0; oi < 2; ++oi) {
      int o0 = (wave * 2 + oi) * 16 + quad * 4;
      float4 bb = *(const float4*)&m1b[o0];
      float4 gg = *(const float4*)&m1g[o0];
#pragma unroll
      for (int st = 0; st < 8; ++st) {
        int m_out = m0 + st * 16 + nl;
        f32x4 cc = acc[oi][st];
        float4 r;
        r.x = (cc[0] + bb.x) * (gg.x * inv);
        r.y = (cc[1] + bb.y) * (gg.y * inv);
        r.z = (cc[2] + bb.z) * (gg.z * inv);
        r.w = (cc[3] + bb.w) * (gg.w * inv);
        *(float4*)&W1f[((size_t)(bk * 1024 + m_out)) * 128 + o0] = r;
      }
    }
    return;
  }

  if (bid < 358) {
    // ================= w2/w3 split =================
    int idx = (bid - 342) * 512 + t;               // 0..8191
#pragma unroll
    for (int e = 0; e < 4; ++e) {
      int i = idx * 4 + e;                         // 0..32767
      int c = i & 127, o = (i >> 7) & 127, l = i >> 14;
      float w = (l ? m3w : m2w)[o * 128 + c];
      unsigned sh, sm;
      split2rn(w, sh, sm);
      int ot = o >> 4, mm = o & 15, kk = c >> 5, q = (c & 31) >> 3, j = c & 7;
      int within = (q * 16 + mm) * 8 + j;
      Wf[(((l * 2 + 0) * 4 + kk) * 8 + ot) * 512 + within] = (short)sh;
      Wf[(((l * 2 + 1) * 4 + kk) * 8 + ot) * 512 + within] = (short)sm;
    }
    return;
  }

  if (bid < 374) {
    // ================= c1/c2 split =================
    int idx2 = (bid - 358) * 512 + t;              // 0..8191
#pragma unroll
    for (int e = 0; e < 4; ++e) {
      int i = idx2 * 4 + e;                        // 0..32767
      int c = i & 127, o = (i >> 7) & 127, l = i >> 14;
      float w = (l ? c2w : c1w)[o * 128 + c];
      unsigned sh, sm;
      split2rn(w, sh, sm);
      int ot = o >> 4, mm = o & 15, kk = c >> 5, q = (c & 31) >> 3, j = c & 7;
      int within = (q * 16 + mm) * 8 + j;
      Wf[131072 + (((l * 2 + 0) * 4 + kk) * 8 + ot) * 512 + within] = (short)sh;
      Wf[131072 + (((l * 2 + 1) * 4 + kk) * 8 + ot) * 512 + within] = (short)sm;
    }
    return;
  }

  // ================= prep constants =================
  if (t < 128) {
    float inv = 1.0f / sqrtf(1.0f + 1e-5f);
    float a1 = m1g[t] * inv;
    prep[t] = a1;
    float a2 = m2g[t] * inv;  prep[256 + t] = a2;  prep[384 + t] = fmaf(m2b[t], a2, m2be[t]);
    float a3 = m3g[t] * inv;  prep[512 + t] = a3;  prep[640 + t] = fmaf(m3b[t], a3, m3be[t]);
    float ac1 = c1g[t] * inv; prep[768 + t] = ac1; prep[896 + t] = fmaf(c1b[t], ac1, c1be[t]);
    float ac2 = c2g[t] * inv; prep[1024 + t] = ac2; prep[1152 + t] = fmaf(c2b[t], ac2, c2be[t]);
    prep[1280 + 4 * t + 0] = m1w[t * 259 + 0] * a1;
    prep[1280 + 4 * t + 1] = m1w[t * 259 + 1] * a1;
    prep[1280 + 4 * t + 2] = m1w[t * 259 + 2] * a1;
    prep[1280 + 4 * t + 3] = m1be[t];
  }
}

// ---------------- MFMA GEMM over one 128(c) x nst_h*16(s) fragment buffer ----------
__device__ __forceinline__ void mfma_layer(const short* __restrict__ Wf,
                                           const short* hfrag, int l,
                                           int wave, int lane, int nst_h,
                                           f32x4 acc[2][4])
{
#pragma unroll 1
  for (int kk = 0; kk < 4; ++kk) {
    bf16x8 a[2][2];
#pragma unroll
    for (int oi = 0; oi < 2; ++oi)
#pragma unroll
      for (int sp = 0; sp < 2; ++sp)
        a[oi][sp] = *(const bf16x8*)(Wf + (((l * 2 + sp) * 4 + kk) * 8 + (wave * 2 + oi)) * 512 + lane * 8);
    for (int st = 0; st < nst_h; ++st) {
      const short* hb = hfrag + kk * 2048 + st * 512 + lane * 8;
      bf16x8 b0 = *(const bf16x8*)(hb);           // hi
      bf16x8 b1 = *(const bf16x8*)(hb + 8192);    // mid
#pragma unroll
      for (int oi = 0; oi < 2; ++oi) {
        f32x4 c = acc[oi][st];
        c = __builtin_amdgcn_mfma_f32_16x16x32_bf16(a[oi][1], b0, c, 0, 0, 0);
        c = __builtin_amdgcn_mfma_f32_16x16x32_bf16(a[oi][0], b1, c, 0, 0, 0);
        c = __builtin_amdgcn_mfma_f32_16x16x32_bf16(a[oi][0], b0, c, 0, 0, 0);
        acc[oi][st] = c;
      }
    }
  }
}

// ---------------- fused SA: 4 balls per block, tiles packed over passes ----------
__global__ __launch_bounds__(256, 3) void sa_kernel(
    const float* __restrict__ xc, const float* __restrict__ nxyz,
    const int* __restrict__ bidx, const int* __restrict__ counts,
    const float* __restrict__ W1f, const float* __restrict__ prep,
    const short* __restrict__ Wf, float* __restrict__ feat_out)
{
  __shared__ __align__(16) short hfrag[16384];   // 32KB
  __shared__ float pcs[512];
  __shared__ float sm[32 * 128];                 // 16KB per-tile o-max
  __shared__ float ccen[12];
  __shared__ int scnt[4];
  int gb = blockIdx.x, bk = gb >> 5, pb = (gb & 31) << 2;
  int t = threadIdx.x;
  int wave = t >> 6, lane = t & 63;
  int quad = lane >> 4, nl = lane & 15;

  pcs[t] = prep[1280 + t];
  pcs[256 + t] = prep[1536 + t];
  if (t < 4) scnt[t] = counts[bk * 128 + pb + t];
  if (t < 12) {
    int bb = t / 3, c = t % 3;
    ccen[t] = nxyz[(bk * 128 + pb + bb) * 3 + c];
  }
  __syncthreads();
  int n0 = (scnt[0] + 15) >> 4, n1 = (scnt[1] + 15) >> 4;
  int n2 = (scnt[2] + 15) >> 4, n3 = (scnt[3] + 15) >> 4;
  int pf1 = n0, pf2 = n0 + n1, pf3 = n0 + n1 + n2, T = n0 + n1 + n2 + n3;

  for (int q0 = 0; q0 < T; q0 += 4) {
    int nst_h = T - q0;
    if (nst_h > 4) nst_h = 4;
    // ---- h1 build ----
    {
      int cg = wave;
      int st = lane >> 4, sl = lane & 15;
      if (st < nst_h) {
        int q = q0 + st;
        int bq = (q >= pf1) + (q >= pf2) + (q >= pf3);
        int tstart = (bq == 0) ? 0 : (bq == 1) ? pf1 : (bq == 2) ? pf2 : pf3;
        int tslot = q - tstart;
        int m = bidx[((size_t)(bk * 128 + pb + bq)) * 128 + tslot * 16 + sl];
        float cen0 = ccen[bq * 3 + 0], cen1 = ccen[bq * 3 + 1], cen2 = ccen[bq * 3 + 2];
        float g0 = (xc[(bk * 3 + 0) * 1024 + m] - cen0) * (1.0f / 0.15f);
        float g1 = (xc[(bk * 3 + 1) * 1024 + m] - cen1) * (1.0f / 0.15f);
        float g2 = (xc[(bk * 3 + 2) * 1024 + m] - cen2) * (1.0f / 0.15f);
        const float4* wrow = (const float4*)(W1f + ((size_t)(bk * 1024 + m)) * 128 + cg * 32);
        const float4* pcp = (const float4*)pcs + cg * 32;
#pragma unroll
        for (int g = 0; g < 4; ++g) {
          float4 wva = wrow[g * 2], wvb = wrow[g * 2 + 1];
          float wv[8] = {wva.x, wva.y, wva.z, wva.w, wvb.x, wvb.y, wvb.z, wvb.w};
          unsigned sh[8], smv[8];
#pragma unroll
          for (int e = 0; e < 8; ++e) {
            float4 pc = pcp[g * 8 + e];
            float hv = fmaxf(wv[e] + pc.x * g0 + pc.y * g1 + pc.z * g2 + pc.w, 0.f);
            split2rn(hv, sh[e], smv[e]);
          }
          int base = (cg * 4 + st) * 512 + (g * 16 + sl) * 8;
          v4i ph = {(int)(sh[0] | (sh[1] << 16)), (int)(sh[2] | (sh[3] << 16)),
                    (int)(sh[4] | (sh[5] << 16)), (int)(sh[6] | (sh[7] << 16))};
          *(v4i*)&hfrag[base] = ph;
          v4i pm = {(int)(smv[0] | (smv[1] << 16)), (int)(smv[2] | (smv[3] << 16)),
                    (int)(smv[4] | (smv[5] << 16)), (int)(smv[6] | (smv[7] << 16))};
          *(v4i*)&hfrag[base + 8192] = pm;
        }
      }
    }
    __syncthreads();

    // ---- layer 2 ----
    f32x4 acc[2][4];
#pragma unroll
    for (int oi = 0; oi < 2; ++oi)
#pragma unroll
      for (int st = 0; st < 4; ++st) acc[oi][st] = (f32x4){0.f, 0.f, 0.f, 0.f};
    mfma_layer(Wf, hfrag, 0, wave, lane, nst_h, acc);
    __syncthreads();

    // ---- h2 epilogue ----
#pragma unroll
    for (int oi = 0; oi < 2; ++oi) {
      int o0 = (wave * 2 + oi) * 16 + quad * 4;
      float4 al = *(const float4*)&prep[256 + o0];
      float4 be = *(const float4*)&prep[384 + o0];
      int kk2 = o0 >> 5, g2 = (o0 & 31) >> 3, j0 = o0 & 7;
      for (int st = 0; st < nst_h; ++st) {
        f32x4 cc = acc[oi][st];
        float v0 = fmaxf(fmaf(cc[0], al.x, be.x), 0.f);
        float v1 = fmaxf(fmaf(cc[1], al.y, be.y), 0.f);
        float v2 = fmaxf(fmaf(cc[2], al.z, be.z), 0.f);
        float v3 = fmaxf(fmaf(cc[3], al.w, be.w), 0.f);
        unsigned h0, m0_, h1, m1_, h2, m2_, h3, m3_;
        split2rn(v0, h0, m0_); split2rn(v1, h1, m1_);
        split2rn(v2, h2, m2_); split2rn(v3, h3, m3_);
        int base = (kk2 * 4 + st) * 512 + (g2 * 16 + nl) * 8 + j0;
        v2i w0 = {(int)(h0 | (h1 << 16)), (int)(h2 | (h3 << 16))};
        *(v2i*)&hfrag[base] = w0;
        v2i w1 = {(int)(m0_ | (m1_ << 16)), (int)(m2_ | (m3_ << 16))};
        *(v2i*)&hfrag[base + 8192] = w1;
      }
    }
    __syncthreads();

    // ---- layer 3 ----
#pragma unroll
    for (int oi = 0; oi < 2; ++oi)
#pragma unroll
      for (int st = 0; st < 4; ++st) acc[oi][st] = (f32x4){0.f, 0.f, 0.f, 0.f};
    mfma_layer(Wf, hfrag, 1, wave, lane, nst_h, acc);

    // ---- layer-3 epilogue: BN+ReLU, quad-reduce max per tile ----
#pragma unroll
    for (int oi = 0; oi < 2; ++oi) {
      int o0 = (wave * 2 + oi) * 16 + quad * 4;
      float4 al = *(const float4*)&prep[512 + o0];
      float4 be = *(const float4*)&prep[640 + o0];
      for (int st = 0; st < nst_h; ++st) {
        f32x4 cc = acc[oi][st];
        float v[4];
        v[0] = fmaxf(fmaf(cc[0], al.x, be.x), 0.f);
        v[1] = fmaxf(fmaf(cc[1], al.y, be.y), 0.f);
        v[2] = fmaxf(fmaf(cc[2], al.z, be.z), 0.f);
        v[3] = fmaxf(fmaf(cc[3], al.w, be.w), 0.f);
#pragma unroll
        for (int r = 0; r < 4; ++r) {
          float x = v[r];
          x = fmaxf(x, __shfl_xor(x, 1));
          x = fmaxf(x, __shfl_xor(x, 2));
          x = fmaxf(x, __shfl_xor(x, 4));
          x = fmaxf(x, __shfl_xor(x, 8));
          if (nl == 0) sm[(q0 + st) * 128 + o0 + r] = x;
        }
      }
    }
    __syncthreads();
  }

  // ---- final: merge tiles per ball, write feat ----
#pragma unroll
  for (int e = t; e < 512; e += 256) {
    int bb = e >> 7, o = e & 127;
    int qs = (bb == 0) ? 0 : (bb == 1) ? pf1 : (bb == 2) ? pf2 : pf3;
    int nq = (bb == 0) ? n0 : (bb == 1) ? n1 : (bb == 2) ? n2 : n3;
    float v = sm[qs * 128 + o];
    for (int q = 1; q < nq; ++q) v = fmaxf(v, sm[(qs + q) * 128 + o]);
    feat_out[(((size_t)bk) << 14) + (o << 7) + pb + bb] = v;
  }
}

// ---------------- head: c1 -> c2 (split2 MFMA) -> op -> scores; 2 blocks/bk ------
__global__ __launch_bounds__(256) void head_kernel(const float* __restrict__ featg,
    const float* __restrict__ prep, const short* __restrict__ Wf,
    const float* __restrict__ nxyz, const float* __restrict__ opw,
    const float* __restrict__ opb, float* __restrict__ scores)
{
  __shared__ __align__(16) short hfrag[16384];   // 32KB frags (128c x 64p)
  __shared__ float hplain[128 * 65];             // stride 65 vs conflicts
  int bk = blockIdx.x >> 1, p0 = (blockIdx.x & 1) << 6;
  int t = threadIdx.x;
  int wave = t >> 6, lane = t & 63;
  int quad = lane >> 4, nl = lane & 15;
  const short* WC = Wf + 131072;

  // ---- stage feat[c][p0..p0+63] into split2 B-frags ----
  {
    int cg = wave;
    int st = lane >> 4, sl = lane & 15;
    const float* fb = featg + (bk << 14) + p0 + lane;
#pragma unroll
    for (int g = 0; g < 4; ++g) {
      float v[8];
#pragma unroll
      for (int e = 0; e < 8; ++e)
        v[e] = fb[(cg * 32 + g * 8 + e) << 7];
      unsigned sh[8], sm[8];
#pragma unroll
      for (int e = 0; e < 8; ++e) split2rn(v[e], sh[e], sm[e]);
      int base = (cg * 4 + st) * 512 + (g * 16 + sl) * 8;
      v4i ph = {(int)(sh[0] | (sh[1] << 16)), (int)(sh[2] | (sh[3] << 16)),
                (int)(sh[4] | (sh[5] << 16)), (int)(sh[6] | (sh[7] << 16))};
      *(v4i*)&hfrag[base] = ph;
      v4i pm = {(int)(sm[0] | (sm[1] << 16)), (int)(sm[2] | (sm[3] << 16)),
                (int)(sm[4] | (sm[5] << 16)), (int)(sm[6] | (sm[7] << 16))};
      *(v4i*)&hfrag[base + 8192] = pm;
    }
  }
  __syncthreads();

  // ---- c1 ----
  f32x4 acc[2][4];
#pragma unroll
  for (int oi = 0; oi < 2; ++oi)
#pragma unroll
    for (int st = 0; st < 4; ++st) acc[oi][st] = (f32x4){0.f, 0.f, 0.f, 0.f};
  mfma_layer(WC, hfrag, 0, wave, lane, 4, acc);
  __syncthreads();

  // ---- c1 epilogue: BN+ReLU, write back frags ----
#pragma unroll
  for (int oi = 0; oi < 2; ++oi) {
    int o0 = (wave * 2 + oi) * 16 + quad * 4;
    float4 al = *(const float4*)&prep[768 + o0];
    float4 be = *(const float4*)&prep[896 + o0];
    int kk2 = o0 >> 5, g2 = (o0 & 31) >> 3, j0 = o0 & 7;
#pragma unroll
    for (int st = 0; st < 4; ++st) {
      f32x4 cc = acc[oi][st];
      float v0 = fmaxf(fmaf(cc[0], al.x, be.x), 0.f);
      float v1 = fmaxf(fmaf(cc[1], al.y, be.y), 0.f);
      float v2 = fmaxf(fmaf(cc[2], al.z, be.z), 0.f);
      float v3 = fmaxf(fmaf(cc[3], al.w, be.w), 0.f);
      unsigned h0, m0_, h1, m1_, h2, m2_, h3, m3_;
      split2rn(v0, h0, m0_); split2rn(v1, h1, m1_);
      split2rn(v2, h2, m2_); split2rn(v3, h3, m3_);
      int base = (kk2 * 4 + st) * 512 + (g2 * 16 + nl) * 8 + j0;
      v2i w0 = {(int)(h0 | (h1 << 16)), (int)(h2 | (h3 << 16))};
      *(v2i*)&hfrag[base] = w0;
      v2i w1 = {(int)(m0_ | (m1_ << 16)), (int)(m2_ | (m3_ << 16))};
      *(v2i*)&hfrag[base + 8192] = w1;
    }
  }
  __syncthreads();

  // ---- c2 ----
#pragma unroll
  for (int oi = 0; oi < 2; ++oi)
#pragma unroll
    for (int st = 0; st < 4; ++st) acc[oi][st] = (f32x4){0.f, 0.f, 0.f, 0.f};
  mfma_layer(WC, hfrag, 1, wave, lane, 4, acc);

  // ---- c2 epilogue: BN+ReLU -> hplain[c][p] ----
#pragma unroll
  for (int oi = 0; oi < 2; ++oi) {
    int o0 = (wave * 2 + oi) * 16 + quad * 4;
    float4 al = *(const float4*)&prep[1024 + o0];
    float4 be = *(const float4*)&prep[1152 + o0];
#pragma unroll
    for (int st = 0; st < 4; ++st) {
      f32x4 cc = acc[oi][st];
      int p = st * 16 + nl;
      hplain[(o0 + 0) * 65 + p] = fmaxf(fmaf(cc[0], al.x, be.x), 0.f);
      hplain[(o0 + 1) * 65 + p] = fmaxf(fmaf(cc[1], al.y, be.y), 0.f);
      hplain[(o0 + 2) * 65 + p] = fmaxf(fmaf(cc[2], al.z, be.z), 0.f);
      hplain[(o0 + 3) * 65 + p] = fmaxf(fmaf(cc[3], al.w, be.w), 0.f);
    }
  }
  __syncthreads();

  // ---- op head + scores ----
  if (t < 64) {
    int p = t, k = bk % 19;
    float res[5];
#pragma unroll
    for (int j = 0; j < 5; ++j) {
      const float* wr = opw + ((size_t)(k * 5 + j)) * 128;
      float a = opb[k * 5 + j];
      for (int c = 0; c < 128; ++c) a = fmaf(wr[c], hplain[c * 65 + p], a);
      res[j] = a;
    }
    int pg = p0 + p;
    float a0 = nxyz[(bk * 128 + pg) * 3 + 0];
    float a1 = nxyz[(bk * 128 + pg) * 3 + 1];
    float a2 = nxyz[(bk * 128 + pg) * 3 + 2];
    float* sc = scores + ((size_t)(bk * 128 + pg)) * 5;
    sc[0] = res[0];
    sc[1] = res[1];
    sc[2] = a0 + res[2];
    sc[3] = a1 + res[3];
    sc[4] = a2 + res[4];
  }
}

extern "C" void kernel_launch(void* const* d_in, const int* in_sizes, int n_in,
                              void* d_out, int out_size, void* d_ws, size_t ws_size,
                              hipStream_t stream) {
  (void)in_sizes; (void)n_in; (void)out_size; (void)ws_size;
  const float* xyz  = (const float*)d_in[0];
  const float* fts  = (const float*)d_in[1];
  const float* m1w  = (const float*)d_in[2];
  const float* m1b  = (const float*)d_in[3];
  const float* m1g  = (const float*)d_in[4];
  const float* m1be = (const float*)d_in[5];
  const float* m2w  = (const float*)d_in[6];
  const float* m2b  = (const float*)d_in[7];
  const float* m2g  = (const float*)d_in[8];
  const float* m2be = (const float*)d_in[9];
  const float* m3w  = (const float*)d_in[10];
  const float* m3b  = (const float*)d_in[11];
  const float* m3g  = (const float*)d_in[12];
  const float* m3be = (const float*)d_in[13];
  const float* c1w  = (const float*)d_in[14];
  const float* c1b  = (const float*)d_in[15];
  const float* c1g  = (const float*)d_in[16];
  const float* c1be = (const float*)d_in[17];
  const float* c2w  = (const float*)d_in[18];
  const float* c2b  = (const float*)d_in[19];
  const float* c2g  = (const float*)d_in[20];
  const float* c2be = (const float*)d_in[21];
  const float* opw  = (const float*)d_in[22];
  const float* opb  = (const float*)d_in[23];

  float* out = (float*)d_out;
  char* ws = (char*)d_ws;
  float* xc   = (float*)(ws + OFF_XC);
  float* nxyz = (float*)(ws + OFF_NXYZ);
  int*   bidx = (int*)(ws + OFF_BIDX);
  float* W1f  = (float*)(ws + OFF_W1F);
  float* prep = (float*)(ws + OFF_PREP);
  short* Wf   = (short*)(ws + OFF_WF);
  int*   cnt  = (int*)(ws + OFF_CNT);

  hipLaunchKernelGGL(front_kernel, dim3(375), dim3(512), 0, stream,
                     xyz, fts, m1w, m1b, m1g, m1be, m2w, m2b, m2g, m2be,
                     m3w, m3b, m3g, m3be, c1w, c1b, c1g, c1be,
                     c2w, c2b, c2g, c2be,
                     xc, nxyz, out + OUT_AGG, bidx, cnt, W1f, Wf, prep);
  hipLaunchKernelGGL(sa_kernel, dim3(NBK * 32), dim3(256), 0, stream,
                     xc, nxyz, bidx, cnt, W1f, prep, Wf, out + OUT_FEAT);
  hipLaunchKernelGGL(head_kernel, dim3(NBK * 2), dim3(256), 0, stream,
                     out + OUT_FEAT, prep, Wf, nxyz, opw, opb, out);
}

// Round 6
// 284.406 us; speedup vs baseline: 2.1969x; 1.0152x over previous
//
#include <hip/hip_runtime.h>
#include <math.h>

// ---------------- problem constants ----------------
// B=2, K=19 -> BK=38 batches; M=1024 points; C=256 feat ch; NPOINT=NSAMPLE=128
#define NBK   38

// ---------------- workspace layout (bytes) ----------------
#define OFF_XC    0u          // [38][3][1024] f32        = 466944
#define OFF_NXYZ  466944u     // [38][128][3]  f32        = 58368
#define OFF_BIDX  525312u     // [38][128][128] i32       = 2490368
#define OFF_W1F   3015680u    // [38][1024][128] f32      = 19922944
#define OFF_PREP  22938624u   // 4096 f32
#define OFF_WF    22955008u   // 196608 shorts: w2/w3 (0), unused (65536), c1/c2 (131072)
#define OFF_CNT   23348224u   // [38][128] i32 ball counts = 19456

// ---------------- d_out layout (float offsets) ----------------
#define OUT_AGG   24320       // scores at 0: (2,19,128,5)
#define OUT_FEAT  38912       // agg: (2,19,128,3), feat: (2,19,128,128)

typedef short bf16x8 __attribute__((ext_vector_type(8)));   // 8 bf16 = 4 VGPR
typedef float f32x4  __attribute__((ext_vector_type(4)));
typedef int   v4i    __attribute__((ext_vector_type(4)));
typedef int   v2i    __attribute__((ext_vector_type(2)));

// exact IEEE fp32 squared distance, no FMA contraction, ((d0^2+d1^2)+d2^2)
__device__ __forceinline__ float dist2f(float a0, float a1, float a2,
                                        float b0, float b1, float b2) {
#pragma clang fp contract(off)
  float d0 = a0 - b0;
  float d1 = a1 - b1;
  float d2 = a2 - b2;
  return d0 * d0 + d1 * d1 + d2 * d2;
}

// 2-way bf16 split with round-to-nearest-even: v ~= hi + mid, residual <= 2^-18 |v|
__device__ __forceinline__ void split2rn(float v, unsigned& sh, unsigned& sm) {
  unsigned u = __float_as_uint(v);
  unsigned rh = (u + 0x7fffu + ((u >> 16) & 1u)) & 0xffff0000u;
  sh = rh >> 16;
  float r1 = v - __uint_as_float(rh);        // exact in fp32
  unsigned u1 = __float_as_uint(r1);
  unsigned rm = (u1 + 0x7fffu + ((u1 >> 16) & 1u)) & 0xffff0000u;
  sm = rm >> 16;
}

// DPP fmax step: v = fmax(v, v shifted by ctrl); invalid lanes keep own value.
#define DPP_FMAX_STEP(v, ctrl)                                                 \
  {                                                                            \
    int _s = __builtin_amdgcn_update_dpp(__float_as_int(v), __float_as_int(v), \
                                         (ctrl), 0xf, 0xf, false);             \
    (v) = fmaxf((v), __int_as_float(_s));                                      \
  }

__device__ __forceinline__ float readlane_f(float v, int l) {
  return __int_as_float(__builtin_amdgcn_readlane(__float_as_int(v), l));
}

// ---------------- K1 "front" (512-thread blocks) ----------------
// blocks 0..37: fps (2-wave, 8 pts/lane, ~44 live VGPRs) at s_setprio(1) so
//   the latency-critical serial chain wins issue arbitration against
//   co-resident w1f throughput waves; + ball query (8 waves).
// 38..341: w1f (256 active threads); 342..357: w2/w3 split;
// 358..373: c1/c2 split; 374: prep constants.
__global__ __launch_bounds__(512, 2) void front_kernel(
    const float* __restrict__ xyz, const float* __restrict__ feats,
    const float* __restrict__ m1w, const float* __restrict__ m1b,
    const float* __restrict__ m1g, const float* __restrict__ m1be,
    const float* __restrict__ m2w, const float* __restrict__ m2b,
    const float* __restrict__ m2g, const float* __restrict__ m2be,
    const float* __restrict__ m3w, const float* __restrict__ m3b,
    const float* __restrict__ m3g, const float* __restrict__ m3be,
    const float* __restrict__ c1w, const float* __restrict__ c1b,
    const float* __restrict__ c1g, const float* __restrict__ c1be,
    const float* __restrict__ c2w, const float* __restrict__ c2b,
    const float* __restrict__ c2g, const float* __restrict__ c2be,
    float* __restrict__ xc, float* __restrict__ nxyz, float* __restrict__ agg,
    int* __restrict__ bidx, int* __restrict__ counts,
    float* __restrict__ W1f, short* __restrict__ Wf, float* __restrict__ prep)
{
  __shared__ __align__(16) char smem[32768];
  int bid = blockIdx.x, t = threadIdx.x;
  int wave = t >> 6, lane = t & 63;

  if (bid < NBK) {
    // ================= fps (waves 0-1) + ball query (8 waves) =============
    int bk = bid;
    int b = bk / 19, k = bk % 19;
    float4* sp4 = (float4*)smem;                    // 1024 float4 = 16KB
    float4* scen4 = (float4*)(smem + 16384);        // 128 float4 = 2KB
    int* sfar = (int*)(smem + 18432);               // 128 ints
    int2* cexch = (int2*)(smem + 18944);            // [parity][wave]

    for (int i = t; i < 1024; i += 512) {
      const float* src = xyz + ((size_t)((b * 1024 + i) * 19 + k)) * 3;
      float x0 = src[0], x1 = src[1], x2 = src[2];
      sp4[i] = make_float4(x0, x1, x2, 0.f);
      xc[(bk * 3 + 0) * 1024 + i] = x0;
      xc[(bk * 3 + 1) * 1024 + i] = x1;
      xc[(bk * 3 + 2) * 1024 + i] = x2;
    }
    if (t == 0) sfar[0] = 0;
    __syncthreads();

    // lane-local points: m = wave*512 + lane*8 + j (contiguous => ctz/left-wins
    // tie-breaking reproduces jnp.argmax first-max exactly)
    float px[8], py[8], pz[8], dist[8];
    if (wave < 2) {
      __builtin_amdgcn_s_setprio(1);   // latency-critical serial chain
      int mbase = (wave << 9) + (lane << 3);
#pragma unroll
      for (int j = 0; j < 8; ++j) {
        float4 p = sp4[mbase + j];
        px[j] = p.x; py[j] = p.y; pz[j] = p.z;
        dist[j] = 1e10f;
      }
    }

    int far = 0;
    for (int it = 1; it < 128; ++it) {
      if (wave < 2) {
        float4 c = sp4[far];                       // uniform-address b128 read
#pragma unroll
        for (int j = 0; j < 8; ++j) {
          float d = dist2f(px[j], py[j], pz[j], c.x, c.y, c.z);
          dist[j] = fminf(dist[j], d);
        }
        // local first-max tree over 8 (>= keeps left => smallest j on ties)
        float tv[4]; int tj[4];
#pragma unroll
        for (int i = 0; i < 4; ++i) {
          bool L = dist[2 * i] >= dist[2 * i + 1];
          tv[i] = L ? dist[2 * i] : dist[2 * i + 1];
          tj[i] = L ? (2 * i) : (2 * i + 1);
        }
        {
          bool L0 = tv[0] >= tv[1];
          float v0 = L0 ? tv[0] : tv[1]; int j0 = L0 ? tj[0] : tj[1];
          bool L1 = tv[2] >= tv[3];
          float v1 = L1 ? tv[2] : tv[3]; int j1 = L1 ? tj[2] : tj[3];
          bool L = v0 >= v1;
          tv[0] = L ? v0 : v1; tj[0] = L ? j0 : j1;
        }
        float lmax = tv[0];
        // in-row max via DPP row_shr: lanes 15/31/47/63 hold row maxes
        float g = lmax;
        DPP_FMAX_STEP(g, 0x111);   // row_shr:1
        DPP_FMAX_STEP(g, 0x112);   // row_shr:2
        DPP_FMAX_STEP(g, 0x114);   // row_shr:4
        DPP_FMAX_STEP(g, 0x118);   // row_shr:8
        float r0 = readlane_f(g, 15);
        float r1 = readlane_f(g, 31);
        float r2 = readlane_f(g, 47);
        float r3 = readlane_f(g, 63);
        float gmax = fmaxf(fmaxf(r0, r1), fmaxf(r2, r3));
        // smallest lane whose local max equals the wave max
        unsigned long long mk = __ballot(lmax == gmax);
        int wl = (int)__builtin_ctzll(mk);
        int lj = (lane << 3) + tj[0];
        int cand_m = (wave << 9) + __builtin_amdgcn_readlane(lj, wl);
        if (lane == 0) cexch[(it & 1) * 2 + wave] =
            make_int2(__float_as_int(gmax), cand_m);
      }
      __syncthreads();
      if (wave < 2) {
        int2 c0 = cexch[(it & 1) * 2 + 0];
        int2 c1 = cexch[(it & 1) * 2 + 1];
        // wave0 wins ties (owns smaller indices)
        far = (__int_as_float(c1.x) > __int_as_float(c0.x)) ? c1.y : c0.y;
        if (t == 0) sfar[it] = far;
      }
    }
    if (wave < 2) __builtin_amdgcn_s_setprio(0);
    __syncthreads();

    // ---- flush centers (LDS scen4 + global nxyz/agg) ----
    if (t < 128) {
      float4 c = sp4[sfar[t]];
      scen4[t] = c;
      nxyz[bk * 384 + t * 3 + 0] = c.x;
      nxyz[bk * 384 + t * 3 + 1] = c.y;
      nxyz[bk * 384 + t * 3 + 2] = c.z;
      agg[bk * 384 + t * 3 + 0] = c.x;
      agg[bk * 384 + t * 3 + 1] = c.y;
      agg[bk * 384 + t * 3 + 2] = c.z;
    }
    __syncthreads();

    // ---- ball query: 8 waves x 16 balls from LDS ----
    for (int p = wave * 16; p < wave * 16 + 16; ++p) {
      float4 cen = scen4[p];
      int* outp = bidx + ((size_t)(bk * 128 + p)) * 128;
      int count = 0, first = 0;
      bool got = false;
      for (int ch = 0; ch < 16 && count < 128; ++ch) {
        int m = (ch << 6) + lane;
        float4 pv = sp4[m];
        float d = dist2f(pv.x, pv.y, pv.z, cen.x, cen.y, cen.z);
        bool flag = d < 0.0225f;                 // strict fp32, RADIUS^2
        unsigned long long mask = __ballot(flag);
        if (!got && mask) { first = (ch << 6) + __builtin_ctzll(mask); got = true; }
        int pos = count + (int)__popcll(mask & ((1ull << lane) - 1ull));
        if (flag && pos < 128) outp[pos] = m;
        count += (int)__popcll(mask);
      }
      for (int j = count + lane; j < 128; j += 64) outp[j] = first;
      if (lane == 0) counts[bk * 128 + p] = count > 128 ? 128 : count;
    }
    return;
  }

  if (bid < 342) {
    // ================= w1f: 256 active threads; idle waves match 8 barriers =====
    short* ffrag = (short*)smem;                  // 32KB
    if (t >= 256) {
      for (int i = 0; i < 8; ++i) __syncthreads();
      return;
    }
    int blk = bid - NBK;
    int bk = blk >> 3, m0 = (blk & 7) << 7;
    int b = bk / 19, k = bk % 19;
    int quad = lane >> 4, nl = lane & 15;
    int mloc = t & 127, chalf = t >> 7;
    int st_w = mloc >> 4, sl_w = mloc & 15;
    const float* fbase = feats + ((size_t)(b * 4864 + k)) * 1024 + m0 + mloc;

    f32x4 acc[2][8];
#pragma unroll
    for (int oi = 0; oi < 2; ++oi)
#pragma unroll
      for (int st = 0; st < 8; ++st) acc[oi][st] = (f32x4){0.f, 0.f, 0.f, 0.f};

    for (int ch = 0; ch < 4; ++ch) {
      int cbase = ch * 64 + chalf * 32;
#pragma unroll
      for (int g = 0; g < 4; ++g) {
        float v[8];
#pragma unroll
        for (int j = 0; j < 8; ++j)
          v[j] = fbase[(size_t)(cbase + g * 8 + j) * 19456];
        unsigned sh[8], sm[8];
#pragma unroll
        for (int j = 0; j < 8; ++j) split2rn(v[j], sh[j], sm[j]);
        int base = chalf * 4096 + st_w * 512 + (g * 16 + sl_w) * 8;
        v4i ph = {(int)(sh[0] | (sh[1] << 16)), (int)(sh[2] | (sh[3] << 16)),
                  (int)(sh[4] | (sh[5] << 16)), (int)(sh[6] | (sh[7] << 16))};
        *(v4i*)&ffrag[base] = ph;
        v4i pm = {(int)(sm[0] | (sm[1] << 16)), (int)(sm[2] | (sm[3] << 16)),
                  (int)(sm[4] | (sm[5] << 16)), (int)(sm[6] | (sm[7] << 16))};
        *(v4i*)&ffrag[base + 8192] = pm;
      }
      __syncthreads();
#pragma unroll
      for (int kkl = 0; kkl < 2; ++kkl) {
        int kk = ch * 2 + kkl;
        bf16x8 a[2][2];
#pragma unroll
        for (int oi = 0; oi < 2; ++oi) {
          int o_row = (wave * 2 + oi) * 16 + nl;
          const float* wsrc = m1w + o_row * 259 + 3 + kk * 32 + quad * 8;
          float wv[8];
#pragma unroll
          for (int j = 0; j < 8; ++j) wv[j] = wsrc[j];
          unsigned sh[8], sm[8];
#pragma unroll
          for (int j = 0; j < 8; ++j) split2rn(wv[j], sh[j], sm[j]);
          short ah[8], am[8];
#pragma unroll
          for (int j = 0; j < 8; ++j) { ah[j] = (short)sh[j]; am[j] = (short)sm[j]; }
          a[oi][0] = (bf16x8){ah[0], ah[1], ah[2], ah[3], ah[4], ah[5], ah[6], ah[7]};
          a[oi][1] = (bf16x8){am[0], am[1], am[2], am[3], am[4], am[5], am[6], am[7]};
        }
#pragma unroll
        for (int st = 0; st < 8; ++st) {
          const short* hb = ffrag + kkl * 4096 + st * 512 + lane * 8;
          bf16x8 b0 = *(const bf16x8*)hb;
          bf16x8 b1 = *(const bf16x8*)(hb + 8192);
#pragma unroll
          for (int oi = 0; oi < 2; ++oi) {
            f32x4 c = acc[oi][st];
            c = __builtin_amdgcn_mfma_f32_16x16x32_bf16(a[oi][1], b0, c, 0, 0, 0);
            c = __builtin_amdgcn_mfma_f32_16x16x32_bf16(a[oi][0], b1, c, 0, 0, 0);
            c = __builtin_amdgcn_mfma_f32_16x16x32_bf16(a[oi][0], b0, c, 0, 0, 0);
            acc[oi][st] = c;
          }
        }
      }
      __syncthreads();
    }
    float inv = 1.0f / sqrtf(1.0f + 1e-5f);
#pragma unroll
    for (int oi = 0; oi < 2; ++oi) {
      int o0 = (wave * 2 + oi) * 16 + quad * 4;
      float4 bb = *(const float4*)&m1b[o0];
      float4 gg = *(const float4*)&m1g[o0];
#pragma unroll
      for (int st = 0; st < 8; ++st) {
        int m_out = m0 + st * 16 + nl;
        f32x4 cc = acc[oi][st];
        float4 r;
        r.x = (cc[0] + bb.x) * (gg.x * inv);
        r.y = (cc[1] + bb.y) * (gg.y * inv);
        r.z = (cc[2] + bb.z) * (gg.z * inv);
        r.w = (cc[3] + bb.w) * (gg.w * inv);
        *(float4*)&W1f[((size_t)(bk * 1024 + m_out)) * 128 + o0] = r;
      }
    }
    return;
  }

  if (bid < 358) {
    // ================= w2/w3 split =================
    int idx = (bid - 342) * 512 + t;               // 0..8191
#pragma unroll
    for (int e = 0; e < 4; ++e) {
      int i = idx * 4 + e;                         // 0..32767
      int c = i & 127, o = (i >> 7) & 127, l = i >> 14;
      float w = (l ? m3w : m2w)[o * 128 + c];
      unsigned sh, sm;
      split2rn(w, sh, sm);
      int ot = o >> 4, mm = o & 15, kk = c >> 5, q = (c & 31) >> 3, j = c & 7;
      int within = (q * 16 + mm) * 8 + j;
      Wf[(((l * 2 + 0) * 4 + kk) * 8 + ot) * 512 + within] = (short)sh;
      Wf[(((l * 2 + 1) * 4 + kk) * 8 + ot) * 512 + within] = (short)sm;
    }
    return;
  }

  if (bid < 374) {
    // ================= c1/c2 split =================
    int idx2 = (bid - 358) * 512 + t;              // 0..8191
#pragma unroll
    for (int e = 0; e < 4; ++e) {
      int i = idx2 * 4 + e;                        // 0..32767
      int c = i & 127, o = (i >> 7) & 127, l = i >> 14;
      float w = (l ? c2w : c1w)[o * 128 + c];
      unsigned sh, sm;
      split2rn(w, sh, sm);
      int ot = o >> 4, mm = o & 15, kk = c >> 5, q = (c & 31) >> 3, j = c & 7;
      int within = (q * 16 + mm) * 8 + j;
      Wf[131072 + (((l * 2 + 0) * 4 + kk) * 8 + ot) * 512 + within] = (short)sh;
      Wf[131072 + (((l * 2 + 1) * 4 + kk) * 8 + ot) * 512 + within] = (short)sm;
    }
    return;
  }

  // ================= prep constants =================
  if (t < 128) {
    float inv = 1.0f / sqrtf(1.0f + 1e-5f);
    float a1 = m1g[t] * inv;
    prep[t] = a1;
    float a2 = m2g[t] * inv;  prep[256 + t] = a2;  prep[384 + t] = fmaf(m2b[t], a2, m2be[t]);
    float a3 = m3g[t] * inv;  prep[512 + t] = a3;  prep[640 + t] = fmaf(m3b[t], a3, m3be[t]);
    float ac1 = c1g[t] * inv; prep[768 + t] = ac1; prep[896 + t] = fmaf(c1b[t], ac1, c1be[t]);
    float ac2 = c2g[t] * inv; prep[1024 + t] = ac2; prep[1152 + t] = fmaf(c2b[t], ac2, c2be[t]);
    prep[1280 + 4 * t + 0] = m1w[t * 259 + 0] * a1;
    prep[1280 + 4 * t + 1] = m1w[t * 259 + 1] * a1;
    prep[1280 + 4 * t + 2] = m1w[t * 259 + 2] * a1;
    prep[1280 + 4 * t + 3] = m1be[t];
  }
}

// ---------------- MFMA GEMM over one 128(c) x nst_h*16(s) fragment buffer ----------
__device__ __forceinline__ void mfma_layer(const short* __restrict__ Wf,
                                           const short* hfrag, int l,
                                           int wave, int lane, int nst_h,
                                           f32x4 acc[2][4])
{
#pragma unroll 1
  for (int kk = 0; kk < 4; ++kk) {
    bf16x8 a[2][2];
#pragma unroll
    for (int oi = 0; oi < 2; ++oi)
#pragma unroll
      for (int sp = 0; sp < 2; ++sp)
        a[oi][sp] = *(const bf16x8*)(Wf + (((l * 2 + sp) * 4 + kk) * 8 + (wave * 2 + oi)) * 512 + lane * 8);
    for (int st = 0; st < nst_h; ++st) {
      const short* hb = hfrag + kk * 2048 + st * 512 + lane * 8;
      bf16x8 b0 = *(const bf16x8*)(hb);           // hi
      bf16x8 b1 = *(const bf16x8*)(hb + 8192);    // mid
#pragma unroll
      for (int oi = 0; oi < 2; ++oi) {
        f32x4 c = acc[oi][st];
        c = __builtin_amdgcn_mfma_f32_16x16x32_bf16(a[oi][1], b0, c, 0, 0, 0);
        c = __builtin_amdgcn_mfma_f32_16x16x32_bf16(a[oi][0], b1, c, 0, 0, 0);
        c = __builtin_amdgcn_mfma_f32_16x16x32_bf16(a[oi][0], b0, c, 0, 0, 0);
        acc[oi][st] = c;
      }
    }
  }
}

// ---------------- fused SA: 4 balls per block, tiles packed over passes ----------
__global__ __launch_bounds__(256, 3) void sa_kernel(
    const float* __restrict__ xc, const float* __restrict__ nxyz,
    const int* __restrict__ bidx, const int* __restrict__ counts,
    const float* __restrict__ W1f, const float* __restrict__ prep,
    const short* __restrict__ Wf, float* __restrict__ feat_out)
{
  __shared__ __align__(16) short hfrag[16384];   // 32KB
  __shared__ float pcs[512];
  __shared__ float sm[32 * 128];                 // 16KB per-tile o-max
  __shared__ float ccen[12];
  __shared__ int scnt[4];
  int gb = blockIdx.x, bk = gb >> 5, pb = (gb & 31) << 2;
  int t = threadIdx.x;
  int wave = t >> 6, lane = t & 63;
  int quad = lane >> 4, nl = lane & 15;

  pcs[t] = prep[1280 + t];
  pcs[256 + t] = prep[1536 + t];
  if (t < 4) scnt[t] = counts[bk * 128 + pb + t];
  if (t < 12) {
    int bb = t / 3, c = t % 3;
    ccen[t] = nxyz[(bk * 128 + pb + bb) * 3 + c];
  }
  __syncthreads();
  int n0 = (scnt[0] + 15) >> 4, n1 = (scnt[1] + 15) >> 4;
  int n2 = (scnt[2] + 15) >> 4, n3 = (scnt[3] + 15) >> 4;
  int pf1 = n0, pf2 = n0 + n1, pf3 = n0 + n1 + n2, T = n0 + n1 + n2 + n3;

  for (int q0 = 0; q0 < T; q0 += 4) {
    int nst_h = T - q0;
    if (nst_h > 4) nst_h = 4;
    // ---- h1 build ----
    {
      int cg = wave;
      int st = lane >> 4, sl = lane & 15;
      if (st < nst_h) {
        int q = q0 + st;
        int bq = (q >= pf1) + (q >= pf2) + (q >= pf3);
        int tstart = (bq == 0) ? 0 : (bq == 1) ? pf1 : (bq == 2) ? pf2 : pf3;
        int tslot = q - tstart;
        int m = bidx[((size_t)(bk * 128 + pb + bq)) * 128 + tslot * 16 + sl];
        float cen0 = ccen[bq * 3 + 0], cen1 = ccen[bq * 3 + 1], cen2 = ccen[bq * 3 + 2];
        float g0 = (xc[(bk * 3 + 0) * 1024 + m] - cen0) * (1.0f / 0.15f);
        float g1 = (xc[(bk * 3 + 1) * 1024 + m] - cen1) * (1.0f / 0.15f);
        float g2 = (xc[(bk * 3 + 2) * 1024 + m] - cen2) * (1.0f / 0.15f);
        const float4* wrow = (const float4*)(W1f + ((size_t)(bk * 1024 + m)) * 128 + cg * 32);
        const float4* pcp = (const float4*)pcs + cg * 32;
#pragma unroll
        for (int g = 0; g < 4; ++g) {
          float4 wva = wrow[g * 2], wvb = wrow[g * 2 + 1];
          float wv[8] = {wva.x, wva.y, wva.z, wva.w, wvb.x, wvb.y, wvb.z, wvb.w};
          unsigned sh[8], smv[8];
#pragma unroll
          for (int e = 0; e < 8; ++e) {
            float4 pc = pcp[g * 8 + e];
            float hv = fmaxf(wv[e] + pc.x * g0 + pc.y * g1 + pc.z * g2 + pc.w, 0.f);
            split2rn(hv, sh[e], smv[e]);
          }
          int base = (cg * 4 + st) * 512 + (g * 16 + sl) * 8;
          v4i ph = {(int)(sh[0] | (sh[1] << 16)), (int)(sh[2] | (sh[3] << 16)),
                    (int)(sh[4] | (sh[5] << 16)), (int)(sh[6] | (sh[7] << 16))};
          *(v4i*)&hfrag[base] = ph;
          v4i pm = {(int)(smv[0] | (smv[1] << 16)), (int)(smv[2] | (smv[3] << 16)),
                    (int)(smv[4] | (smv[5] << 16)), (int)(smv[6] | (smv[7] << 16))};
          *(v4i*)&hfrag[base + 8192] = pm;
        }
      }
    }
    __syncthreads();

    // ---- layer 2 ----
    f32x4 acc[2][4];
#pragma unroll
    for (int oi = 0; oi < 2; ++oi)
#pragma unroll
      for (int st = 0; st < 4; ++st) acc[oi][st] = (f32x4){0.f, 0.f, 0.f, 0.f};
    mfma_layer(Wf, hfrag, 0, wave, lane, nst_h, acc);
    __syncthreads();

    // ---- h2 epilogue ----
#pragma unroll
    for (int oi = 0; oi < 2; ++oi) {
      int o0 = (wave * 2 + oi) * 16 + quad * 4;
      float4 al = *(const float4*)&prep[256 + o0];
      float4 be = *(const float4*)&prep[384 + o0];
      int kk2 = o0 >> 5, g2 = (o0 & 31) >> 3, j0 = o0 & 7;
      for (int st = 0; st < nst_h; ++st) {
        f32x4 cc = acc[oi][st];
        float v0 = fmaxf(fmaf(cc[0], al.x, be.x), 0.f);
        float v1 = fmaxf(fmaf(cc[1], al.y, be.y), 0.f);
        float v2 = fmaxf(fmaf(cc[2], al.z, be.z), 0.f);
        float v3 = fmaxf(fmaf(cc[3], al.w, be.w), 0.f);
        unsigned h0, m0_, h1, m1_, h2, m2_, h3, m3_;
        split2rn(v0, h0, m0_); split2rn(v1, h1, m1_);
        split2rn(v2, h2, m2_); split2rn(v3, h3, m3_);
        int base = (kk2 * 4 + st) * 512 + (g2 * 16 + nl) * 8 + j0;
        v2i w0 = {(int)(h0 | (h1 << 16)), (int)(h2 | (h3 << 16))};
        *(v2i*)&hfrag[base] = w0;
        v2i w1 = {(int)(m0_ | (m1_ << 16)), (int)(m2_ | (m3_ << 16))};
        *(v2i*)&hfrag[base + 8192] = w1;
      }
    }
    __syncthreads();

    // ---- layer 3 ----
#pragma unroll
    for (int oi = 0; oi < 2; ++oi)
#pragma unroll
      for (int st = 0; st < 4; ++st) acc[oi][st] = (f32x4){0.f, 0.f, 0.f, 0.f};
    mfma_layer(Wf, hfrag, 1, wave, lane, nst_h, acc);

    // ---- layer-3 epilogue: BN+ReLU, quad-reduce max per tile ----
#pragma unroll
    for (int oi = 0; oi < 2; ++oi) {
      int o0 = (wave * 2 + oi) * 16 + quad * 4;
      float4 al = *(const float4*)&prep[512 + o0];
      float4 be = *(const float4*)&prep[640 + o0];
      for (int st = 0; st < nst_h; ++st) {
        f32x4 cc = acc[oi][st];
        float v[4];
        v[0] = fmaxf(fmaf(cc[0], al.x, be.x), 0.f);
        v[1] = fmaxf(fmaf(cc[1], al.y, be.y), 0.f);
        v[2] = fmaxf(fmaf(cc[2], al.z, be.z), 0.f);
        v[3] = fmaxf(fmaf(cc[3], al.w, be.w), 0.f);
#pragma unroll
        for (int r = 0; r < 4; ++r) {
          float x = v[r];
          x = fmaxf(x, __shfl_xor(x, 1));
          x = fmaxf(x, __shfl_xor(x, 2));
          x = fmaxf(x, __shfl_xor(x, 4));
          x = fmaxf(x, __shfl_xor(x, 8));
          if (nl == 0) sm[(q0 + st) * 128 + o0 + r] = x;
        }
      }
    }
    __syncthreads();
  }

  // ---- final: merge tiles per ball, write feat ----
#pragma unroll
  for (int e = t; e < 512; e += 256) {
    int bb = e >> 7, o = e & 127;
    int qs = (bb == 0) ? 0 : (bb == 1) ? pf1 : (bb == 2) ? pf2 : pf3;
    int nq = (bb == 0) ? n0 : (bb == 1) ? n1 : (bb == 2) ? n2 : n3;
    float v = sm[qs * 128 + o];
    for (int q = 1; q < nq; ++q) v = fmaxf(v, sm[(qs + q) * 128 + o]);
    feat_out[(((size_t)bk) << 14) + (o << 7) + pb + bb] = v;
  }
}

// ---------------- head: c1 -> c2 (split2 MFMA) -> op -> scores; 2 blocks/bk ------
__global__ __launch_bounds__(256) void head_kernel(const float* __restrict__ featg,
    const float* __restrict__ prep, const short* __restrict__ Wf,
    const float* __restrict__ nxyz, const float* __restrict__ opw,
    const float* __restrict__ opb, float* __restrict__ scores)
{
  __shared__ __align__(16) short hfrag[16384];   // 32KB frags (128c x 64p)
  __shared__ float hplain[128 * 65];             // stride 65 vs conflicts
  int bk = blockIdx.x >> 1, p0 = (blockIdx.x & 1) << 6;
  int t = threadIdx.x;
  int wave = t >> 6, lane = t & 63;
  int quad = lane >> 4, nl = lane & 15;
  const short* WC = Wf + 131072;

  // ---- stage feat[c][p0..p0+63] into split2 B-frags ----
  {
    int cg = wave;
    int st = lane >> 4, sl = lane & 15;
    const float* fb = featg + (bk << 14) + p0 + lane;
#pragma unroll
    for (int g = 0; g < 4; ++g) {
      float v[8];
#pragma unroll
      for (int e = 0; e < 8; ++e)
        v[e] = fb[(cg * 32 + g * 8 + e) << 7];
      unsigned sh[8], sm[8];
#pragma unroll
      for (int e = 0; e < 8; ++e) split2rn(v[e], sh[e], sm[e]);
      int base = (cg * 4 + st) * 512 + (g * 16 + sl) * 8;
      v4i ph = {(int)(sh[0] | (sh[1] << 16)), (int)(sh[2] | (sh[3] << 16)),
                (int)(sh[4] | (sh[5] << 16)), (int)(sh[6] | (sh[7] << 16))};
      *(v4i*)&hfrag[base] = ph;
      v4i pm = {(int)(sm[0] | (sm[1] << 16)), (int)(sm[2] | (sm[3] << 16)),
                (int)(sm[4] | (sm[5] << 16)), (int)(sm[6] | (sm[7] << 16))};
      *(v4i*)&hfrag[base + 8192] = pm;
    }
  }
  __syncthreads();

  // ---- c1 ----
  f32x4 acc[2][4];
#pragma unroll
  for (int oi = 0; oi < 2; ++oi)
#pragma unroll
    for (int st = 0; st < 4; ++st) acc[oi][st] = (f32x4){0.f, 0.f, 0.f, 0.f};
  mfma_layer(WC, hfrag, 0, wave, lane, 4, acc);
  __syncthreads();

  // ---- c1 epilogue: BN+ReLU, write back frags ----
#pragma unroll
  for (int oi = 0; oi < 2; ++oi) {
    int o0 = (wave * 2 + oi) * 16 + quad * 4;
    float4 al = *(const float4*)&prep[768 + o0];
    float4 be = *(const float4*)&prep[896 + o0];
    int kk2 = o0 >> 5, g2 = (o0 & 31) >> 3, j0 = o0 & 7;
#pragma unroll
    for (int st = 0; st < 4; ++st) {
      f32x4 cc = acc[oi][st];
      float v0 = fmaxf(fmaf(cc[0], al.x, be.x), 0.f);
      float v1 = fmaxf(fmaf(cc[1], al.y, be.y), 0.f);
      float v2 = fmaxf(fmaf(cc[2], al.z, be.z), 0.f);
      float v3 = fmaxf(fmaf(cc[3], al.w, be.w), 0.f);
      unsigned h0, m0_, h1, m1_, h2, m2_, h3, m3_;
      split2rn(v0, h0, m0_); split2rn(v1, h1, m1_);
      split2rn(v2, h2, m2_); split2rn(v3, h3, m3_);
      int base = (kk2 * 4 + st) * 512 + (g2 * 16 + nl) * 8 + j0;
      v2i w0 = {(int)(h0 | (h1 << 16)), (int)(h2 | (h3 << 16))};
      *(v2i*)&hfrag[base] = w0;
      v2i w1 = {(int)(m0_ | (m1_ << 16)), (int)(m2_ | (m3_ << 16))};
      *(v2i*)&hfrag[base + 8192] = w1;
    }
  }
  __syncthreads();

  // ---- c2 ----
#pragma unroll
  for (int oi = 0; oi < 2; ++oi)
#pragma unroll
    for (int st = 0; st < 4; ++st) acc[oi][st] = (f32x4){0.f, 0.f, 0.f, 0.f};
  mfma_layer(WC, hfrag, 1, wave, lane, 4, acc);

  // ---- c2 epilogue: BN+ReLU -> hplain[c][p] ----
#pragma unroll
  for (int oi = 0; oi < 2; ++oi) {
    int o0 = (wave * 2 + oi) * 16 + quad * 4;
    float4 al = *(const float4*)&prep[1024 + o0];
    float4 be = *(const float4*)&prep[1152 + o0];
#pragma unroll
    for (int st = 0; st < 4; ++st) {
      f32x4 cc = acc[oi][st];
      int p = st * 16 + nl;
      hplain[(o0 + 0) * 65 + p] = fmaxf(fmaf(cc[0], al.x, be.x), 0.f);
      hplain[(o0 + 1) * 65 + p] = fmaxf(fmaf(cc[1], al.y, be.y), 0.f);
      hplain[(o0 + 2) * 65 + p] = fmaxf(fmaf(cc[2], al.z, be.z), 0.f);
      hplain[(o0 + 3) * 65 + p] = fmaxf(fmaf(cc[3], al.w, be.w), 0.f);
    }
  }
  __syncthreads();

  // ---- op head + scores ----
  if (t < 64) {
    int p = t, k = bk % 19;
    float res[5];
#pragma unroll
    for (int j = 0; j < 5; ++j) {
      const float* wr = opw + ((size_t)(k * 5 + j)) * 128;
      float a = opb[k * 5 + j];
      for (int c = 0; c < 128; ++c) a = fmaf(wr[c], hplain[c * 65 + p], a);
      res[j] = a;
    }
    int pg = p0 + p;
    float a0 = nxyz[(bk * 128 + pg) * 3 + 0];
    float a1 = nxyz[(bk * 128 + pg) * 3 + 1];
    float a2 = nxyz[(bk * 128 + pg) * 3 + 2];
    float* sc = scores + ((size_t)(bk * 128 + pg)) * 5;
    sc[0] = res[0];
    sc[1] = res[1];
    sc[2] = a0 + res[2];
    sc[3] = a1 + res[3];
    sc[4] = a2 + res[4];
  }
}

extern "C" void kernel_launch(void* const* d_in, const int* in_sizes, int n_in,
                              void* d_out, int out_size, void* d_ws, size_t ws_size,
                              hipStream_t stream) {
  (void)in_sizes; (void)n_in; (void)out_size; (void)ws_size;
  const float* xyz  = (const float*)d_in[0];
  const float* fts  = (const float*)d_in[1];
  const float* m1w  = (const float*)d_in[2];
  const float* m1b  = (const float*)d_in[3];
  const float* m1g  = (const float*)d_in[4];
  const float* m1be = (const float*)d_in[5];
  const float* m2w  = (const float*)d_in[6];
  const float* m2b  = (const float*)d_in[7];
  const float* m2g  = (const float*)d_in[8];
  const float* m2be = (const float*)d_in[9];
  const float* m3w  = (const float*)d_in[10];
  const float* m3b  = (const float*)d_in[11];
  const float* m3g  = (const float*)d_in[12];
  const float* m3be = (const float*)d_in[13];
  const float* c1w  = (const float*)d_in[14];
  const float* c1b  = (const float*)d_in[15];
  const float* c1g  = (const float*)d_in[16];
  const float* c1be = (const float*)d_in[17];
  const float* c2w  = (const float*)d_in[18];
  const float* c2b  = (const float*)d_in[19];
  const float* c2g  = (const float*)d_in[20];
  const float* c2be = (const float*)d_in[21];
  const float* opw  = (const float*)d_in[22];
  const float* opb  = (const float*)d_in[23];

  float* out = (float*)d_out;
  char* ws = (char*)d_ws;
  float* xc   = (float*)(ws + OFF_XC);
  float* nxyz = (float*)(ws + OFF_NXYZ);
  int*   bidx = (int*)(ws + OFF_BIDX);
  float* W1f  = (float*)(ws + OFF_W1F);
  float* prep = (float*)(ws + OFF_PREP);
  short* Wf   = (short*)(ws + OFF_WF);
  int*   cnt  = (int*)(ws + OFF_CNT);

  hipLaunchKernelGGL(front_kernel, dim3(375), dim3(512), 0, stream,
                     xyz, fts, m1w, m1b, m1g, m1be, m2w, m2b, m2g, m2be,
                     m3w, m3b, m3g, m3be, c1w, c1b, c1g, c1be,
                     c2w, c2b, c2g, c2be,
                     xc, nxyz, out + OUT_AGG, bidx, cnt, W1f, Wf, prep);
  hipLaunchKernelGGL(sa_kernel, dim3(NBK * 32), dim3(256), 0, stream,
                     xc, nxyz, bidx, cnt, W1f, prep, Wf, out + OUT_FEAT);
  hipLaunchKernelGGL(head_kernel, dim3(NBK * 2), dim3(256), 0, stream,
                     out + OUT_FEAT, prep, Wf, nxyz, opw, opb, out);
}

// Round 7
// 283.847 us; speedup vs baseline: 2.2012x; 1.0020x over previous
//
#include <hip/hip_runtime.h>
#include <math.h>

// ---------------- problem constants ----------------
// B=2, K=19 -> BK=38 batches; M=1024 points; C=256 feat ch; NPOINT=NSAMPLE=128
#define NBK   38

// ---------------- workspace layout (bytes) ----------------
#define OFF_XC    0u          // [38][3][1024] f32        = 466944
#define OFF_NXYZ  466944u     // [38][128][3]  f32        = 58368
#define OFF_BIDX  525312u     // [38][128][128] i32       = 2490368
#define OFF_W1F   3015680u    // [38][1024][128] f32      = 19922944
#define OFF_PREP  22938624u   // 4096 f32
#define OFF_WF    22955008u   // 196608 shorts: w2/w3 (0), unused (65536), c1/c2 (131072)
#define OFF_CNT   23348224u   // [38][128] i32 ball counts = 19456

// ---------------- d_out layout (float offsets) ----------------
#define OUT_AGG   24320       // scores at 0: (2,19,128,5)
#define OUT_FEAT  38912       // agg: (2,19,128,3), feat: (2,19,128,128)

typedef short bf16x8 __attribute__((ext_vector_type(8)));   // 8 bf16 = 4 VGPR
typedef float f32x4  __attribute__((ext_vector_type(4)));
typedef int   v4i    __attribute__((ext_vector_type(4)));
typedef int   v2i    __attribute__((ext_vector_type(2)));

// exact IEEE fp32 squared distance, no FMA contraction, ((d0^2+d1^2)+d2^2)
__device__ __forceinline__ float dist2f(float a0, float a1, float a2,
                                        float b0, float b1, float b2) {
#pragma clang fp contract(off)
  float d0 = a0 - b0;
  float d1 = a1 - b1;
  float d2 = a2 - b2;
  return d0 * d0 + d1 * d1 + d2 * d2;
}

// 2-way bf16 split with round-to-nearest-even: v ~= hi + mid, residual <= 2^-18 |v|
__device__ __forceinline__ void split2rn(float v, unsigned& sh, unsigned& sm) {
  unsigned u = __float_as_uint(v);
  unsigned rh = (u + 0x7fffu + ((u >> 16) & 1u)) & 0xffff0000u;
  sh = rh >> 16;
  float r1 = v - __uint_as_float(rh);        // exact in fp32
  unsigned u1 = __float_as_uint(r1);
  unsigned rm = (u1 + 0x7fffu + ((u1 >> 16) & 1u)) & 0xffff0000u;
  sm = rm >> 16;
}

// DPP fmax step: v = fmax(v, v shifted by ctrl); invalid lanes keep own value.
#define DPP_FMAX_STEP(v, ctrl)                                                 \
  {                                                                            \
    int _s = __builtin_amdgcn_update_dpp(__float_as_int(v), __float_as_int(v), \
                                         (ctrl), 0xf, 0xf, false);             \
    (v) = fmaxf((v), __int_as_float(_s));                                      \
  }

__device__ __forceinline__ float readlane_f(float v, int l) {
  return __int_as_float(__builtin_amdgcn_readlane(__float_as_int(v), l));
}

// ---------------- K1 "front" (512-thread blocks, 223 total <= 256 CUs) ------
// Grid fits one block per CU -> fps blocks get uncontended CUs (no LDS-pipe
// contention from co-resident w1f blocks; R5/R6 showed that contention ~2x'd
// the fps serial chain and setprio could not fix it).
// blocks 0..37: fps (2-wave, 8 pts/lane, ~44 live VGPRs) + ball query;
// 38..189: w1f (8 waves, one o-tile/wave, 2 m-chunks per block);
// 190..205: w2/w3 split; 206..221: c1/c2 split; 222: prep constants.
__global__ __launch_bounds__(512, 2) void front_kernel(
    const float* __restrict__ xyz, const float* __restrict__ feats,
    const float* __restrict__ m1w, const float* __restrict__ m1b,
    const float* __restrict__ m1g, const float* __restrict__ m1be,
    const float* __restrict__ m2w, const float* __restrict__ m2b,
    const float* __restrict__ m2g, const float* __restrict__ m2be,
    const float* __restrict__ m3w, const float* __restrict__ m3b,
    const float* __restrict__ m3g, const float* __restrict__ m3be,
    const float* __restrict__ c1w, const float* __restrict__ c1b,
    const float* __restrict__ c1g, const float* __restrict__ c1be,
    const float* __restrict__ c2w, const float* __restrict__ c2b,
    const float* __restrict__ c2g, const float* __restrict__ c2be,
    float* __restrict__ xc, float* __restrict__ nxyz, float* __restrict__ agg,
    int* __restrict__ bidx, int* __restrict__ counts,
    float* __restrict__ W1f, short* __restrict__ Wf, float* __restrict__ prep)
{
  __shared__ __align__(16) char smem[32768];
  int bid = blockIdx.x, t = threadIdx.x;
  int wave = t >> 6, lane = t & 63;

  if (bid < NBK) {
    // ================= fps (waves 0-1) + ball query (8 waves) =============
    int bk = bid;
    int b = bk / 19, k = bk % 19;
    float4* sp4 = (float4*)smem;                    // 1024 float4 = 16KB
    float4* scen4 = (float4*)(smem + 16384);        // 128 float4 = 2KB
    int* sfar = (int*)(smem + 18432);               // 128 ints
    int2* cexch = (int2*)(smem + 18944);            // [parity][wave]

    for (int i = t; i < 1024; i += 512) {
      const float* src = xyz + ((size_t)((b * 1024 + i) * 19 + k)) * 3;
      float x0 = src[0], x1 = src[1], x2 = src[2];
      sp4[i] = make_float4(x0, x1, x2, 0.f);
      xc[(bk * 3 + 0) * 1024 + i] = x0;
      xc[(bk * 3 + 1) * 1024 + i] = x1;
      xc[(bk * 3 + 2) * 1024 + i] = x2;
    }
    if (t == 0) sfar[0] = 0;
    __syncthreads();

    // lane-local points: m = wave*512 + lane*8 + j (contiguous => ctz/left-wins
    // tie-breaking reproduces jnp.argmax first-max exactly)
    float px[8], py[8], pz[8], dist[8];
    if (wave < 2) {
      __builtin_amdgcn_s_setprio(1);   // latency-critical serial chain
      int mbase = (wave << 9) + (lane << 3);
#pragma unroll
      for (int j = 0; j < 8; ++j) {
        float4 p = sp4[mbase + j];
        px[j] = p.x; py[j] = p.y; pz[j] = p.z;
        dist[j] = 1e10f;
      }
    }

    int far = 0;
    for (int it = 1; it < 128; ++it) {
      if (wave < 2) {
        float4 c = sp4[far];                       // uniform-address b128 read
#pragma unroll
        for (int j = 0; j < 8; ++j) {
          float d = dist2f(px[j], py[j], pz[j], c.x, c.y, c.z);
          dist[j] = fminf(dist[j], d);
        }
        // local first-max tree over 8 (>= keeps left => smallest j on ties)
        float tv[4]; int tj[4];
#pragma unroll
        for (int i = 0; i < 4; ++i) {
          bool L = dist[2 * i] >= dist[2 * i + 1];
          tv[i] = L ? dist[2 * i] : dist[2 * i + 1];
          tj[i] = L ? (2 * i) : (2 * i + 1);
        }
        {
          bool L0 = tv[0] >= tv[1];
          float v0 = L0 ? tv[0] : tv[1]; int j0 = L0 ? tj[0] : tj[1];
          bool L1 = tv[2] >= tv[3];
          float v1 = L1 ? tv[2] : tv[3]; int j1 = L1 ? tj[2] : tj[3];
          bool L = v0 >= v1;
          tv[0] = L ? v0 : v1; tj[0] = L ? j0 : j1;
        }
        float lmax = tv[0];
        // in-row max via DPP row_shr: lanes 15/31/47/63 hold row maxes
        float g = lmax;
        DPP_FMAX_STEP(g, 0x111);   // row_shr:1
        DPP_FMAX_STEP(g, 0x112);   // row_shr:2
        DPP_FMAX_STEP(g, 0x114);   // row_shr:4
        DPP_FMAX_STEP(g, 0x118);   // row_shr:8
        float r0 = readlane_f(g, 15);
        float r1 = readlane_f(g, 31);
        float r2 = readlane_f(g, 47);
        float r3 = readlane_f(g, 63);
        float gmax = fmaxf(fmaxf(r0, r1), fmaxf(r2, r3));
        // smallest lane whose local max equals the wave max
        unsigned long long mk = __ballot(lmax == gmax);
        int wl = (int)__builtin_ctzll(mk);
        int lj = (lane << 3) + tj[0];
        int cand_m = (wave << 9) + __builtin_amdgcn_readlane(lj, wl);
        if (lane == 0) cexch[(it & 1) * 2 + wave] =
            make_int2(__float_as_int(gmax), cand_m);
      }
      __syncthreads();
      if (wave < 2) {
        int2 c0 = cexch[(it & 1) * 2 + 0];
        int2 c1 = cexch[(it & 1) * 2 + 1];
        // wave0 wins ties (owns smaller indices)
        far = (__int_as_float(c1.x) > __int_as_float(c0.x)) ? c1.y : c0.y;
        if (t == 0) sfar[it] = far;
      }
    }
    if (wave < 2) __builtin_amdgcn_s_setprio(0);
    __syncthreads();

    // ---- flush centers (LDS scen4 + global nxyz/agg) ----
    if (t < 128) {
      float4 c = sp4[sfar[t]];
      scen4[t] = c;
      nxyz[bk * 384 + t * 3 + 0] = c.x;
      nxyz[bk * 384 + t * 3 + 1] = c.y;
      nxyz[bk * 384 + t * 3 + 2] = c.z;
      agg[bk * 384 + t * 3 + 0] = c.x;
      agg[bk * 384 + t * 3 + 1] = c.y;
      agg[bk * 384 + t * 3 + 2] = c.z;
    }
    __syncthreads();

    // ---- ball query: 8 waves x 16 balls from LDS ----
    for (int p = wave * 16; p < wave * 16 + 16; ++p) {
      float4 cen = scen4[p];
      int* outp = bidx + ((size_t)(bk * 128 + p)) * 128;
      int count = 0, first = 0;
      bool got = false;
      for (int ch = 0; ch < 16 && count < 128; ++ch) {
        int m = (ch << 6) + lane;
        float4 pv = sp4[m];
        float d = dist2f(pv.x, pv.y, pv.z, cen.x, cen.y, cen.z);
        bool flag = d < 0.0225f;                 // strict fp32, RADIUS^2
        unsigned long long mask = __ballot(flag);
        if (!got && mask) { first = (ch << 6) + __builtin_ctzll(mask); got = true; }
        int pos = count + (int)__popcll(mask & ((1ull << lane) - 1ull));
        if (flag && pos < 128) outp[pos] = m;
        count += (int)__popcll(mask);
      }
      for (int j = count + lane; j < 128; j += 64) outp[j] = first;
      if (lane == 0) counts[bk * 128 + p] = count > 128 ? 128 : count;
    }
    return;
  }

  if (bid < 190) {
    // ======== w1f: 8 waves (one 16-o tile each), 2 m-chunks per block ========
    short* ffrag = (short*)smem;                  // 32KB
    int blk = bid - NBK;                          // 0..151
    int bk = blk >> 2, mq = blk & 3;
    int b = bk / 19, k = bk % 19;
    int quad = lane >> 4, nl = lane & 15;
    int mloc = t & 127, cq = t >> 7;              // cq 0..3
    int chalf = cq >> 1, ghalf = cq & 1;
    int st_w = mloc >> 4, sl_w = mloc & 15;

    for (int half = 0; half < 2; ++half) {
      int m0 = (mq << 8) + (half << 7);
      const float* fbase = feats + ((size_t)(b * 4864 + k)) * 1024 + m0 + mloc;

      f32x4 acc[8];
#pragma unroll
      for (int st = 0; st < 8; ++st) acc[st] = (f32x4){0.f, 0.f, 0.f, 0.f};

      for (int ch = 0; ch < 4; ++ch) {
        int cbase = ch * 64 + chalf * 32;
#pragma unroll
        for (int g2 = 0; g2 < 2; ++g2) {
          int g = ghalf * 2 + g2;
          float v[8];
#pragma unroll
          for (int j = 0; j < 8; ++j)
            v[j] = fbase[(size_t)(cbase + g * 8 + j) * 19456];
          unsigned sh[8], sm[8];
#pragma unroll
          for (int j = 0; j < 8; ++j) split2rn(v[j], sh[j], sm[j]);
          int base = chalf * 4096 + st_w * 512 + (g * 16 + sl_w) * 8;
          v4i ph = {(int)(sh[0] | (sh[1] << 16)), (int)(sh[2] | (sh[3] << 16)),
                    (int)(sh[4] | (sh[5] << 16)), (int)(sh[6] | (sh[7] << 16))};
          *(v4i*)&ffrag[base] = ph;
          v4i pm = {(int)(sm[0] | (sm[1] << 16)), (int)(sm[2] | (sm[3] << 16)),
                    (int)(sm[4] | (sm[5] << 16)), (int)(sm[6] | (sm[7] << 16))};
          *(v4i*)&ffrag[base + 8192] = pm;
        }
        __syncthreads();
#pragma unroll
        for (int kkl = 0; kkl < 2; ++kkl) {
          int kk = ch * 2 + kkl;
          bf16x8 a0, a1;
          {
            int o_row = wave * 16 + nl;
            const float* wsrc = m1w + o_row * 259 + 3 + kk * 32 + quad * 8;
            float wv[8];
#pragma unroll
            for (int j = 0; j < 8; ++j) wv[j] = wsrc[j];
            unsigned sh[8], sm[8];
#pragma unroll
            for (int j = 0; j < 8; ++j) split2rn(wv[j], sh[j], sm[j]);
            short ah[8], am[8];
#pragma unroll
            for (int j = 0; j < 8; ++j) { ah[j] = (short)sh[j]; am[j] = (short)sm[j]; }
            a0 = (bf16x8){ah[0], ah[1], ah[2], ah[3], ah[4], ah[5], ah[6], ah[7]};
            a1 = (bf16x8){am[0], am[1], am[2], am[3], am[4], am[5], am[6], am[7]};
          }
#pragma unroll
          for (int st = 0; st < 8; ++st) {
            const short* hb = ffrag + kkl * 4096 + st * 512 + lane * 8;
            bf16x8 b0 = *(const bf16x8*)hb;
            bf16x8 b1 = *(const bf16x8*)(hb + 8192);
            f32x4 c = acc[st];
            c = __builtin_amdgcn_mfma_f32_16x16x32_bf16(a1, b0, c, 0, 0, 0);
            c = __builtin_amdgcn_mfma_f32_16x16x32_bf16(a0, b1, c, 0, 0, 0);
            c = __builtin_amdgcn_mfma_f32_16x16x32_bf16(a0, b0, c, 0, 0, 0);
            acc[st] = c;
          }
        }
        __syncthreads();
      }
      float inv = 1.0f / sqrtf(1.0f + 1e-5f);
      int o0 = wave * 16 + quad * 4;
      float4 bb = *(const float4*)&m1b[o0];
      float4 gg = *(const float4*)&m1g[o0];
#pragma unroll
      for (int st = 0; st < 8; ++st) {
        int m_out = m0 + st * 16 + nl;
        f32x4 cc = acc[st];
        float4 r;
        r.x = (cc[0] + bb.x) * (gg.x * inv);
        r.y = (cc[1] + bb.y) * (gg.y * inv);
        r.z = (cc[2] + bb.z) * (gg.z * inv);
        r.w = (cc[3] + bb.w) * (gg.w * inv);
        *(float4*)&W1f[((size_t)(bk * 1024 + m_out)) * 128 + o0] = r;
      }
    }
    return;
  }

  if (bid < 206) {
    // ================= w2/w3 split =================
    int idx = (bid - 190) * 512 + t;               // 0..8191
#pragma unroll
    for (int e = 0; e < 4; ++e) {
      int i = idx * 4 + e;                         // 0..32767
      int c = i & 127, o = (i >> 7) & 127, l = i >> 14;
      float w = (l ? m3w : m2w)[o * 128 + c];
      unsigned sh, sm;
      split2rn(w, sh, sm);
      int ot = o >> 4, mm = o & 15, kk = c >> 5, q = (c & 31) >> 3, j = c & 7;
      int within = (q * 16 + mm) * 8 + j;
      Wf[(((l * 2 + 0) * 4 + kk) * 8 + ot) * 512 + within] = (short)sh;
      Wf[(((l * 2 + 1) * 4 + kk) * 8 + ot) * 512 + within] = (short)sm;
    }
    return;
  }

  if (bid < 222) {
    // ================= c1/c2 split =================
    int idx2 = (bid - 206) * 512 + t;              // 0..8191
#pragma unroll
    for (int e = 0; e < 4; ++e) {
      int i = idx2 * 4 + e;                        // 0..32767
      int c = i & 127, o = (i >> 7) & 127, l = i >> 14;
      float w = (l ? c2w : c1w)[o * 128 + c];
      unsigned sh, sm;
      split2rn(w, sh, sm);
      int ot = o >> 4, mm = o & 15, kk = c >> 5, q = (c & 31) >> 3, j = c & 7;
      int within = (q * 16 + mm) * 8 + j;
      Wf[131072 + (((l * 2 + 0) * 4 + kk) * 8 + ot) * 512 + within] = (short)sh;
      Wf[131072 + (((l * 2 + 1) * 4 + kk) * 8 + ot) * 512 + within] = (short)sm;
    }
    return;
  }

  // ================= prep constants =================
  if (t < 128) {
    float inv = 1.0f / sqrtf(1.0f + 1e-5f);
    float a1 = m1g[t] * inv;
    prep[t] = a1;
    float a2 = m2g[t] * inv;  prep[256 + t] = a2;  prep[384 + t] = fmaf(m2b[t], a2, m2be[t]);
    float a3 = m3g[t] * inv;  prep[512 + t] = a3;  prep[640 + t] = fmaf(m3b[t], a3, m3be[t]);
    float ac1 = c1g[t] * inv; prep[768 + t] = ac1; prep[896 + t] = fmaf(c1b[t], ac1, c1be[t]);
    float ac2 = c2g[t] * inv; prep[1024 + t] = ac2; prep[1152 + t] = fmaf(c2b[t], ac2, c2be[t]);
    prep[1280 + 4 * t + 0] = m1w[t * 259 + 0] * a1;
    prep[1280 + 4 * t + 1] = m1w[t * 259 + 1] * a1;
    prep[1280 + 4 * t + 2] = m1w[t * 259 + 2] * a1;
    prep[1280 + 4 * t + 3] = m1be[t];
  }
}

// ---------------- MFMA GEMM over one 128(c) x nst_h*16(s) fragment buffer ----------
__device__ __forceinline__ void mfma_layer(const short* __restrict__ Wf,
                                           const short* hfrag, int l,
                                           int wave, int lane, int nst_h,
                                           f32x4 acc[2][4])
{
#pragma unroll 1
  for (int kk = 0; kk < 4; ++kk) {
    bf16x8 a[2][2];
#pragma unroll
    for (int oi = 0; oi < 2; ++oi)
#pragma unroll
      for (int sp = 0; sp < 2; ++sp)
        a[oi][sp] = *(const bf16x8*)(Wf + (((l * 2 + sp) * 4 + kk) * 8 + (wave * 2 + oi)) * 512 + lane * 8);
    for (int st = 0; st < nst_h; ++st) {
      const short* hb = hfrag + kk * 2048 + st * 512 + lane * 8;
      bf16x8 b0 = *(const bf16x8*)(hb);           // hi
      bf16x8 b1 = *(const bf16x8*)(hb + 8192);    // mid
#pragma unroll
      for (int oi = 0; oi < 2; ++oi) {
        f32x4 c = acc[oi][st];
        c = __builtin_amdgcn_mfma_f32_16x16x32_bf16(a[oi][1], b0, c, 0, 0, 0);
        c = __builtin_amdgcn_mfma_f32_16x16x32_bf16(a[oi][0], b1, c, 0, 0, 0);
        c = __builtin_amdgcn_mfma_f32_16x16x32_bf16(a[oi][0], b0, c, 0, 0, 0);
        acc[oi][st] = c;
      }
    }
  }
}

// ---------------- fused SA: 4 balls per block, tiles packed over passes ----------
__global__ __launch_bounds__(256, 3) void sa_kernel(
    const float* __restrict__ xc, const float* __restrict__ nxyz,
    const int* __restrict__ bidx, const int* __restrict__ counts,
    const float* __restrict__ W1f, const float* __restrict__ prep,
    const short* __restrict__ Wf, float* __restrict__ feat_out)
{
  __shared__ __align__(16) short hfrag[16384];   // 32KB
  __shared__ float pcs[512];
  __shared__ float sm[32 * 128];                 // 16KB per-tile o-max
  __shared__ float ccen[12];
  __shared__ int scnt[4];
  int gb = blockIdx.x, bk = gb >> 5, pb = (gb & 31) << 2;
  int t = threadIdx.x;
  int wave = t >> 6, lane = t & 63;
  int quad = lane >> 4, nl = lane & 15;

  pcs[t] = prep[1280 + t];
  pcs[256 + t] = prep[1536 + t];
  if (t < 4) scnt[t] = counts[bk * 128 + pb + t];
  if (t < 12) {
    int bb = t / 3, c = t % 3;
    ccen[t] = nxyz[(bk * 128 + pb + bb) * 3 + c];
  }
  __syncthreads();
  int n0 = (scnt[0] + 15) >> 4, n1 = (scnt[1] + 15) >> 4;
  int n2 = (scnt[2] + 15) >> 4, n3 = (scnt[3] + 15) >> 4;
  int pf1 = n0, pf2 = n0 + n1, pf3 = n0 + n1 + n2, T = n0 + n1 + n2 + n3;

  for (int q0 = 0; q0 < T; q0 += 4) {
    int nst_h = T - q0;
    if (nst_h > 4) nst_h = 4;
    // ---- h1 build ----
    {
      int cg = wave;
      int st = lane >> 4, sl = lane & 15;
      if (st < nst_h) {
        int q = q0 + st;
        int bq = (q >= pf1) + (q >= pf2) + (q >= pf3);
        int tstart = (bq == 0) ? 0 : (bq == 1) ? pf1 : (bq == 2) ? pf2 : pf3;
        int tslot = q - tstart;
        int m = bidx[((size_t)(bk * 128 + pb + bq)) * 128 + tslot * 16 + sl];
        float cen0 = ccen[bq * 3 + 0], cen1 = ccen[bq * 3 + 1], cen2 = ccen[bq * 3 + 2];
        float g0 = (xc[(bk * 3 + 0) * 1024 + m] - cen0) * (1.0f / 0.15f);
        float g1 = (xc[(bk * 3 + 1) * 1024 + m] - cen1) * (1.0f / 0.15f);
        float g2 = (xc[(bk * 3 + 2) * 1024 + m] - cen2) * (1.0f / 0.15f);
        const float4* wrow = (const float4*)(W1f + ((size_t)(bk * 1024 + m)) * 128 + cg * 32);
        const float4* pcp = (const float4*)pcs + cg * 32;
#pragma unroll
        for (int g = 0; g < 4; ++g) {
          float4 wva = wrow[g * 2], wvb = wrow[g * 2 + 1];
          float wv[8] = {wva.x, wva.y, wva.z, wva.w, wvb.x, wvb.y, wvb.z, wvb.w};
          unsigned sh[8], smv[8];
#pragma unroll
          for (int e = 0; e < 8; ++e) {
            float4 pc = pcp[g * 8 + e];
            float hv = fmaxf(wv[e] + pc.x * g0 + pc.y * g1 + pc.z * g2 + pc.w, 0.f);
            split2rn(hv, sh[e], smv[e]);
          }
          int base = (cg * 4 + st) * 512 + (g * 16 + sl) * 8;
          v4i ph = {(int)(sh[0] | (sh[1] << 16)), (int)(sh[2] | (sh[3] << 16)),
                    (int)(sh[4] | (sh[5] << 16)), (int)(sh[6] | (sh[7] << 16))};
          *(v4i*)&hfrag[base] = ph;
          v4i pm = {(int)(smv[0] | (smv[1] << 16)), (int)(smv[2] | (smv[3] << 16)),
                    (int)(smv[4] | (smv[5] << 16)), (int)(smv[6] | (smv[7] << 16))};
          *(v4i*)&hfrag[base + 8192] = pm;
        }
      }
    }
    __syncthreads();

    // ---- layer 2 ----
    f32x4 acc[2][4];
#pragma unroll
    for (int oi = 0; oi < 2; ++oi)
#pragma unroll
      for (int st = 0; st < 4; ++st) acc[oi][st] = (f32x4){0.f, 0.f, 0.f, 0.f};
    mfma_layer(Wf, hfrag, 0, wave, lane, nst_h, acc);
    __syncthreads();

    // ---- h2 epilogue ----
#pragma unroll
    for (int oi = 0; oi < 2; ++oi) {
      int o0 = (wave * 2 + oi) * 16 + quad * 4;
      float4 al = *(const float4*)&prep[256 + o0];
      float4 be = *(const float4*)&prep[384 + o0];
      int kk2 = o0 >> 5, g2 = (o0 & 31) >> 3, j0 = o0 & 7;
      for (int st = 0; st < nst_h; ++st) {
        f32x4 cc = acc[oi][st];
        float v0 = fmaxf(fmaf(cc[0], al.x, be.x), 0.f);
        float v1 = fmaxf(fmaf(cc[1], al.y, be.y), 0.f);
        float v2 = fmaxf(fmaf(cc[2], al.z, be.z), 0.f);
        float v3 = fmaxf(fmaf(cc[3], al.w, be.w), 0.f);
        unsigned h0, m0_, h1, m1_, h2, m2_, h3, m3_;
        split2rn(v0, h0, m0_); split2rn(v1, h1, m1_);
        split2rn(v2, h2, m2_); split2rn(v3, h3, m3_);
        int base = (kk2 * 4 + st) * 512 + (g2 * 16 + nl) * 8 + j0;
        v2i w0 = {(int)(h0 | (h1 << 16)), (int)(h2 | (h3 << 16))};
        *(v2i*)&hfrag[base] = w0;
        v2i w1 = {(int)(m0_ | (m1_ << 16)), (int)(m2_ | (m3_ << 16))};
        *(v2i*)&hfrag[base + 8192] = w1;
      }
    }
    __syncthreads();

    // ---- layer 3 ----
#pragma unroll
    for (int oi = 0; oi < 2; ++oi)
#pragma unroll
      for (int st = 0; st < 4; ++st) acc[oi][st] = (f32x4){0.f, 0.f, 0.f, 0.f};
    mfma_layer(Wf, hfrag, 1, wave, lane, nst_h, acc);

    // ---- layer-3 epilogue: BN+ReLU, quad-reduce max per tile ----
#pragma unroll
    for (int oi = 0; oi < 2; ++oi) {
      int o0 = (wave * 2 + oi) * 16 + quad * 4;
      float4 al = *(const float4*)&prep[512 + o0];
      float4 be = *(const float4*)&prep[640 + o0];
      for (int st = 0; st < nst_h; ++st) {
        f32x4 cc = acc[oi][st];
        float v[4];
        v[0] = fmaxf(fmaf(cc[0], al.x, be.x), 0.f);
        v[1] = fmaxf(fmaf(cc[1], al.y, be.y), 0.f);
        v[2] = fmaxf(fmaf(cc[2], al.z, be.z), 0.f);
        v[3] = fmaxf(fmaf(cc[3], al.w, be.w), 0.f);
#pragma unroll
        for (int r = 0; r < 4; ++r) {
          float x = v[r];
          x = fmaxf(x, __shfl_xor(x, 1));
          x = fmaxf(x, __shfl_xor(x, 2));
          x = fmaxf(x, __shfl_xor(x, 4));
          x = fmaxf(x, __shfl_xor(x, 8));
          if (nl == 0) sm[(q0 + st) * 128 + o0 + r] = x;
        }
      }
    }
    __syncthreads();
  }

  // ---- final: merge tiles per ball, write feat ----
#pragma unroll
  for (int e = t; e < 512; e += 256) {
    int bb = e >> 7, o = e & 127;
    int qs = (bb == 0) ? 0 : (bb == 1) ? pf1 : (bb == 2) ? pf2 : pf3;
    int nq = (bb == 0) ? n0 : (bb == 1) ? n1 : (bb == 2) ? n2 : n3;
    float v = sm[qs * 128 + o];
    for (int q = 1; q < nq; ++q) v = fmaxf(v, sm[(qs + q) * 128 + o]);
    feat_out[(((size_t)bk) << 14) + (o << 7) + pb + bb] = v;
  }
}

// ---------------- head: c1 -> c2 (split2 MFMA) -> op -> scores; 2 blocks/bk ------
__global__ __launch_bounds__(256) void head_kernel(const float* __restrict__ featg,
    const float* __restrict__ prep, const short* __restrict__ Wf,
    const float* __restrict__ nxyz, const float* __restrict__ opw,
    const float* __restrict__ opb, float* __restrict__ scores)
{
  __shared__ __align__(16) short hfrag[16384];   // 32KB frags (128c x 64p)
  __shared__ float hplain[128 * 65];             // stride 65 vs conflicts
  int bk = blockIdx.x >> 1, p0 = (blockIdx.x & 1) << 6;
  int t = threadIdx.x;
  int wave = t >> 6, lane = t & 63;
  int quad = lane >> 4, nl = lane & 15;
  const short* WC = Wf + 131072;

  // ---- stage feat[c][p0..p0+63] into split2 B-frags ----
  {
    int cg = wave;
    int st = lane >> 4, sl = lane & 15;
    const float* fb = featg + (bk << 14) + p0 + lane;
#pragma unroll
    for (int g = 0; g < 4; ++g) {
      float v[8];
#pragma unroll
      for (int e = 0; e < 8; ++e)
        v[e] = fb[(cg * 32 + g * 8 + e) << 7];
      unsigned sh[8], sm[8];
#pragma unroll
      for (int e = 0; e < 8; ++e) split2rn(v[e], sh[e], sm[e]);
      int base = (cg * 4 + st) * 512 + (g * 16 + sl) * 8;
      v4i ph = {(int)(sh[0] | (sh[1] << 16)), (int)(sh[2] | (sh[3] << 16)),
                (int)(sh[4] | (sh[5] << 16)), (int)(sh[6] | (sh[7] << 16))};
      *(v4i*)&hfrag[base] = ph;
      v4i pm = {(int)(sm[0] | (sm[1] << 16)), (int)(sm[2] | (sm[3] << 16)),
                (int)(sm[4] | (sm[5] << 16)), (int)(sm[6] | (sm[7] << 16))};
      *(v4i*)&hfrag[base + 8192] = pm;
    }
  }
  __syncthreads();

  // ---- c1 ----
  f32x4 acc[2][4];
#pragma unroll
  for (int oi = 0; oi < 2; ++oi)
#pragma unroll
    for (int st = 0; st < 4; ++st) acc[oi][st] = (f32x4){0.f, 0.f, 0.f, 0.f};
  mfma_layer(WC, hfrag, 0, wave, lane, 4, acc);
  __syncthreads();

  // ---- c1 epilogue: BN+ReLU, write back frags ----
#pragma unroll
  for (int oi = 0; oi < 2; ++oi) {
    int o0 = (wave * 2 + oi) * 16 + quad * 4;
    float4 al = *(const float4*)&prep[768 + o0];
    float4 be = *(const float4*)&prep[896 + o0];
    int kk2 = o0 >> 5, g2 = (o0 & 31) >> 3, j0 = o0 & 7;
#pragma unroll
    for (int st = 0; st < 4; ++st) {
      f32x4 cc = acc[oi][st];
      float v0 = fmaxf(fmaf(cc[0], al.x, be.x), 0.f);
      float v1 = fmaxf(fmaf(cc[1], al.y, be.y), 0.f);
      float v2 = fmaxf(fmaf(cc[2], al.z, be.z), 0.f);
      float v3 = fmaxf(fmaf(cc[3], al.w, be.w), 0.f);
      unsigned h0, m0_, h1, m1_, h2, m2_, h3, m3_;
      split2rn(v0, h0, m0_); split2rn(v1, h1, m1_);
      split2rn(v2, h2, m2_); split2rn(v3, h3, m3_);
      int base = (kk2 * 4 + st) * 512 + (g2 * 16 + nl) * 8 + j0;
      v2i w0 = {(int)(h0 | (h1 << 16)), (int)(h2 | (h3 << 16))};
      *(v2i*)&hfrag[base] = w0;
      v2i w1 = {(int)(m0_ | (m1_ << 16)), (int)(m2_ | (m3_ << 16))};
      *(v2i*)&hfrag[base + 8192] = w1;
    }
  }
  __syncthreads();

  // ---- c2 ----
#pragma unroll
  for (int oi = 0; oi < 2; ++oi)
#pragma unroll
    for (int st = 0; st < 4; ++st) acc[oi][st] = (f32x4){0.f, 0.f, 0.f, 0.f};
  mfma_layer(WC, hfrag, 1, wave, lane, 4, acc);

  // ---- c2 epilogue: BN+ReLU -> hplain[c][p] ----
#pragma unroll
  for (int oi = 0; oi < 2; ++oi) {
    int o0 = (wave * 2 + oi) * 16 + quad * 4;
    float4 al = *(const float4*)&prep[1024 + o0];
    float4 be = *(const float4*)&prep[1152 + o0];
#pragma unroll
    for (int st = 0; st < 4; ++st) {
      f32x4 cc = acc[oi][st];
      int p = st * 16 + nl;
      hplain[(o0 + 0) * 65 + p] = fmaxf(fmaf(cc[0], al.x, be.x), 0.f);
      hplain[(o0 + 1) * 65 + p] = fmaxf(fmaf(cc[1], al.y, be.y), 0.f);
      hplain[(o0 + 2) * 65 + p] = fmaxf(fmaf(cc[2], al.z, be.z), 0.f);
      hplain[(o0 + 3) * 65 + p] = fmaxf(fmaf(cc[3], al.w, be.w), 0.f);
    }
  }
  __syncthreads();

  // ---- op head + scores ----
  if (t < 64) {
    int p = t, k = bk % 19;
    float res[5];
#pragma unroll
    for (int j = 0; j < 5; ++j) {
      const float* wr = opw + ((size_t)(k * 5 + j)) * 128;
      float a = opb[k * 5 + j];
      for (int c = 0; c < 128; ++c) a = fmaf(wr[c], hplain[c * 65 + p], a);
      res[j] = a;
    }
    int pg = p0 + p;
    float a0 = nxyz[(bk * 128 + pg) * 3 + 0];
    float a1 = nxyz[(bk * 128 + pg) * 3 + 1];
    float a2 = nxyz[(bk * 128 + pg) * 3 + 2];
    float* sc = scores + ((size_t)(bk * 128 + pg)) * 5;
    sc[0] = res[0];
    sc[1] = res[1];
    sc[2] = a0 + res[2];
    sc[3] = a1 + res[3];
    sc[4] = a2 + res[4];
  }
}

extern "C" void kernel_launch(void* const* d_in, const int* in_sizes, int n_in,
                              void* d_out, int out_size, void* d_ws, size_t ws_size,
                              hipStream_t stream) {
  (void)in_sizes; (void)n_in; (void)out_size; (void)ws_size;
  const float* xyz  = (const float*)d_in[0];
  const float* fts  = (const float*)d_in[1];
  const float* m1w  = (const float*)d_in[2];
  const float* m1b  = (const float*)d_in[3];
  const float* m1g  = (const float*)d_in[4];
  const float* m1be = (const float*)d_in[5];
  const float* m2w  = (const float*)d_in[6];
  const float* m2b  = (const float*)d_in[7];
  const float* m2g  = (const float*)d_in[8];
  const float* m2be = (const float*)d_in[9];
  const float* m3w  = (const float*)d_in[10];
  const float* m3b  = (const float*)d_in[11];
  const float* m3g  = (const float*)d_in[12];
  const float* m3be = (const float*)d_in[13];
  const float* c1w  = (const float*)d_in[14];
  const float* c1b  = (const float*)d_in[15];
  const float* c1g  = (const float*)d_in[16];
  const float* c1be = (const float*)d_in[17];
  const float* c2w  = (const float*)d_in[18];
  const float* c2b  = (const float*)d_in[19];
  const float* c2g  = (const float*)d_in[20];
  const float* c2be = (const float*)d_in[21];
  const float* opw  = (const float*)d_in[22];
  const float* opb  = (const float*)d_in[23];

  float* out = (float*)d_out;
  char* ws = (char*)d_ws;
  float* xc   = (float*)(ws + OFF_XC);
  float* nxyz = (float*)(ws + OFF_NXYZ);
  int*   bidx = (int*)(ws + OFF_BIDX);
  float* W1f  = (float*)(ws + OFF_W1F);
  float* prep = (float*)(ws + OFF_PREP);
  short* Wf   = (short*)(ws + OFF_WF);
  int*   cnt  = (int*)(ws + OFF_CNT);

  hipLaunchKernelGGL(front_kernel, dim3(223), dim3(512), 0, stream,
                     xyz, fts, m1w, m1b, m1g, m1be, m2w, m2b, m2g, m2be,
                     m3w, m3b, m3g, m3be, c1w, c1b, c1g, c1be,
                     c2w, c2b, c2g, c2be,
                     xc, nxyz, out + OUT_AGG, bidx, cnt, W1f, Wf, prep);
  hipLaunchKernelGGL(sa_kernel, dim3(NBK * 32), dim3(256), 0, stream,
                     xc, nxyz, bidx, cnt, W1f, prep, Wf, out + OUT_FEAT);
  hipLaunchKernelGGL(head_kernel, dim3(NBK * 2), dim3(256), 0, stream,
                     out + OUT_FEAT, prep, Wf, nxyz, opw, opb, out);
}

// Round 8
// 282.537 us; speedup vs baseline: 2.2114x; 1.0046x over previous
//
#include <hip/hip_runtime.h>
#include <math.h>

// ---------------- problem constants ----------------
// B=2, K=19 -> BK=38 batches; M=1024 points; C=256 feat ch; NPOINT=NSAMPLE=128
#define NBK   38

// ---------------- workspace layout (bytes) ----------------
#define OFF_XC    0u          // [38][3][1024] f32        = 466944
#define OFF_NXYZ  466944u     // [38][128][3]  f32        = 58368
#define OFF_BIDX  525312u     // [38][128][128] i32       = 2490368
#define OFF_W1F   3015680u    // [38][1024][128] f32      = 19922944
#define OFF_PREP  22938624u   // 4096 f32
#define OFF_WF    22955008u   // 196608 shorts: w2/w3 (0), unused (65536), c1/c2 (131072)
#define OFF_CNT   23348224u   // [38][128] i32 ball counts = 19456

// ---------------- d_out layout (float offsets) ----------------
#define OUT_AGG   24320       // scores at 0: (2,19,128,5)
#define OUT_FEAT  38912       // agg: (2,19,128,3), feat: (2,19,128,128)

typedef short bf16x8 __attribute__((ext_vector_type(8)));   // 8 bf16 = 4 VGPR
typedef float f32x4  __attribute__((ext_vector_type(4)));
typedef int   v4i    __attribute__((ext_vector_type(4)));
typedef int   v2i    __attribute__((ext_vector_type(2)));

// exact IEEE fp32 squared distance, no FMA contraction, ((d0^2+d1^2)+d2^2)
__device__ __forceinline__ float dist2f(float a0, float a1, float a2,
                                        float b0, float b1, float b2) {
#pragma clang fp contract(off)
  float d0 = a0 - b0;
  float d1 = a1 - b1;
  float d2 = a2 - b2;
  return d0 * d0 + d1 * d1 + d2 * d2;
}

// 2-way bf16 split with round-to-nearest-even: v ~= hi + mid, residual <= 2^-18 |v|
__device__ __forceinline__ void split2rn(float v, unsigned& sh, unsigned& sm) {
  unsigned u = __float_as_uint(v);
  unsigned rh = (u + 0x7fffu + ((u >> 16) & 1u)) & 0xffff0000u;
  sh = rh >> 16;
  float r1 = v - __uint_as_float(rh);        // exact in fp32
  unsigned u1 = __float_as_uint(r1);
  unsigned rm = (u1 + 0x7fffu + ((u1 >> 16) & 1u)) & 0xffff0000u;
  sm = rm >> 16;
}

// DPP fmax step: v = fmax(v, v shifted by ctrl); invalid lanes keep own value.
#define DPP_FMAX_STEP(v, ctrl)                                                 \
  {                                                                            \
    int _s = __builtin_amdgcn_update_dpp(__float_as_int(v), __float_as_int(v), \
                                         (ctrl), 0xf, 0xf, false);             \
    (v) = fmaxf((v), __int_as_float(_s));                                      \
  }

__device__ __forceinline__ float readlane_f(float v, int l) {
  return __int_as_float(__builtin_amdgcn_readlane(__float_as_int(v), l));
}

// ---------------- K1 "front" (512-thread blocks, 223 total <= 256 CUs) ------
// blocks 0..37: fps with ALL 8 waves computing (2 pts/lane, symmetric
//   barrier — R5-R7 showed the 2-compute/6-idle wave split cost ~350cy/iter
//   of asymmetric-barrier overhead that neither setprio nor sole-tenancy
//   fixed) + ball query;
// 38..189: w1f (8 waves, one o-tile/wave, 2 m-chunks per block);
// 190..205: w2/w3 split; 206..221: c1/c2 split; 222: prep constants.
__global__ __launch_bounds__(512, 2) void front_kernel(
    const float* __restrict__ xyz, const float* __restrict__ feats,
    const float* __restrict__ m1w, const float* __restrict__ m1b,
    const float* __restrict__ m1g, const float* __restrict__ m1be,
    const float* __restrict__ m2w, const float* __restrict__ m2b,
    const float* __restrict__ m2g, const float* __restrict__ m2be,
    const float* __restrict__ m3w, const float* __restrict__ m3b,
    const float* __restrict__ m3g, const float* __restrict__ m3be,
    const float* __restrict__ c1w, const float* __restrict__ c1b,
    const float* __restrict__ c1g, const float* __restrict__ c1be,
    const float* __restrict__ c2w, const float* __restrict__ c2b,
    const float* __restrict__ c2g, const float* __restrict__ c2be,
    float* __restrict__ xc, float* __restrict__ nxyz, float* __restrict__ agg,
    int* __restrict__ bidx, int* __restrict__ counts,
    float* __restrict__ W1f, short* __restrict__ Wf, float* __restrict__ prep)
{
  __shared__ __align__(16) char smem[32768];
  int bid = blockIdx.x, t = threadIdx.x;
  int wave = t >> 6, lane = t & 63;

  if (bid < NBK) {
    // ========== fps (all 8 waves, 2 pts/lane) + ball query (8 waves) =======
    int bk = bid;
    int b = bk / 19, k = bk % 19;
    float4* sp4 = (float4*)smem;                    // 1024 float4 = 16KB
    float4* scen4 = (float4*)(smem + 16384);        // 128 float4 = 2KB
    int* sfar = (int*)(smem + 18432);               // 128 ints
    int2* cexch = (int2*)(smem + 18944);            // [parity][wave] 2x8 int2

    for (int i = t; i < 1024; i += 512) {
      const float* src = xyz + ((size_t)((b * 1024 + i) * 19 + k)) * 3;
      float x0 = src[0], x1 = src[1], x2 = src[2];
      sp4[i] = make_float4(x0, x1, x2, 0.f);
      xc[(bk * 3 + 0) * 1024 + i] = x0;
      xc[(bk * 3 + 1) * 1024 + i] = x1;
      xc[(bk * 3 + 2) * 1024 + i] = x2;
    }
    if (t == 0) sfar[0] = 0;
    __syncthreads();

    // wave owns contiguous points m = wave*128 + lane*2 + j. Ascending m over
    // (wave, lane, j) => earliest-wave/ctz-lane/left-wins tie-breaking
    // reproduces jnp.argmax first-max semantics exactly (R4-proven scheme).
    float px[2], py[2], pz[2], dist[2];
    int mbase = (wave << 7) + (lane << 1);
#pragma unroll
    for (int j = 0; j < 2; ++j) {
      float4 p = sp4[mbase + j];
      px[j] = p.x; py[j] = p.y; pz[j] = p.z;
      dist[j] = 1e10f;
    }

    int far = 0;
    for (int it = 1; it < 128; ++it) {
      float4 c = sp4[far];                       // uniform-address b128 read
      float d0 = dist2f(px[0], py[0], pz[0], c.x, c.y, c.z);
      float d1 = dist2f(px[1], py[1], pz[1], c.x, c.y, c.z);
      dist[0] = fminf(dist[0], d0);
      dist[1] = fminf(dist[1], d1);
      bool L = dist[0] >= dist[1];               // >= keeps left: smaller j
      float lmax = L ? dist[0] : dist[1];
      int lj = (lane << 1) + (L ? 0 : 1);
      // in-row max via DPP row_shr: lanes 15/31/47/63 hold row maxes
      float g = lmax;
      DPP_FMAX_STEP(g, 0x111);   // row_shr:1
      DPP_FMAX_STEP(g, 0x112);   // row_shr:2
      DPP_FMAX_STEP(g, 0x114);   // row_shr:4
      DPP_FMAX_STEP(g, 0x118);   // row_shr:8
      float r0 = readlane_f(g, 15);
      float r1 = readlane_f(g, 31);
      float r2 = readlane_f(g, 47);
      float r3 = readlane_f(g, 63);
      float gmax = fmaxf(fmaxf(r0, r1), fmaxf(r2, r3));
      // smallest lane whose local max equals the wave max
      unsigned long long mk = __ballot(lmax == gmax);
      int wl = (int)__builtin_ctzll(mk);
      int cand_m = (wave << 7) + __builtin_amdgcn_readlane(lj, wl);
      if (lane == 0) cexch[(it & 1) * 8 + wave] =
          make_int2(__float_as_int(gmax), cand_m);
      __syncthreads();
      // scan 8 wave candidates: strict > with ascending wave => earliest
      // wave wins ties (owns smaller indices)
      int2 cc = cexch[(it & 1) * 8 + 0];
      float bd = __int_as_float(cc.x);
      int bm = cc.y;
#pragma unroll
      for (int w = 1; w < 8; ++w) {
        int2 cw = cexch[(it & 1) * 8 + w];
        float dw = __int_as_float(cw.x);
        bool G = dw > bd;
        bd = G ? dw : bd;
        bm = G ? cw.y : bm;
      }
      far = bm;
      if (t == 0) sfar[it] = far;
    }
    __syncthreads();

    // ---- flush centers (LDS scen4 + global nxyz/agg) ----
    if (t < 128) {
      float4 c = sp4[sfar[t]];
      scen4[t] = c;
      nxyz[bk * 384 + t * 3 + 0] = c.x;
      nxyz[bk * 384 + t * 3 + 1] = c.y;
      nxyz[bk * 384 + t * 3 + 2] = c.z;
      agg[bk * 384 + t * 3 + 0] = c.x;
      agg[bk * 384 + t * 3 + 1] = c.y;
      agg[bk * 384 + t * 3 + 2] = c.z;
    }
    __syncthreads();

    // ---- ball query: 8 waves x 16 balls from LDS ----
    for (int p = wave * 16; p < wave * 16 + 16; ++p) {
      float4 cen = scen4[p];
      int* outp = bidx + ((size_t)(bk * 128 + p)) * 128;
      int count = 0, first = 0;
      bool got = false;
      for (int ch = 0; ch < 16 && count < 128; ++ch) {
        int m = (ch << 6) + lane;
        float4 pv = sp4[m];
        float d = dist2f(pv.x, pv.y, pv.z, cen.x, cen.y, cen.z);
        bool flag = d < 0.0225f;                 // strict fp32, RADIUS^2
        unsigned long long mask = __ballot(flag);
        if (!got && mask) { first = (ch << 6) + __builtin_ctzll(mask); got = true; }
        int pos = count + (int)__popcll(mask & ((1ull << lane) - 1ull));
        if (flag && pos < 128) outp[pos] = m;
        count += (int)__popcll(mask);
      }
      for (int j = count + lane; j < 128; j += 64) outp[j] = first;
      if (lane == 0) counts[bk * 128 + p] = count > 128 ? 128 : count;
    }
    return;
  }

  if (bid < 190) {
    // ======== w1f: 8 waves (one 16-o tile each), 2 m-chunks per block ========
    short* ffrag = (short*)smem;                  // 32KB
    int blk = bid - NBK;                          // 0..151
    int bk = blk >> 2, mq = blk & 3;
    int b = bk / 19, k = bk % 19;
    int quad = lane >> 4, nl = lane & 15;
    int mloc = t & 127, cq = t >> 7;              // cq 0..3
    int chalf = cq >> 1, ghalf = cq & 1;
    int st_w = mloc >> 4, sl_w = mloc & 15;

    for (int half = 0; half < 2; ++half) {
      int m0 = (mq << 8) + (half << 7);
      const float* fbase = feats + ((size_t)(b * 4864 + k)) * 1024 + m0 + mloc;

      f32x4 acc[8];
#pragma unroll
      for (int st = 0; st < 8; ++st) acc[st] = (f32x4){0.f, 0.f, 0.f, 0.f};

      for (int ch = 0; ch < 4; ++ch) {
        int cbase = ch * 64 + chalf * 32;
#pragma unroll
        for (int g2 = 0; g2 < 2; ++g2) {
          int g = ghalf * 2 + g2;
          float v[8];
#pragma unroll
          for (int j = 0; j < 8; ++j)
            v[j] = fbase[(size_t)(cbase + g * 8 + j) * 19456];
          unsigned sh[8], sm[8];
#pragma unroll
          for (int j = 0; j < 8; ++j) split2rn(v[j], sh[j], sm[j]);
          int base = chalf * 4096 + st_w * 512 + (g * 16 + sl_w) * 8;
          v4i ph = {(int)(sh[0] | (sh[1] << 16)), (int)(sh[2] | (sh[3] << 16)),
                    (int)(sh[4] | (sh[5] << 16)), (int)(sh[6] | (sh[7] << 16))};
          *(v4i*)&ffrag[base] = ph;
          v4i pm = {(int)(sm[0] | (sm[1] << 16)), (int)(sm[2] | (sm[3] << 16)),
                    (int)(sm[4] | (sm[5] << 16)), (int)(sm[6] | (sm[7] << 16))};
          *(v4i*)&ffrag[base + 8192] = pm;
        }
        __syncthreads();
#pragma unroll
        for (int kkl = 0; kkl < 2; ++kkl) {
          int kk = ch * 2 + kkl;
          bf16x8 a0, a1;
          {
            int o_row = wave * 16 + nl;
            const float* wsrc = m1w + o_row * 259 + 3 + kk * 32 + quad * 8;
            float wv[8];
#pragma unroll
            for (int j = 0; j < 8; ++j) wv[j] = wsrc[j];
            unsigned sh[8], sm[8];
#pragma unroll
            for (int j = 0; j < 8; ++j) split2rn(wv[j], sh[j], sm[j]);
            short ah[8], am[8];
#pragma unroll
            for (int j = 0; j < 8; ++j) { ah[j] = (short)sh[j]; am[j] = (short)sm[j]; }
            a0 = (bf16x8){ah[0], ah[1], ah[2], ah[3], ah[4], ah[5], ah[6], ah[7]};
            a1 = (bf16x8){am[0], am[1], am[2], am[3], am[4], am[5], am[6], am[7]};
          }
#pragma unroll
          for (int st = 0; st < 8; ++st) {
            const short* hb = ffrag + kkl * 4096 + st * 512 + lane * 8;
            bf16x8 b0 = *(const bf16x8*)hb;
            bf16x8 b1 = *(const bf16x8*)(hb + 8192);
            f32x4 c = acc[st];
            c = __builtin_amdgcn_mfma_f32_16x16x32_bf16(a1, b0, c, 0, 0, 0);
            c = __builtin_amdgcn_mfma_f32_16x16x32_bf16(a0, b1, c, 0, 0, 0);
            c = __builtin_amdgcn_mfma_f32_16x16x32_bf16(a0, b0, c, 0, 0, 0);
            acc[st] = c;
          }
        }
        __syncthreads();
      }
      float inv = 1.0f / sqrtf(1.0f + 1e-5f);
      int o0 = wave * 16 + quad * 4;
      float4 bb = *(const float4*)&m1b[o0];
      float4 gg = *(const float4*)&m1g[o0];
#pragma unroll
      for (int st = 0; st < 8; ++st) {
        int m_out = m0 + st * 16 + nl;
        f32x4 cc = acc[st];
        float4 r;
        r.x = (cc[0] + bb.x) * (gg.x * inv);
        r.y = (cc[1] + bb.y) * (gg.y * inv);
        r.z = (cc[2] + bb.z) * (gg.z * inv);
        r.w = (cc[3] + bb.w) * (gg.w * inv);
        *(float4*)&W1f[((size_t)(bk * 1024 + m_out)) * 128 + o0] = r;
      }
    }
    return;
  }

  if (bid < 206) {
    // ================= w2/w3 split =================
    int idx = (bid - 190) * 512 + t;               // 0..8191
#pragma unroll
    for (int e = 0; e < 4; ++e) {
      int i = idx * 4 + e;                         // 0..32767
      int c = i & 127, o = (i >> 7) & 127, l = i >> 14;
      float w = (l ? m3w : m2w)[o * 128 + c];
      unsigned sh, sm;
      split2rn(w, sh, sm);
      int ot = o >> 4, mm = o & 15, kk = c >> 5, q = (c & 31) >> 3, j = c & 7;
      int within = (q * 16 + mm) * 8 + j;
      Wf[(((l * 2 + 0) * 4 + kk) * 8 + ot) * 512 + within] = (short)sh;
      Wf[(((l * 2 + 1) * 4 + kk) * 8 + ot) * 512 + within] = (short)sm;
    }
    return;
  }

  if (bid < 222) {
    // ================= c1/c2 split =================
    int idx2 = (bid - 206) * 512 + t;              // 0..8191
#pragma unroll
    for (int e = 0; e < 4; ++e) {
      int i = idx2 * 4 + e;                        // 0..32767
      int c = i & 127, o = (i >> 7) & 127, l = i >> 14;
      float w = (l ? c2w : c1w)[o * 128 + c];
      unsigned sh, sm;
      split2rn(w, sh, sm);
      int ot = o >> 4, mm = o & 15, kk = c >> 5, q = (c & 31) >> 3, j = c & 7;
      int within = (q * 16 + mm) * 8 + j;
      Wf[131072 + (((l * 2 + 0) * 4 + kk) * 8 + ot) * 512 + within] = (short)sh;
      Wf[131072 + (((l * 2 + 1) * 4 + kk) * 8 + ot) * 512 + within] = (short)sm;
    }
    return;
  }

  // ================= prep constants =================
  if (t < 128) {
    float inv = 1.0f / sqrtf(1.0f + 1e-5f);
    float a1 = m1g[t] * inv;
    prep[t] = a1;
    float a2 = m2g[t] * inv;  prep[256 + t] = a2;  prep[384 + t] = fmaf(m2b[t], a2, m2be[t]);
    float a3 = m3g[t] * inv;  prep[512 + t] = a3;  prep[640 + t] = fmaf(m3b[t], a3, m3be[t]);
    float ac1 = c1g[t] * inv; prep[768 + t] = ac1; prep[896 + t] = fmaf(c1b[t], ac1, c1be[t]);
    float ac2 = c2g[t] * inv; prep[1024 + t] = ac2; prep[1152 + t] = fmaf(c2b[t], ac2, c2be[t]);
    prep[1280 + 4 * t + 0] = m1w[t * 259 + 0] * a1;
    prep[1280 + 4 * t + 1] = m1w[t * 259 + 1] * a1;
    prep[1280 + 4 * t + 2] = m1w[t * 259 + 2] * a1;
    prep[1280 + 4 * t + 3] = m1be[t];
  }
}

// ---------------- MFMA GEMM over one 128(c) x nst_h*16(s) fragment buffer ----------
__device__ __forceinline__ void mfma_layer(const short* __restrict__ Wf,
                                           const short* hfrag, int l,
                                           int wave, int lane, int nst_h,
                                           f32x4 acc[2][4])
{
#pragma unroll 1
  for (int kk = 0; kk < 4; ++kk) {
    bf16x8 a[2][2];
#pragma unroll
    for (int oi = 0; oi < 2; ++oi)
#pragma unroll
      for (int sp = 0; sp < 2; ++sp)
        a[oi][sp] = *(const bf16x8*)(Wf + (((l * 2 + sp) * 4 + kk) * 8 + (wave * 2 + oi)) * 512 + lane * 8);
    for (int st = 0; st < nst_h; ++st) {
      const short* hb = hfrag + kk * 2048 + st * 512 + lane * 8;
      bf16x8 b0 = *(const bf16x8*)(hb);           // hi
      bf16x8 b1 = *(const bf16x8*)(hb + 8192);    // mid
#pragma unroll
      for (int oi = 0; oi < 2; ++oi) {
        f32x4 c = acc[oi][st];
        c = __builtin_amdgcn_mfma_f32_16x16x32_bf16(a[oi][1], b0, c, 0, 0, 0);
        c = __builtin_amdgcn_mfma_f32_16x16x32_bf16(a[oi][0], b1, c, 0, 0, 0);
        c = __builtin_amdgcn_mfma_f32_16x16x32_bf16(a[oi][0], b0, c, 0, 0, 0);
        acc[oi][st] = c;
      }
    }
  }
}

// ---------------- fused SA: 4 balls per block, tiles packed over passes ----------
__global__ __launch_bounds__(256, 3) void sa_kernel(
    const float* __restrict__ xc, const float* __restrict__ nxyz,
    const int* __restrict__ bidx, const int* __restrict__ counts,
    const float* __restrict__ W1f, const float* __restrict__ prep,
    const short* __restrict__ Wf, float* __restrict__ feat_out)
{
  __shared__ __align__(16) short hfrag[16384];   // 32KB
  __shared__ float pcs[512];
  __shared__ float sm[32 * 128];                 // 16KB per-tile o-max
  __shared__ float ccen[12];
  __shared__ int scnt[4];
  int gb = blockIdx.x, bk = gb >> 5, pb = (gb & 31) << 2;
  int t = threadIdx.x;
  int wave = t >> 6, lane = t & 63;
  int quad = lane >> 4, nl = lane & 15;

  pcs[t] = prep[1280 + t];
  pcs[256 + t] = prep[1536 + t];
  if (t < 4) scnt[t] = counts[bk * 128 + pb + t];
  if (t < 12) {
    int bb = t / 3, c = t % 3;
    ccen[t] = nxyz[(bk * 128 + pb + bb) * 3 + c];
  }
  __syncthreads();
  int n0 = (scnt[0] + 15) >> 4, n1 = (scnt[1] + 15) >> 4;
  int n2 = (scnt[2] + 15) >> 4, n3 = (scnt[3] + 15) >> 4;
  int pf1 = n0, pf2 = n0 + n1, pf3 = n0 + n1 + n2, T = n0 + n1 + n2 + n3;

  for (int q0 = 0; q0 < T; q0 += 4) {
    int nst_h = T - q0;
    if (nst_h > 4) nst_h = 4;
    // ---- h1 build ----
    {
      int cg = wave;
      int st = lane >> 4, sl = lane & 15;
      if (st < nst_h) {
        int q = q0 + st;
        int bq = (q >= pf1) + (q >= pf2) + (q >= pf3);
        int tstart = (bq == 0) ? 0 : (bq == 1) ? pf1 : (bq == 2) ? pf2 : pf3;
        int tslot = q - tstart;
        int m = bidx[((size_t)(bk * 128 + pb + bq)) * 128 + tslot * 16 + sl];
        float cen0 = ccen[bq * 3 + 0], cen1 = ccen[bq * 3 + 1], cen2 = ccen[bq * 3 + 2];
        float g0 = (xc[(bk * 3 + 0) * 1024 + m] - cen0) * (1.0f / 0.15f);
        float g1 = (xc[(bk * 3 + 1) * 1024 + m] - cen1) * (1.0f / 0.15f);
        float g2 = (xc[(bk * 3 + 2) * 1024 + m] - cen2) * (1.0f / 0.15f);
        const float4* wrow = (const float4*)(W1f + ((size_t)(bk * 1024 + m)) * 128 + cg * 32);
        const float4* pcp = (const float4*)pcs + cg * 32;
#pragma unroll
        for (int g = 0; g < 4; ++g) {
          float4 wva = wrow[g * 2], wvb = wrow[g * 2 + 1];
          float wv[8] = {wva.x, wva.y, wva.z, wva.w, wvb.x, wvb.y, wvb.z, wvb.w};
          unsigned sh[8], smv[8];
#pragma unroll
          for (int e = 0; e < 8; ++e) {
            float4 pc = pcp[g * 8 + e];
            float hv = fmaxf(wv[e] + pc.x * g0 + pc.y * g1 + pc.z * g2 + pc.w, 0.f);
            split2rn(hv, sh[e], smv[e]);
          }
          int base = (cg * 4 + st) * 512 + (g * 16 + sl) * 8;
          v4i ph = {(int)(sh[0] | (sh[1] << 16)), (int)(sh[2] | (sh[3] << 16)),
                    (int)(sh[4] | (sh[5] << 16)), (int)(sh[6] | (sh[7] << 16))};
          *(v4i*)&hfrag[base] = ph;
          v4i pm = {(int)(smv[0] | (smv[1] << 16)), (int)(smv[2] | (smv[3] << 16)),
                    (int)(smv[4] | (smv[5] << 16)), (int)(smv[6] | (smv[7] << 16))};
          *(v4i*)&hfrag[base + 8192] = pm;
        }
      }
    }
    __syncthreads();

    // ---- layer 2 ----
    f32x4 acc[2][4];
#pragma unroll
    for (int oi = 0; oi < 2; ++oi)
#pragma unroll
      for (int st = 0; st < 4; ++st) acc[oi][st] = (f32x4){0.f, 0.f, 0.f, 0.f};
    mfma_layer(Wf, hfrag, 0, wave, lane, nst_h, acc);
    __syncthreads();

    // ---- h2 epilogue ----
#pragma unroll
    for (int oi = 0; oi < 2; ++oi) {
      int o0 = (wave * 2 + oi) * 16 + quad * 4;
      float4 al = *(const float4*)&prep[256 + o0];
      float4 be = *(const float4*)&prep[384 + o0];
      int kk2 = o0 >> 5, g2 = (o0 & 31) >> 3, j0 = o0 & 7;
      for (int st = 0; st < nst_h; ++st) {
        f32x4 cc = acc[oi][st];
        float v0 = fmaxf(fmaf(cc[0], al.x, be.x), 0.f);
        float v1 = fmaxf(fmaf(cc[1], al.y, be.y), 0.f);
        float v2 = fmaxf(fmaf(cc[2], al.z, be.z), 0.f);
        float v3 = fmaxf(fmaf(cc[3], al.w, be.w), 0.f);
        unsigned h0, m0_, h1, m1_, h2, m2_, h3, m3_;
        split2rn(v0, h0, m0_); split2rn(v1, h1, m1_);
        split2rn(v2, h2, m2_); split2rn(v3, h3, m3_);
        int base = (kk2 * 4 + st) * 512 + (g2 * 16 + nl) * 8 + j0;
        v2i w0 = {(int)(h0 | (h1 << 16)), (int)(h2 | (h3 << 16))};
        *(v2i*)&hfrag[base] = w0;
        v2i w1 = {(int)(m0_ | (m1_ << 16)), (int)(m2_ | (m3_ << 16))};
        *(v2i*)&hfrag[base + 8192] = w1;
      }
    }
    __syncthreads();

    // ---- layer 3 ----
#pragma unroll
    for (int oi = 0; oi < 2; ++oi)
#pragma unroll
      for (int st = 0; st < 4; ++st) acc[oi][st] = (f32x4){0.f, 0.f, 0.f, 0.f};
    mfma_layer(Wf, hfrag, 1, wave, lane, nst_h, acc);

    // ---- layer-3 epilogue: BN+ReLU, quad-reduce max per tile ----
#pragma unroll
    for (int oi = 0; oi < 2; ++oi) {
      int o0 = (wave * 2 + oi) * 16 + quad * 4;
      float4 al = *(const float4*)&prep[512 + o0];
      float4 be = *(const float4*)&prep[640 + o0];
      for (int st = 0; st < nst_h; ++st) {
        f32x4 cc = acc[oi][st];
        float v[4];
        v[0] = fmaxf(fmaf(cc[0], al.x, be.x), 0.f);
        v[1] = fmaxf(fmaf(cc[1], al.y, be.y), 0.f);
        v[2] = fmaxf(fmaf(cc[2], al.z, be.z), 0.f);
        v[3] = fmaxf(fmaf(cc[3], al.w, be.w), 0.f);
#pragma unroll
        for (int r = 0; r < 4; ++r) {
          float x = v[r];
          x = fmaxf(x, __shfl_xor(x, 1));
          x = fmaxf(x, __shfl_xor(x, 2));
          x = fmaxf(x, __shfl_xor(x, 4));
          x = fmaxf(x, __shfl_xor(x, 8));
          if (nl == 0) sm[(q0 + st) * 128 + o0 + r] = x;
        }
      }
    }
    __syncthreads();
  }

  // ---- final: merge tiles per ball, write feat ----
#pragma unroll
  for (int e = t; e < 512; e += 256) {
    int bb = e >> 7, o = e & 127;
    int qs = (bb == 0) ? 0 : (bb == 1) ? pf1 : (bb == 2) ? pf2 : pf3;
    int nq = (bb == 0) ? n0 : (bb == 1) ? n1 : (bb == 2) ? n2 : n3;
    float v = sm[qs * 128 + o];
    for (int q = 1; q < nq; ++q) v = fmaxf(v, sm[(qs + q) * 128 + o]);
    feat_out[(((size_t)bk) << 14) + (o << 7) + pb + bb] = v;
  }
}

// ---------------- head: c1 -> c2 (split2 MFMA) -> op -> scores; 2 blocks/bk ------
__global__ __launch_bounds__(256) void head_kernel(const float* __restrict__ featg,
    const float* __restrict__ prep, const short* __restrict__ Wf,
    const float* __restrict__ nxyz, const float* __restrict__ opw,
    const float* __restrict__ opb, float* __restrict__ scores)
{
  __shared__ __align__(16) short hfrag[16384];   // 32KB frags (128c x 64p)
  __shared__ float hplain[128 * 65];             // stride 65 vs conflicts
  int bk = blockIdx.x >> 1, p0 = (blockIdx.x & 1) << 6;
  int t = threadIdx.x;
  int wave = t >> 6, lane = t & 63;
  int quad = lane >> 4, nl = lane & 15;
  const short* WC = Wf + 131072;

  // ---- stage feat[c][p0..p0+63] into split2 B-frags ----
  {
    int cg = wave;
    int st = lane >> 4, sl = lane & 15;
    const float* fb = featg + (bk << 14) + p0 + lane;
#pragma unroll
    for (int g = 0; g < 4; ++g) {
      float v[8];
#pragma unroll
      for (int e = 0; e < 8; ++e)
        v[e] = fb[(cg * 32 + g * 8 + e) << 7];
      unsigned sh[8], sm[8];
#pragma unroll
      for (int e = 0; e < 8; ++e) split2rn(v[e], sh[e], sm[e]);
      int base = (cg * 4 + st) * 512 + (g * 16 + sl) * 8;
      v4i ph = {(int)(sh[0] | (sh[1] << 16)), (int)(sh[2] | (sh[3] << 16)),
                (int)(sh[4] | (sh[5] << 16)), (int)(sh[6] | (sh[7] << 16))};
      *(v4i*)&hfrag[base] = ph;
      v4i pm = {(int)(sm[0] | (sm[1] << 16)), (int)(sm[2] | (sm[3] << 16)),
                (int)(sm[4] | (sm[5] << 16)), (int)(sm[6] | (sm[7] << 16))};
      *(v4i*)&hfrag[base + 8192] = pm;
    }
  }
  __syncthreads();

  // ---- c1 ----
  f32x4 acc[2][4];
#pragma unroll
  for (int oi = 0; oi < 2; ++oi)
#pragma unroll
    for (int st = 0; st < 4; ++st) acc[oi][st] = (f32x4){0.f, 0.f, 0.f, 0.f};
  mfma_layer(WC, hfrag, 0, wave, lane, 4, acc);
  __syncthreads();

  // ---- c1 epilogue: BN+ReLU, write back frags ----
#pragma unroll
  for (int oi = 0; oi < 2; ++oi) {
    int o0 = (wave * 2 + oi) * 16 + quad * 4;
    float4 al = *(const float4*)&prep[768 + o0];
    float4 be = *(const float4*)&prep[896 + o0];
    int kk2 = o0 >> 5, g2 = (o0 & 31) >> 3, j0 = o0 & 7;
#pragma unroll
    for (int st = 0; st < 4; ++st) {
      f32x4 cc = acc[oi][st];
      float v0 = fmaxf(fmaf(cc[0], al.x, be.x), 0.f);
      float v1 = fmaxf(fmaf(cc[1], al.y, be.y), 0.f);
      float v2 = fmaxf(fmaf(cc[2], al.z, be.z), 0.f);
      float v3 = fmaxf(fmaf(cc[3], al.w, be.w), 0.f);
      unsigned h0, m0_, h1, m1_, h2, m2_, h3, m3_;
      split2rn(v0, h0, m0_); split2rn(v1, h1, m1_);
      split2rn(v2, h2, m2_); split2rn(v3, h3, m3_);
      int base = (kk2 * 4 + st) * 512 + (g2 * 16 + nl) * 8 + j0;
      v2i w0 = {(int)(h0 | (h1 << 16)), (int)(h2 | (h3 << 16))};
      *(v2i*)&hfrag[base] = w0;
      v2i w1 = {(int)(m0_ | (m1_ << 16)), (int)(m2_ | (m3_ << 16))};
      *(v2i*)&hfrag[base + 8192] = w1;
    }
  }
  __syncthreads();

  // ---- c2 ----
#pragma unroll
  for (int oi = 0; oi < 2; ++oi)
#pragma unroll
    for (int st = 0; st < 4; ++st) acc[oi][st] = (f32x4){0.f, 0.f, 0.f, 0.f};
  mfma_layer(WC, hfrag, 1, wave, lane, 4, acc);

  // ---- c2 epilogue: BN+ReLU -> hplain[c][p] ----
#pragma unroll
  for (int oi = 0; oi < 2; ++oi) {
    int o0 = (wave * 2 + oi) * 16 + quad * 4;
    float4 al = *(const float4*)&prep[1024 + o0];
    float4 be = *(const float4*)&prep[1152 + o0];
#pragma unroll
    for (int st = 0; st < 4; ++st) {
      f32x4 cc = acc[oi][st];
      int p = st * 16 + nl;
      hplain[(o0 + 0) * 65 + p] = fmaxf(fmaf(cc[0], al.x, be.x), 0.f);
      hplain[(o0 + 1) * 65 + p] = fmaxf(fmaf(cc[1], al.y, be.y), 0.f);
      hplain[(o0 + 2) * 65 + p] = fmaxf(fmaf(cc[2], al.z, be.z), 0.f);
      hplain[(o0 + 3) * 65 + p] = fmaxf(fmaf(cc[3], al.w, be.w), 0.f);
    }
  }
  __syncthreads();

  // ---- op head + scores ----
  if (t < 64) {
    int p = t, k = bk % 19;
    float res[5];
#pragma unroll
    for (int j = 0; j < 5; ++j) {
      const float* wr = opw + ((size_t)(k * 5 + j)) * 128;
      float a = opb[k * 5 + j];
      for (int c = 0; c < 128; ++c) a = fmaf(wr[c], hplain[c * 65 + p], a);
      res[j] = a;
    }
    int pg = p0 + p;
    float a0 = nxyz[(bk * 128 + pg) * 3 + 0];
    float a1 = nxyz[(bk * 128 + pg) * 3 + 1];
    float a2 = nxyz[(bk * 128 + pg) * 3 + 2];
    float* sc = scores + ((size_t)(bk * 128 + pg)) * 5;
    sc[0] = res[0];
    sc[1] = res[1];
    sc[2] = a0 + res[2];
    sc[3] = a1 + res[3];
    sc[4] = a2 + res[4];
  }
}

extern "C" void kernel_launch(void* const* d_in, const int* in_sizes, int n_in,
                              void* d_out, int out_size, void* d_ws, size_t ws_size,
                              hipStream_t stream) {
  (void)in_sizes; (void)n_in; (void)out_size; (void)ws_size;
  const float* xyz  = (const float*)d_in[0];
  const float* fts  = (const float*)d_in[1];
  const float* m1w  = (const float*)d_in[2];
  const float* m1b  = (const float*)d_in[3];
  const float* m1g  = (const float*)d_in[4];
  const float* m1be = (const float*)d_in[5];
  const float* m2w  = (const float*)d_in[6];
  const float* m2b  = (const float*)d_in[7];
  const float* m2g  = (const float*)d_in[8];
  const float* m2be = (const float*)d_in[9];
  const float* m3w  = (const float*)d_in[10];
  const float* m3b  = (const float*)d_in[11];
  const float* m3g  = (const float*)d_in[12];
  const float* m3be = (const float*)d_in[13];
  const float* c1w  = (const float*)d_in[14];
  const float* c1b  = (const float*)d_in[15];
  const float* c1g  = (const float*)d_in[16];
  const float* c1be = (const float*)d_in[17];
  const float* c2w  = (const float*)d_in[18];
  const float* c2b  = (const float*)d_in[19];
  const float* c2g  = (const float*)d_in[20];
  const float* c2be = (const float*)d_in[21];
  const float* opw  = (const float*)d_in[22];
  const float* opb  = (const float*)d_in[23];

  float* out = (float*)d_out;
  char* ws = (char*)d_ws;
  float* xc   = (float*)(ws + OFF_XC);
  float* nxyz = (float*)(ws + OFF_NXYZ);
  int*   bidx = (int*)(ws + OFF_BIDX);
  float* W1f  = (float*)(ws + OFF_W1F);
  float* prep = (float*)(ws + OFF_PREP);
  short* Wf   = (short*)(ws + OFF_WF);
  int*   cnt  = (int*)(ws + OFF_CNT);

  hipLaunchKernelGGL(front_kernel, dim3(223), dim3(512), 0, stream,
                     xyz, fts, m1w, m1b, m1g, m1be, m2w, m2b, m2g, m2be,
                     m3w, m3b, m3g, m3be, c1w, c1b, c1g, c1be,
                     c2w, c2b, c2g, c2be,
                     xc, nxyz, out + OUT_AGG, bidx, cnt, W1f, Wf, prep);
  hipLaunchKernelGGL(sa_kernel, dim3(NBK * 32), dim3(256), 0, stream,
                     xc, nxyz, bidx, cnt, W1f, prep, Wf, out + OUT_FEAT);
  hipLaunchKernelGGL(head_kernel, dim3(NBK * 2), dim3(256), 0, stream,
                     out + OUT_FEAT, prep, Wf, nxyz, opw, opb, out);
}